// Round 6
// baseline (316.262 us; speedup 1.0000x reference)
//
#include <hip/hip_runtime.h>
#include <hip/hip_bf16.h>
#include <math.h>

#define BB 512
#define SS 128
#define DD 256
#define HH 4
#define TOPK 8
#define D3 768
#define DMA 248
#define ACT_ 8
#define NTOK 65536            // B*S

typedef __attribute__((ext_vector_type(8))) short bf16x8;
typedef __attribute__((ext_vector_type(4))) short short4v;
typedef __attribute__((ext_vector_type(4))) float f32x4;

static __device__ __forceinline__ short f2bf(float x) {
    __hip_bfloat16 h = __float2bfloat16(x);
    return *reinterpret_cast<short*>(&h);
}
static __device__ __forceinline__ float bf2f(short s) {
    __hip_bfloat16 h = *reinterpret_cast<__hip_bfloat16*>(&s);
    return __bfloat162float(h);
}
static __device__ __forceinline__ float tanh_fast(float x) {
    float e = __expf(2.f * x);
    return 1.f - 2.f / (e + 1.f);
}

// Swizzled LDS index for the [64][256]-short H/X strips: XOR row bits into the
// 16B-unit bits of col. Keeps bf16x8 groups contiguous (XOR bits >= 3 only).
#define HSW(r, c) ((r) * 256 + ((c) ^ (((r) & 7) << 3)))

// ---------------------------------------------------------------------------
// device helpers for the merged prep kernel
// ---------------------------------------------------------------------------
__device__ __forceinline__ void dev_wsplit(float (*t)[33], const float* src,
        short* dhi, short* dlo, int R, int C, int Cpad, int blk, int tid) {
    const int ctiles = Cpad >> 5;
    const int rt = blk / ctiles, ct = blk % ctiles;
    const int r0 = rt * 32, c0 = ct * 32;
#pragma unroll
    for (int i = 0; i < 4; ++i) {
        int idx = i * 256 + tid;
        int lr = idx >> 5, lc = idx & 31;
        t[lr][lc] = (c0 + lc < C) ? src[(size_t)(r0 + lr) * C + c0 + lc] : 0.f;
    }
    __syncthreads();
#pragma unroll
    for (int i = 0; i < 4; ++i) {
        int idx = i * 256 + tid;
        int lc = idx >> 5, lr = idx & 31;
        float v = t[lr][lc];
        short h = f2bf(v);
        size_t o = (size_t)(c0 + lc) * R + r0 + lr;
        dhi[o] = h;
        dlo[o] = f2bf(v - bf2f(h));
    }
}

__device__ __forceinline__ void dev_trbf(float (*t)[33], const float* src,
        __hip_bfloat16* dst, int R, int C, int blk, int tid) {
    const int ctiles = C >> 5;
    const int rt = blk / ctiles, ct = blk % ctiles;
    const int r0 = rt * 32, c0 = ct * 32;
#pragma unroll
    for (int i = 0; i < 4; ++i) {
        int idx = i * 256 + tid;
        int lr = idx >> 5, lc = idx & 31;
        t[lr][lc] = src[(size_t)(r0 + lr) * C + c0 + lc];
    }
    __syncthreads();
#pragma unroll
    for (int i = 0; i < 4; ++i) {
        int idx = i * 256 + tid;
        int lc = idx >> 5, lr = idx & 31;
        dst[(size_t)(c0 + lc) * R + r0 + lr] = __float2bfloat16(t[lr][lc]);
    }
}

__device__ __forceinline__ void dev_prep(float (*t)[33], const float* Wqkv,
        float* WqT, short* WqTbf, __hip_bfloat16* WkvT, int blk, int tid) {
    const int rt = blk / 24, ct = blk % 24;
    const int r0 = rt * 32, c0 = ct * 32;
#pragma unroll
    for (int i = 0; i < 4; ++i) {
        int idx = i * 256 + tid;
        int lr = idx >> 5, lc = idx & 31;
        t[lr][lc] = Wqkv[(size_t)(r0 + lr) * D3 + c0 + lc];
    }
    __syncthreads();
#pragma unroll
    for (int i = 0; i < 4; ++i) {
        int idx = i * 256 + tid;
        int lc = idx >> 5, lr = idx & 31;
        float v = t[lr][lc];
        int c = c0 + lc, r = r0 + lr;
        if (c < 256) {
            WqT[(size_t)c * 256 + r] = v;
            WqTbf[(size_t)c * 256 + r] = f2bf(v);
        } else {
            WkvT[(size_t)(c - 256) * 256 + r] = __float2bfloat16(v);
        }
    }
}

// ---------------------------------------------------------------------------
// K_prepall: all weight transposes/splits + pdcast + xasum_g zeroing.
// ---------------------------------------------------------------------------
__global__ void __launch_bounds__(256) k_prepall(
        const float* __restrict__ W1, short* __restrict__ W1Thi, short* __restrict__ W1Tlo,
        const float* __restrict__ W2, short* __restrict__ W2Thi, short* __restrict__ W2Tlo,
        const float* __restrict__ Wqkv, float* __restrict__ WqT, short* __restrict__ WqTbf,
        __hip_bfloat16* __restrict__ WkvT,
        const float* __restrict__ W_ih, __hip_bfloat16* __restrict__ WihT,
        const float* __restrict__ W_hh, __hip_bfloat16* __restrict__ WhhT,
        const float* __restrict__ Wo, __hip_bfloat16* __restrict__ WoT,
        const float* __restrict__ prev_d, __hip_bfloat16* __restrict__ pdbf,
        float* __restrict__ xasum_g) {
    __shared__ float t[32][33];
    const int blk = blockIdx.x, tid = threadIdx.x;
    if (blk < 16)        dev_wsplit(t, W1, W1Thi, W1Tlo, 64, 256, 256, blk, tid);
    else if (blk < 80)   dev_wsplit(t, W2, W2Thi, W2Tlo, 256, DMA, 256, blk - 16, tid);
    else if (blk < 272)  dev_prep(t, Wqkv, WqT, WqTbf, WkvT, blk - 80, tid);
    else if (blk < 1808) dev_trbf(t, W_ih, WihT, 2048, 768, blk - 272, tid);
    else if (blk < 2000) dev_trbf(t, W_hh, WhhT, 256, 768, blk - 1808, tid);
    else if (blk < 2064) dev_trbf(t, Wo, WoT, 256, 256, blk - 2000, tid);
    else if (blk < 2192) {
        int i = (blk - 2064) * 1024 + tid * 4;
        float4 v = *(const float4*)&prev_d[i];
        pdbf[i]     = __float2bfloat16(v.x);
        pdbf[i + 1] = __float2bfloat16(v.y);
        pdbf[i + 2] = __float2bfloat16(v.z);
        pdbf[i + 3] = __float2bfloat16(v.w);
    } else {
        // zero xasum_g (512*256 floats = 128 blocks * 1024)
        int i = (blk - 2192) * 1024 + tid * 4;
        *(float4*)&xasum_g[i] = (float4){0.f, 0.f, 0.f, 0.f};
    }
}

// ---------------------------------------------------------------------------
// K_mlp: FUSED MLP + K/V emit + xasum partial (R6).
// R5 structure (64 tok/block, 512 thr / 8 waves, nt=2) unchanged. New: the
// xa epilogue accumulates per-column sums of this block's 64 rows and
// atomicAdds into xasum_g[b][col]. Exactly 2 contributions per cell and fp
// add is commutative -> deterministic. Removes k_score's 67MB phase-1 pass.
// ---------------------------------------------------------------------------
__global__ void __launch_bounds__(512, 4) k_mlp(const float* __restrict__ x_obs,
        const short* __restrict__ W1Thi, const short* __restrict__ W1Tlo,
        const float* __restrict__ b1,
        const short* __restrict__ W2Thi, const short* __restrict__ W2Tlo,
        const float* __restrict__ b2, const float* __restrict__ a_prev,
        const short* __restrict__ WkvT, const float* __restrict__ bqkv,
        float* __restrict__ xa, float* __restrict__ xasum_g,
        __hip_bfloat16* __restrict__ kbf, __hip_bfloat16* __restrict__ vbfT) {
    __shared__ __attribute__((aligned(16))) short Hhi[64 * 256];
    __shared__ __attribute__((aligned(16))) short Hlo[64 * 256];
    const int m0 = blockIdx.x * 64;
    const int b = blockIdx.x >> 1;                 // batch
    const int tb0 = (blockIdx.x & 1) * 64;          // token base within batch
    const int tid = threadIdx.x;
    const int wave = tid >> 6, lane = tid & 63;     // wave in [0,8)
    const int quad = lane >> 4, l15 = lane & 15;
    const int n0 = wave * 32;                       // 32-col slice per wave

    // ---- GEMM1: h strip [64 tokens x 32 cols per wave] ----
    {
        bf16x8 Bh[2][2], Bl[2][2];
#pragma unroll
        for (int nt = 0; nt < 2; ++nt)
#pragma unroll
            for (int ks = 0; ks < 2; ++ks) {
                size_t o = (size_t)(n0 + nt * 16 + l15) * 64 + ks * 32 + quad * 8;
                Bh[nt][ks] = *(const bf16x8*)&W1Thi[o];
                Bl[nt][ks] = *(const bf16x8*)&W1Tlo[o];
            }
        f32x4 acc[4][2];
#pragma unroll
        for (int mt = 0; mt < 4; ++mt)
#pragma unroll
            for (int nt = 0; nt < 2; ++nt) acc[mt][nt] = (f32x4){0.f, 0.f, 0.f, 0.f};
#pragma unroll
        for (int mt = 0; mt < 4; ++mt) {
            bf16x8 Ah[2], Al[2];
#pragma unroll
            for (int ks = 0; ks < 2; ++ks) {
                const float* xp = &x_obs[(size_t)(m0 + mt * 16 + l15) * 64 + ks * 32 + quad * 8];
                float4 a0 = *(const float4*)xp;
                float4 a1 = *(const float4*)(xp + 4);
                bf16x8 h, l;
                h[0]=f2bf(a0.x); l[0]=f2bf(a0.x - bf2f(h[0]));
                h[1]=f2bf(a0.y); l[1]=f2bf(a0.y - bf2f(h[1]));
                h[2]=f2bf(a0.z); l[2]=f2bf(a0.z - bf2f(h[2]));
                h[3]=f2bf(a0.w); l[3]=f2bf(a0.w - bf2f(h[3]));
                h[4]=f2bf(a1.x); l[4]=f2bf(a1.x - bf2f(h[4]));
                h[5]=f2bf(a1.y); l[5]=f2bf(a1.y - bf2f(h[5]));
                h[6]=f2bf(a1.z); l[6]=f2bf(a1.z - bf2f(h[6]));
                h[7]=f2bf(a1.w); l[7]=f2bf(a1.w - bf2f(h[7]));
                Ah[ks] = h; Al[ks] = l;
            }
#pragma unroll
            for (int nt = 0; nt < 2; ++nt)
#pragma unroll
                for (int ks = 0; ks < 2; ++ks) {
                    acc[mt][nt] = __builtin_amdgcn_mfma_f32_16x16x32_bf16(Ah[ks], Bh[nt][ks], acc[mt][nt], 0, 0, 0);
                    acc[mt][nt] = __builtin_amdgcn_mfma_f32_16x16x32_bf16(Ah[ks], Bl[nt][ks], acc[mt][nt], 0, 0, 0);
                    acc[mt][nt] = __builtin_amdgcn_mfma_f32_16x16x32_bf16(Al[ks], Bh[nt][ks], acc[mt][nt], 0, 0, 0);
                }
        }
#pragma unroll
        for (int nt = 0; nt < 2; ++nt) {
            int col = n0 + nt * 16 + l15;
            float bias = b1[col];
#pragma unroll
            for (int mt = 0; mt < 4; ++mt)
#pragma unroll
                for (int r = 0; r < 4; ++r) {
                    int tl = mt * 16 + quad * 4 + r;       // local token
                    float tv = tanh_fast(acc[mt][nt][r] + bias);
                    short h = f2bf(tv);
                    Hhi[HSW(tl, col)] = h;
                    Hlo[HSW(tl, col)] = f2bf(tv - bf2f(h));
                }
        }
    }

    // ---- GEMM2: double-buffered B; k0=0 preload overlaps the barrier ----
    f32x4 acc[4][2];
#pragma unroll
    for (int mt = 0; mt < 4; ++mt)
#pragma unroll
        for (int nt = 0; nt < 2; ++nt) acc[mt][nt] = (f32x4){0.f, 0.f, 0.f, 0.f};

    bf16x8 Bh[2][2], Bl[2][2];
#pragma unroll
    for (int nt = 0; nt < 2; ++nt) {
        size_t o = (size_t)(n0 + nt * 16 + l15) * 256 + quad * 8;
        Bh[0][nt] = *(const bf16x8*)&W2Thi[o];
        Bl[0][nt] = *(const bf16x8*)&W2Tlo[o];
    }
    __syncthreads();

#pragma unroll
    for (int ki = 0; ki < 8; ++ki) {
        const int cur = ki & 1, nxt = cur ^ 1;
        if (ki < 7) {
            int k0n = (ki + 1) * 32;
#pragma unroll
            for (int nt = 0; nt < 2; ++nt) {
                size_t o = (size_t)(n0 + nt * 16 + l15) * 256 + k0n + quad * 8;
                Bh[nxt][nt] = *(const bf16x8*)&W2Thi[o];
                Bl[nxt][nt] = *(const bf16x8*)&W2Tlo[o];
            }
        }
        const int k0 = ki * 32;
#pragma unroll
        for (int mt = 0; mt < 4; ++mt) {
            bf16x8 Ah = *(bf16x8*)&Hhi[HSW(mt * 16 + l15, k0 + quad * 8)];
            bf16x8 Al = *(bf16x8*)&Hlo[HSW(mt * 16 + l15, k0 + quad * 8)];
#pragma unroll
            for (int nt = 0; nt < 2; ++nt) {
                acc[mt][nt] = __builtin_amdgcn_mfma_f32_16x16x32_bf16(Ah, Bh[cur][nt], acc[mt][nt], 0, 0, 0);
                acc[mt][nt] = __builtin_amdgcn_mfma_f32_16x16x32_bf16(Ah, Bl[cur][nt], acc[mt][nt], 0, 0, 0);
                acc[mt][nt] = __builtin_amdgcn_mfma_f32_16x16x32_bf16(Al, Bh[cur][nt], acc[mt][nt], 0, 0, 0);
            }
        }
    }

    // all waves finished READING Hhi/Hlo before we overwrite with Xbf
    __syncthreads();
    short* Xbf = Hhi;   // reuse: bf16 xa strip, swizzled [64][256]
    float colsum[2] = {0.f, 0.f};
#pragma unroll
    for (int nt = 0; nt < 2; ++nt) {
        int col = n0 + nt * 16 + l15;
        float bias = (col < DMA) ? b2[col] : 0.f;
#pragma unroll
        for (int mt = 0; mt < 4; ++mt)
#pragma unroll
            for (int r = 0; r < 4; ++r) {
                int tl = mt * 16 + quad * 4 + r;
                int token = m0 + tl;
                float v;
                if (col < DMA) v = acc[mt][nt][r] + bias;
                else           v = a_prev[(size_t)token * ACT_ + (col - DMA)];
                xa[(size_t)token * 256 + col] = v;
                Xbf[HSW(tl, col)] = f2bf(v);
                colsum[nt] += v;
            }
    }
    // xasum partial: reduce the 4 quads (rows), lane quad==0 atomically adds
    // the block's 64-row column sum. 2 blocks/batch, commutative -> exact.
#pragma unroll
    for (int nt = 0; nt < 2; ++nt) {
        float s = colsum[nt];
        s += __shfl_xor(s, 16);
        s += __shfl_xor(s, 32);
        if (quad == 0)
            atomicAdd(&xasum_g[(size_t)b * 256 + n0 + nt * 16 + l15], s);
    }

    // prefetch ntile0's FIRST half B panel (k=0..127) before the barrier
    bf16x8 bfv[4][2];
#pragma unroll
    for (int k8 = 0; k8 < 4; ++k8)
#pragma unroll
        for (int nf = 0; nf < 2; ++nf)
            bfv[k8][nf] = *(const bf16x8*)&WkvT[(size_t)(n0 + nf * 16 + l15) * 256
                                                + k8 * 32 + quad * 8];
    __syncthreads();

    // ---- GEMM3: K/V = Xbf @ WkvT + bkv. 8 waves x 2 ntiles x 32 cols.
    // B panel in 4-deep halves. Per-element k8 order 0..7 -> bit-identical.
    for (int ntile = 0; ntile < 2; ++ntile) {
        const int nbase = ntile * 256 + n0;
        f32x4 acc3[4][2];
#pragma unroll
        for (int nf = 0; nf < 2; ++nf) {
            float bias = bqkv[256 + nbase + nf * 16 + l15];
#pragma unroll
            for (int mt = 0; mt < 4; ++mt)
                acc3[mt][nf] = (f32x4){bias, bias, bias, bias};
        }
        // first half: k8 = 0..3 (bfv already loaded)
#pragma unroll
        for (int k8 = 0; k8 < 4; ++k8) {
            const int k0 = k8 * 32;
            bf16x8 af[4];
#pragma unroll
            for (int mt = 0; mt < 4; ++mt)
                af[mt] = *(bf16x8*)&Xbf[HSW(mt * 16 + l15, k0 + quad * 8)];
#pragma unroll
            for (int mt = 0; mt < 4; ++mt)
#pragma unroll
                for (int nf = 0; nf < 2; ++nf)
                    acc3[mt][nf] = __builtin_amdgcn_mfma_f32_16x16x32_bf16(
                        af[mt], bfv[k8][nf], acc3[mt][nf], 0, 0, 0);
        }
        // second half: load k=128..255 then k8 = 4..7
#pragma unroll
        for (int k8 = 0; k8 < 4; ++k8)
#pragma unroll
            for (int nf = 0; nf < 2; ++nf)
                bfv[k8][nf] = *(const bf16x8*)&WkvT[(size_t)(nbase + nf * 16 + l15) * 256
                                                    + 128 + k8 * 32 + quad * 8];
#pragma unroll
        for (int k8 = 0; k8 < 4; ++k8) {
            const int k0 = 128 + k8 * 32;
            bf16x8 af[4];
#pragma unroll
            for (int mt = 0; mt < 4; ++mt)
                af[mt] = *(bf16x8*)&Xbf[HSW(mt * 16 + l15, k0 + quad * 8)];
#pragma unroll
            for (int mt = 0; mt < 4; ++mt)
#pragma unroll
                for (int nf = 0; nf < 2; ++nf)
                    acc3[mt][nf] = __builtin_amdgcn_mfma_f32_16x16x32_bf16(
                        af[mt], bfv[k8][nf], acc3[mt][nf], 0, 0, 0);
        }
        // prefetch next ntile's first half before the store tail
        if (ntile < 1) {
            const int nb2 = 256 + n0;
#pragma unroll
            for (int k8 = 0; k8 < 4; ++k8)
#pragma unroll
                for (int nf = 0; nf < 2; ++nf)
                    bfv[k8][nf] = *(const bf16x8*)&WkvT[(size_t)(nb2 + nf * 16 + l15) * 256
                                                        + k8 * 32 + quad * 8];
        }
#pragma unroll
        for (int nf = 0; nf < 2; ++nf) {
            int n_g = nbase + nf * 16 + l15;
            if (n_g < 256) {
#pragma unroll
                for (int mt = 0; mt < 4; ++mt)
#pragma unroll
                    for (int r = 0; r < 4; ++r) {
                        int token = tb0 + mt * 16 + quad * 4 + r;
                        kbf[((size_t)b * SS + token) * 256 + n_g] = __float2bfloat16(acc3[mt][nf][r]);
                    }
            } else {
                // transposed V: 4 consecutive tokens -> one aligned 8B store
#pragma unroll
                for (int mt = 0; mt < 4; ++mt) {
                    short4v pv;
#pragma unroll
                    for (int r = 0; r < 4; ++r) pv[r] = f2bf(acc3[mt][nf][r]);
                    *(short4v*)((short*)vbfT + ((size_t)b * 256 + (n_g - 256)) * SS
                                + tb0 + mt * 16 + quad * 4) = pv;
                }
            }
        }
    }
}

// ---------------------------------------------------------------------------
// K_score (R6): xasum comes precomputed from k_mlp (saves the 67MB phase-1
// pass). bqdot and the 0.125 scale are dropped: scores feed ONLY a top-k
// index selection, and adding a per-batch constant / positive scaling is a
// monotone transform -> identical indices (ties shift equally too).
// ---------------------------------------------------------------------------
__global__ void __launch_bounds__(256) k_score(const float* __restrict__ xa,
        const float* __restrict__ xasum_g,
        const float* __restrict__ Wqkv, const float* __restrict__ WqT,
        const float* __restrict__ bqkv, int* __restrict__ idxb) {
    __shared__ float xasum_sh[256];
    __shared__ float ksum_sh[256];
    __shared__ float wqk_sh[256];
    __shared__ double ssd[128];
    const int b = blockIdx.x;
    const int tid = threadIdx.x;
    const float* xab = xa + (size_t)b * SS * DD;

    xasum_sh[tid] = xasum_g[(size_t)b * 256 + tid];
    __syncthreads();

    float ks = 128.f * bqkv[256 + tid];
    for (int d = 0; d < 256; ++d)
        ks = fmaf(xasum_sh[d], Wqkv[(size_t)d * D3 + 256 + tid], ks);
    ksum_sh[tid] = ks;
    __syncthreads();

    float wq = 0.f;
    for (int c = 0; c < 256; ++c)
        wq = fmaf(WqT[(size_t)c * 256 + tid], ksum_sh[c], wq);
    wqk_sh[tid] = wq;
    __syncthreads();

    // row dots: wave w rows [w*32, w*32+32); lane l covers cols 4l..4l+3.
    {
        const int wv = tid >> 6, lane = tid & 63;
#pragma unroll 4
        for (int rr = 0; rr < 32; ++rr) {
            int r = wv * 32 + rr;
            float4 x4 = *(const float4*)&xab[(size_t)r * 256 + lane * 4];
            const float* w4 = wqk_sh + lane * 4;
            double p = (double)x4.x * (double)w4[0];
            p += (double)x4.y * (double)w4[1];
            p += (double)x4.z * (double)w4[2];
            p += (double)x4.w * (double)w4[3];
#pragma unroll
            for (int off = 1; off < 64; off <<= 1) p += __shfl_xor(p, off);
            if (lane == 0) ssd[r] = p;
        }
    }
    __syncthreads();
    if (tid < 64) {
        double v0 = ssd[tid], v1 = ssd[tid + 64];
        int i0 = tid, i1 = tid + 64;
        bool t0 = false, t1 = false;
        for (int t = 0; t < TOPK; ++t) {
            double c0 = t0 ? -1e300 : v0;
            double c1 = t1 ? -1e300 : v1;
            double bvv; int bi;
            if (c1 > c0) { bvv = c1; bi = i1; } else { bvv = c0; bi = i0; }
#pragma unroll
            for (int off = 1; off < 64; off <<= 1) {
                double ov = __shfl_xor(bvv, off);
                int oi = __shfl_xor(bi, off);
                if (ov > bvv || (ov == bvv && oi < bi)) { bvv = ov; bi = oi; }
            }
            if (tid == 0) idxb[b * TOPK + t] = bi;
            if (bi == i0) t0 = true;
            if (bi == i1) t1 = true;
        }
    }
}

// ---------------------------------------------------------------------------
// K_attn2: gather + q-projection + attention fused, per batch. Wave = head.
// ---------------------------------------------------------------------------
__global__ void __launch_bounds__(256) k_attn2(const float* __restrict__ xa,
        const int* __restrict__ idxb, const short* __restrict__ WqTbf,
        const float* __restrict__ bqkv,
        const short* __restrict__ kbf, const short* __restrict__ vbfT,
        short* __restrict__ Ctx) {
    __shared__ __attribute__((aligned(16))) short Xsh[16 * 264];
    __shared__ __attribute__((aligned(16))) short Qsh[16 * 264];
    __shared__ short Pbuf[4][16 * 136];
    __shared__ int sidx[8];
    const int b = blockIdx.x;
    const int tid = threadIdx.x;
    const int h = tid >> 6, lane = tid & 63;
    const int quad = lane >> 4, l15 = lane & 15;

    if (tid < 8) sidx[tid] = idxb[b * TOPK + tid];
    __syncthreads();
#pragma unroll
    for (int t = 0; t < 16; ++t) {
        short v = 0;
        if (t < 8) v = f2bf(xa[((size_t)b * SS + sidx[t]) * 256 + tid]);
        Xsh[t * 264 + tid] = v;
    }
    __syncthreads();

    {
        f32x4 qacc[4];
#pragma unroll
        for (int nt = 0; nt < 4; ++nt) qacc[nt] = (f32x4){0.f, 0.f, 0.f, 0.f};
#pragma unroll
        for (int ki = 0; ki < 8; ++ki) {
            int k0 = ki * 32;
            bf16x8 Ax = *(bf16x8*)&Xsh[l15 * 264 + k0 + quad * 8];
#pragma unroll
            for (int nt = 0; nt < 4; ++nt) {
                int col = h * 64 + nt * 16 + l15;
                bf16x8 Bq = *(const bf16x8*)&WqTbf[(size_t)col * 256 + k0 + quad * 8];
                qacc[nt] = __builtin_amdgcn_mfma_f32_16x16x32_bf16(Ax, Bq, qacc[nt], 0, 0, 0);
            }
        }
#pragma unroll
        for (int nt = 0; nt < 4; ++nt) {
            int col = h * 64 + nt * 16 + l15;
            float bq = bqkv[col];
#pragma unroll
            for (int r = 0; r < 4; ++r)
                Qsh[(quad * 4 + r) * 264 + col] = f2bf(qacc[nt][r] + bq);
        }
    }
    // Qsh strip is wave-local — no barrier needed.

    const short* kb = kbf + (size_t)b * SS * 256 + h * 64;
    const short* vb = vbfT + ((size_t)b * 256 + h * 64) * SS;

    bf16x8 aq[2];
#pragma unroll
    for (int ks = 0; ks < 2; ++ks)
        aq[ks] = *(bf16x8*)&Qsh[l15 * 264 + h * 64 + ks * 32 + quad * 8];
    f32x4 sc[8];
#pragma unroll
    for (int nt = 0; nt < 8; ++nt) sc[nt] = (f32x4){0.f, 0.f, 0.f, 0.f};
#pragma unroll
    for (int nt = 0; nt < 8; ++nt)
#pragma unroll
        for (int ks = 0; ks < 2; ++ks) {
            bf16x8 bk = *(const bf16x8*)&kb[(size_t)(nt * 16 + l15) * 256 + ks * 32 + quad * 8];
            sc[nt] = __builtin_amdgcn_mfma_f32_16x16x32_bf16(aq[ks], bk, sc[nt], 0, 0, 0);
        }
#pragma unroll
    for (int r = 0; r < 4; ++r) {
        float m = -3.4e38f;
#pragma unroll
        for (int nt = 0; nt < 8; ++nt) m = fmaxf(m, sc[nt][r]);
        m = fmaxf(m, __shfl_xor(m, 1));
        m = fmaxf(m, __shfl_xor(m, 2));
        m = fmaxf(m, __shfl_xor(m, 4));
        m = fmaxf(m, __shfl_xor(m, 8));
        float s = 0.f;
#pragma unroll
        for (int nt = 0; nt < 8; ++nt) {
            float e = __expf((sc[nt][r] - m) * 0.125f);
            sc[nt][r] = e;
            s += e;
        }
        s += __shfl_xor(s, 1);
        s += __shfl_xor(s, 2);
        s += __shfl_xor(s, 4);
        s += __shfl_xor(s, 8);
        float inv = 1.f / s;
        int row = quad * 4 + r;
#pragma unroll
        for (int nt = 0; nt < 8; ++nt)
            Pbuf[h][row * 136 + nt * 16 + l15] = f2bf(sc[nt][r] * inv);
    }
    __syncthreads();
    bf16x8 ap[4];
#pragma unroll
    for (int ks = 0; ks < 4; ++ks)
        ap[ks] = *(bf16x8*)&Pbuf[h][l15 * 136 + ks * 32 + quad * 8];
    f32x4 ct[4];
#pragma unroll
    for (int nt = 0; nt < 4; ++nt) ct[nt] = (f32x4){0.f, 0.f, 0.f, 0.f};
#pragma unroll
    for (int nt = 0; nt < 4; ++nt)
#pragma unroll
        for (int ks = 0; ks < 4; ++ks) {
            bf16x8 bv = *(const bf16x8*)&vb[(size_t)(nt * 16 + l15) * SS + ks * 32 + quad * 8];
            ct[nt] = __builtin_amdgcn_mfma_f32_16x16x32_bf16(ap[ks], bv, ct[nt], 0, 0, 0);
        }
#pragma unroll
    for (int nt = 0; nt < 4; ++nt)
#pragma unroll
        for (int r = 0; r < 4; ++r)
            Ctx[((size_t)b * 16 + quad * 4 + r) * 256 + h * 64 + nt * 16 + l15] =
                f2bf(ct[nt][r]);
}

// ---------------------------------------------------------------------------
// K_omm: resh = Ctx @ WoT^T + bo. Writes fp32 resh (d_out) + bf16 resh_bf.
// ---------------------------------------------------------------------------
__global__ void __launch_bounds__(256) k_omm(const short* __restrict__ A,
        const short* __restrict__ BT, const float* __restrict__ bias,
        float* __restrict__ resh_out, __hip_bfloat16* __restrict__ resh_bf) {
    __shared__ __attribute__((aligned(16))) short Ash[128 * 72];
    __shared__ __attribute__((aligned(16))) short Bsh[128 * 72];
    const int mt = blockIdx.x >> 1, nt2 = blockIdx.x & 1;
    const int m0 = mt * 128, n0 = nt2 * 128;
    const int tid = threadIdx.x;
    const int wave = tid >> 6, lane = tid & 63;
    const int wm = wave >> 1, wn = wave & 1;
    const int quad = lane >> 4, l15 = lane & 15;

    f32x4 acc[4][4];
#pragma unroll
    for (int tm = 0; tm < 4; ++tm)
#pragma unroll
        for (int tn = 0; tn < 4; ++tn) acc[tm][tn] = (f32x4){0.f, 0.f, 0.f, 0.f};

    for (int k0 = 0; k0 < 256; k0 += 64) {
        __syncthreads();
#pragma unroll
        for (int it = 0; it < 4; ++it) {
            int idx = it * 256 + tid;
            int row = idx >> 3, c8 = idx & 7;
            *(uint4*)&Ash[row * 72 + c8 * 8] =
                *(const uint4*)&A[(size_t)(m0 + row) * 256 + k0 + c8 * 8];
            *(uint4*)&Bsh[row * 72 + c8 * 8] =
                *(const uint4*)&BT[(size_t)(n0 + row) * 256 + k0 + c8 * 8];
        }
        __syncthreads();
#pragma unroll
        for (int ks = 0; ks < 2; ++ks) {
            bf16x8 af[4], bfr[4];
#pragma unroll
            for (int t = 0; t < 4; ++t) {
                af[t]  = *(bf16x8*)&Ash[(wm * 64 + t * 16 + l15) * 72 + ks * 32 + quad * 8];
                bfr[t] = *(bf16x8*)&Bsh[(wn * 64 + t * 16 + l15) * 72 + ks * 32 + quad * 8];
            }
#pragma unroll
            for (int tm = 0; tm < 4; ++tm)
#pragma unroll
                for (int tn = 0; tn < 4; ++tn)
                    acc[tm][tn] = __builtin_amdgcn_mfma_f32_16x16x32_bf16(
                        af[tm], bfr[tn], acc[tm][tn], 0, 0, 0);
        }
    }
#pragma unroll
    for (int tm = 0; tm < 4; ++tm)
#pragma unroll
        for (int tn = 0; tn < 4; ++tn) {
            int col = n0 + wn * 64 + tn * 16 + l15;
            float bv = bias[col];
#pragma unroll
            for (int r = 0; r < 4; ++r) {
                int row = m0 + wm * 64 + tm * 16 + quad * 4 + r;
                int bidx = row >> 4, r16 = row & 15;
                if (r16 < 8) {
                    float v = acc[tm][tn][r] + bv;
                    size_t o = (size_t)bidx * 2048 + r16 * 256 + col;
                    resh_out[o] = v;
                    resh_bf[o] = __float2bfloat16(v);
                }
            }
        }
}

// ---------------------------------------------------------------------------
// K_gru2: GRU GEMMs with split-K on the K=2048 input GEMM.
// blocks [0,96): gi partials; blocks [96,120): gh (K=256).
// ---------------------------------------------------------------------------
__global__ void __launch_bounds__(256) k_gru2(const __hip_bfloat16* __restrict__ resh_bf,
        const __hip_bfloat16* __restrict__ WihT, const __hip_bfloat16* __restrict__ pdbf,
        const __hip_bfloat16* __restrict__ WhhT, float* __restrict__ gip,
        float* __restrict__ gh) {
    __shared__ __attribute__((aligned(16))) short Ash[128 * 72];
    __shared__ __attribute__((aligned(16))) short Bsh[128 * 72];
    int blk = blockIdx.x;
    const __hip_bfloat16 *A, *BT;
    float* C;
    int K, kbeg, kend;
    if (blk < 96) {
        int chunk = blk / 24; blk %= 24;
        A = resh_bf; BT = WihT; C = gip + (size_t)chunk * 512 * 768;
        K = 2048; kbeg = chunk * 512; kend = kbeg + 512;
    } else {
        blk -= 96; A = pdbf; BT = WhhT; C = gh; K = 256; kbeg = 0; kend = 256;
    }
    const int mt = blk / 6, nt = blk % 6;
    const int m0 = mt * 128, n0 = nt * 128;
    const int tid = threadIdx.x;
    const int wave = tid >> 6, lane = tid & 63;
    const int wm = wave >> 1, wn = wave & 1;
    const int quad = lane >> 4, l15 = lane & 15;

    f32x4 acc[4][4];
#pragma unroll
    for (int tm = 0; tm < 4; ++tm)
#pragma unroll
        for (int tn = 0; tn < 4; ++tn)
            acc[tm][tn] = (f32x4){0.f, 0.f, 0.f, 0.f};

    for (int k0 = kbeg; k0 < kend; k0 += 64) {
        __syncthreads();
#pragma unroll
        for (int it = 0; it < 4; ++it) {
            int idx = it * 256 + tid;
            int row = idx >> 3, c8 = idx & 7;
            *(uint4*)&Ash[row * 72 + c8 * 8] =
                *(const uint4*)&A[(size_t)(m0 + row) * K + k0 + c8 * 8];
            *(uint4*)&Bsh[row * 72 + c8 * 8] =
                *(const uint4*)&BT[(size_t)(n0 + row) * K + k0 + c8 * 8];
        }
        __syncthreads();
#pragma unroll
        for (int ks = 0; ks < 2; ++ks) {
            bf16x8 af[4], bfr[4];
#pragma unroll
            for (int t = 0; t < 4; ++t) {
                af[t]  = *(bf16x8*)&Ash[(wm * 64 + t * 16 + l15) * 72 + ks * 32 + quad * 8];
                bfr[t] = *(bf16x8*)&Bsh[(wn * 64 + t * 16 + l15) * 72 + ks * 32 + quad * 8];
            }
#pragma unroll
            for (int tm = 0; tm < 4; ++tm)
#pragma unroll
                for (int tn = 0; tn < 4; ++tn)
                    acc[tm][tn] = __builtin_amdgcn_mfma_f32_16x16x32_bf16(
                        af[tm], bfr[tn], acc[tm][tn], 0, 0, 0);
        }
    }
#pragma unroll
    for (int tm = 0; tm < 4; ++tm)
#pragma unroll
        for (int tn = 0; tn < 4; ++tn) {
            int col = n0 + wn * 64 + tn * 16 + l15;
#pragma unroll
            for (int r = 0; r < 4; ++r) {
                int row = m0 + wm * 64 + tm * 16 + quad * 4 + r;
                C[(size_t)row * 768 + col] = acc[tm][tn][r];
            }
        }
}

// ---------------------------------------------------------------------------
// K_gruact: gates elementwise. newd = (1-z)*n + z*prev_d. Sums the 4 split-K
// gi partials in fixed order (deterministic).
// ---------------------------------------------------------------------------
__global__ void k_gruact(const float* __restrict__ gip, const float* __restrict__ gh,
                         const float* __restrict__ b_ih, const float* __restrict__ b_hh,
                         const float* __restrict__ prev_d, float* __restrict__ newd) {
    const int b = blockIdx.x, tid = threadIdx.x;
    const size_t SZ = (size_t)512 * 768;
    const float* g0 = gip + (size_t)b * D3;
    const float* ghb = gh + (size_t)b * D3;
    float ir = ((g0[tid] + g0[SZ + tid]) + g0[2 * SZ + tid]) + g0[3 * SZ + tid] + b_ih[tid];
    float iz = ((g0[256 + tid] + g0[SZ + 256 + tid]) + g0[2 * SZ + 256 + tid]) + g0[3 * SZ + 256 + tid] + b_ih[256 + tid];
    float in = ((g0[512 + tid] + g0[SZ + 512 + tid]) + g0[2 * SZ + 512 + tid]) + g0[3 * SZ + 512 + tid] + b_ih[512 + tid];
    float hr = ghb[tid] + b_hh[tid];
    float hz = ghb[256 + tid] + b_hh[256 + tid];
    float hn = ghb[512 + tid] + b_hh[512 + tid];
    float pd = prev_d[(size_t)b * 256 + tid];
    float r = 1.f / (1.f + __expf(-(ir + hr)));
    float z = 1.f / (1.f + __expf(-(iz + hz)));
    float n = tanhf(in + r * hn);
    newd[(size_t)b * 256 + tid] = (1.f - z) * n + z * pd;
}

// ---------------------------------------------------------------------------
extern "C" void kernel_launch(void* const* d_in, const int* in_sizes, int n_in,
                              void* d_out, int out_size, void* d_ws, size_t ws_size,
                              hipStream_t stream) {
    const float* prev_d = (const float*)d_in[0];
    const float* x_obs  = (const float*)d_in[1];
    const float* a_prev = (const float*)d_in[2];
    const float* W1     = (const float*)d_in[3];
    const float* b1     = (const float*)d_in[4];
    const float* W2     = (const float*)d_in[5];
    const float* b2     = (const float*)d_in[6];
    const float* Wqkv   = (const float*)d_in[7];
    const float* bqkv   = (const float*)d_in[8];
    const float* Wo     = (const float*)d_in[9];
    const float* bo     = (const float*)d_in[10];
    const float* W_ih   = (const float*)d_in[11];
    const float* b_ih   = (const float*)d_in[12];
    const float* W_hh   = (const float*)d_in[13];
    const float* b_hh   = (const float*)d_in[14];
    float* out = (float*)d_out;

    const size_t NT = (size_t)BB * SS * DD;   // 16,777,216
    // region 1: xa fp32 (67 MB)
    float* xa = (float*)d_ws;
    // region 2 (67 MB): [kbf|vbfT]; late GRU bufs alias kbf AFTER k_attn2
    short* hkv = (short*)(xa + NT);
    __hip_bfloat16* kbf = (__hip_bfloat16*)hkv;
    __hip_bfloat16* vbfT = (__hip_bfloat16*)(hkv + NT);
    char* r2late = (char*)hkv;
    __hip_bfloat16* resh_bf = (__hip_bfloat16*)r2late;                // 2,097,152
    float* gip = (float*)(r2late + 2359296);                          // 4x 512x768 fp32 = 6,291,456
    float* gh  = (float*)(r2late + 2359296 + 6291456);                // 1,572,864
    // region 3 (16.8 MB): attn-phase buffers
    short* xsp = hkv + 2 * NT;
    char* late = (char*)xsp;
    __hip_bfloat16* WihT = (__hip_bfloat16*)late;                     // 3,145,728
    __hip_bfloat16* WhhT = (__hip_bfloat16*)(late + 3145728);         //   393,216
    __hip_bfloat16* WoT  = (__hip_bfloat16*)(late + 3538944);         //   131,072
    short* WqTbf = (short*)(late + 3670016);                          //   131,072
    short* Ctx   = (short*)(late + 3801088);                          // 4,194,304
    // region 4: persistent small (never aliased)
    short* fixed = xsp + 2 * (size_t)NTOK * 64;
    short* W1Thi = fixed;                    // 16384
    short* W1Tlo = W1Thi + 16384;
    short* W2Thi = W1Tlo + 16384;            // 65536
    short* W2Tlo = W2Thi + 65536;
    float* WqT = (float*)(W2Tlo + 65536);    // 65536 floats
    __hip_bfloat16* WkvT = (__hip_bfloat16*)(WqT + 65536);  // 131072
    int* idxb = (int*)(WkvT + 131072);                      // 4096 ints
    __hip_bfloat16* pdbf = (__hip_bfloat16*)(idxb + 4096);  // 131072 bf16
    float* xasum_g = (float*)(pdbf + 131072);               // 512*256 fp32 = 524,288 B

    float* newd = out;                       // [B, D]
    float* resh = out + (size_t)BB * DD;     // [B, TOPK*D]

    k_prepall <<<2320, 256, 0, stream>>>(W1, W1Thi, W1Tlo, W2, W2Thi, W2Tlo,
                                         Wqkv, WqT, WqTbf, WkvT,
                                         W_ih, WihT, W_hh, WhhT, Wo, WoT,
                                         prev_d, pdbf, xasum_g);
    k_mlp     <<<NTOK / 64, 512, 0, stream>>>(x_obs, W1Thi, W1Tlo, b1,
                                              W2Thi, W2Tlo, b2, a_prev,
                                              (const short*)WkvT, bqkv,
                                              xa, xasum_g, kbf, vbfT);
    k_score   <<<BB, 256, 0, stream>>>(xa, xasum_g, Wqkv, WqT, bqkv, idxb);
    k_attn2   <<<BB, 256, 0, stream>>>(xa, idxb, WqTbf, bqkv,
                                       (const short*)kbf, (const short*)vbfT, Ctx);
    k_omm     <<<128, 256, 0, stream>>>(Ctx, (const short*)WoT, bo, resh, resh_bf);
    k_gru2    <<<120, 256, 0, stream>>>(resh_bf, WihT, pdbf, WhhT, gip, gh);
    k_gruact  <<<BB, 256, 0, stream>>>(gip, gh, b_ih, b_hh, prev_d, newd);
}

// Round 7
// 315.699 us; speedup vs baseline: 1.0018x; 1.0018x over previous
//
#include <hip/hip_runtime.h>
#include <hip/hip_bf16.h>
#include <math.h>

#define BB 512
#define SS 128
#define DD 256
#define HH 4
#define TOPK 8
#define D3 768
#define DMA 248
#define ACT_ 8
#define NTOK 65536            // B*S

typedef __attribute__((ext_vector_type(8))) short bf16x8;
typedef __attribute__((ext_vector_type(4))) short short4v;
typedef __attribute__((ext_vector_type(4))) float f32x4;

static __device__ __forceinline__ short f2bf(float x) {
    __hip_bfloat16 h = __float2bfloat16(x);
    return *reinterpret_cast<short*>(&h);
}
static __device__ __forceinline__ float bf2f(short s) {
    __hip_bfloat16 h = *reinterpret_cast<__hip_bfloat16*>(&s);
    return __bfloat162float(h);
}
static __device__ __forceinline__ float tanh_fast(float x) {
    float e = __expf(2.f * x);
    return 1.f - 2.f / (e + 1.f);
}

// Swizzled LDS index for the [64][256]-short H/X strips: XOR row bits into the
// 16B-unit bits of col. Keeps bf16x8 groups contiguous (XOR bits >= 3 only).
#define HSW(r, c) ((r) * 256 + ((c) ^ (((r) & 7) << 3)))

// ---------------------------------------------------------------------------
// device helpers for the merged prep kernel
// ---------------------------------------------------------------------------
__device__ __forceinline__ void dev_wsplit(float (*t)[33], const float* src,
        short* dhi, short* dlo, int R, int C, int Cpad, int blk, int tid) {
    const int ctiles = Cpad >> 5;
    const int rt = blk / ctiles, ct = blk % ctiles;
    const int r0 = rt * 32, c0 = ct * 32;
#pragma unroll
    for (int i = 0; i < 4; ++i) {
        int idx = i * 256 + tid;
        int lr = idx >> 5, lc = idx & 31;
        t[lr][lc] = (c0 + lc < C) ? src[(size_t)(r0 + lr) * C + c0 + lc] : 0.f;
    }
    __syncthreads();
#pragma unroll
    for (int i = 0; i < 4; ++i) {
        int idx = i * 256 + tid;
        int lc = idx >> 5, lr = idx & 31;
        float v = t[lr][lc];
        short h = f2bf(v);
        size_t o = (size_t)(c0 + lc) * R + r0 + lr;
        dhi[o] = h;
        dlo[o] = f2bf(v - bf2f(h));
    }
}

__device__ __forceinline__ void dev_trbf(float (*t)[33], const float* src,
        __hip_bfloat16* dst, int R, int C, int blk, int tid) {
    const int ctiles = C >> 5;
    const int rt = blk / ctiles, ct = blk % ctiles;
    const int r0 = rt * 32, c0 = ct * 32;
#pragma unroll
    for (int i = 0; i < 4; ++i) {
        int idx = i * 256 + tid;
        int lr = idx >> 5, lc = idx & 31;
        t[lr][lc] = src[(size_t)(r0 + lr) * C + c0 + lc];
    }
    __syncthreads();
#pragma unroll
    for (int i = 0; i < 4; ++i) {
        int idx = i * 256 + tid;
        int lc = idx >> 5, lr = idx & 31;
        dst[(size_t)(c0 + lc) * R + r0 + lr] = __float2bfloat16(t[lr][lc]);
    }
}

__device__ __forceinline__ void dev_prep(float (*t)[33], const float* Wqkv,
        float* WqT, short* WqTbf, __hip_bfloat16* WkvT, int blk, int tid) {
    const int rt = blk / 24, ct = blk % 24;
    const int r0 = rt * 32, c0 = ct * 32;
#pragma unroll
    for (int i = 0; i < 4; ++i) {
        int idx = i * 256 + tid;
        int lr = idx >> 5, lc = idx & 31;
        t[lr][lc] = Wqkv[(size_t)(r0 + lr) * D3 + c0 + lc];
    }
    __syncthreads();
#pragma unroll
    for (int i = 0; i < 4; ++i) {
        int idx = i * 256 + tid;
        int lc = idx >> 5, lr = idx & 31;
        float v = t[lr][lc];
        int c = c0 + lc, r = r0 + lr;
        if (c < 256) {
            WqT[(size_t)c * 256 + r] = v;
            WqTbf[(size_t)c * 256 + r] = f2bf(v);
        } else {
            WkvT[(size_t)(c - 256) * 256 + r] = __float2bfloat16(v);
        }
    }
}

// ---------------------------------------------------------------------------
// K_prepall: all weight transposes/splits + pdcast in ONE launch.
// ---------------------------------------------------------------------------
__global__ void __launch_bounds__(256) k_prepall(
        const float* __restrict__ W1, short* __restrict__ W1Thi, short* __restrict__ W1Tlo,
        const float* __restrict__ W2, short* __restrict__ W2Thi, short* __restrict__ W2Tlo,
        const float* __restrict__ Wqkv, float* __restrict__ WqT, short* __restrict__ WqTbf,
        __hip_bfloat16* __restrict__ WkvT,
        const float* __restrict__ W_ih, __hip_bfloat16* __restrict__ WihT,
        const float* __restrict__ W_hh, __hip_bfloat16* __restrict__ WhhT,
        const float* __restrict__ Wo, __hip_bfloat16* __restrict__ WoT,
        const float* __restrict__ prev_d, __hip_bfloat16* __restrict__ pdbf) {
    __shared__ float t[32][33];
    const int blk = blockIdx.x, tid = threadIdx.x;
    if (blk < 16)        dev_wsplit(t, W1, W1Thi, W1Tlo, 64, 256, 256, blk, tid);
    else if (blk < 80)   dev_wsplit(t, W2, W2Thi, W2Tlo, 256, DMA, 256, blk - 16, tid);
    else if (blk < 272)  dev_prep(t, Wqkv, WqT, WqTbf, WkvT, blk - 80, tid);
    else if (blk < 1808) dev_trbf(t, W_ih, WihT, 2048, 768, blk - 272, tid);
    else if (blk < 2000) dev_trbf(t, W_hh, WhhT, 256, 768, blk - 1808, tid);
    else if (blk < 2064) dev_trbf(t, Wo, WoT, 256, 256, blk - 2000, tid);
    else {
        int i = (blk - 2064) * 1024 + tid * 4;
        float4 v = *(const float4*)&prev_d[i];
        pdbf[i]     = __float2bfloat16(v.x);
        pdbf[i + 1] = __float2bfloat16(v.y);
        pdbf[i + 2] = __float2bfloat16(v.z);
        pdbf[i + 3] = __float2bfloat16(v.w);
    }
}

// ---------------------------------------------------------------------------
// K_mlp: FUSED MLP + K/V emit + xasum partial (R7).
// R6 post-mortem: atomicAdd xasum fusion cost +24MB FETCH/WRITE per dispatch
// (cross-XCD atomic RMW traffic, guide G16) -> k_mlp 126->140us. R7 keeps the
// fusion but each (batch,half) partial goes to its OWN slot xasum_p[half][b]
// with plain coalesced stores (64 stores/block, no RMW). k_score sums the
// two slots in fixed order -> deterministic.
// ---------------------------------------------------------------------------
__global__ void __launch_bounds__(512, 4) k_mlp(const float* __restrict__ x_obs,
        const short* __restrict__ W1Thi, const short* __restrict__ W1Tlo,
        const float* __restrict__ b1,
        const short* __restrict__ W2Thi, const short* __restrict__ W2Tlo,
        const float* __restrict__ b2, const float* __restrict__ a_prev,
        const short* __restrict__ WkvT, const float* __restrict__ bqkv,
        float* __restrict__ xa, float* __restrict__ xasum_p,
        __hip_bfloat16* __restrict__ kbf, __hip_bfloat16* __restrict__ vbfT) {
    __shared__ __attribute__((aligned(16))) short Hhi[64 * 256];
    __shared__ __attribute__((aligned(16))) short Hlo[64 * 256];
    const int m0 = blockIdx.x * 64;
    const int b = blockIdx.x >> 1;                 // batch
    const int half = blockIdx.x & 1;
    const int tb0 = half * 64;                      // token base within batch
    const int tid = threadIdx.x;
    const int wave = tid >> 6, lane = tid & 63;     // wave in [0,8)
    const int quad = lane >> 4, l15 = lane & 15;
    const int n0 = wave * 32;                       // 32-col slice per wave

    // ---- GEMM1: h strip [64 tokens x 32 cols per wave] ----
    {
        bf16x8 Bh[2][2], Bl[2][2];
#pragma unroll
        for (int nt = 0; nt < 2; ++nt)
#pragma unroll
            for (int ks = 0; ks < 2; ++ks) {
                size_t o = (size_t)(n0 + nt * 16 + l15) * 64 + ks * 32 + quad * 8;
                Bh[nt][ks] = *(const bf16x8*)&W1Thi[o];
                Bl[nt][ks] = *(const bf16x8*)&W1Tlo[o];
            }
        f32x4 acc[4][2];
#pragma unroll
        for (int mt = 0; mt < 4; ++mt)
#pragma unroll
            for (int nt = 0; nt < 2; ++nt) acc[mt][nt] = (f32x4){0.f, 0.f, 0.f, 0.f};
#pragma unroll
        for (int mt = 0; mt < 4; ++mt) {
            bf16x8 Ah[2], Al[2];
#pragma unroll
            for (int ks = 0; ks < 2; ++ks) {
                const float* xp = &x_obs[(size_t)(m0 + mt * 16 + l15) * 64 + ks * 32 + quad * 8];
                float4 a0 = *(const float4*)xp;
                float4 a1 = *(const float4*)(xp + 4);
                bf16x8 h, l;
                h[0]=f2bf(a0.x); l[0]=f2bf(a0.x - bf2f(h[0]));
                h[1]=f2bf(a0.y); l[1]=f2bf(a0.y - bf2f(h[1]));
                h[2]=f2bf(a0.z); l[2]=f2bf(a0.z - bf2f(h[2]));
                h[3]=f2bf(a0.w); l[3]=f2bf(a0.w - bf2f(h[3]));
                h[4]=f2bf(a1.x); l[4]=f2bf(a1.x - bf2f(h[4]));
                h[5]=f2bf(a1.y); l[5]=f2bf(a1.y - bf2f(h[5]));
                h[6]=f2bf(a1.z); l[6]=f2bf(a1.z - bf2f(h[6]));
                h[7]=f2bf(a1.w); l[7]=f2bf(a1.w - bf2f(h[7]));
                Ah[ks] = h; Al[ks] = l;
            }
#pragma unroll
            for (int nt = 0; nt < 2; ++nt)
#pragma unroll
                for (int ks = 0; ks < 2; ++ks) {
                    acc[mt][nt] = __builtin_amdgcn_mfma_f32_16x16x32_bf16(Ah[ks], Bh[nt][ks], acc[mt][nt], 0, 0, 0);
                    acc[mt][nt] = __builtin_amdgcn_mfma_f32_16x16x32_bf16(Ah[ks], Bl[nt][ks], acc[mt][nt], 0, 0, 0);
                    acc[mt][nt] = __builtin_amdgcn_mfma_f32_16x16x32_bf16(Al[ks], Bh[nt][ks], acc[mt][nt], 0, 0, 0);
                }
        }
#pragma unroll
        for (int nt = 0; nt < 2; ++nt) {
            int col = n0 + nt * 16 + l15;
            float bias = b1[col];
#pragma unroll
            for (int mt = 0; mt < 4; ++mt)
#pragma unroll
                for (int r = 0; r < 4; ++r) {
                    int tl = mt * 16 + quad * 4 + r;       // local token
                    float tv = tanh_fast(acc[mt][nt][r] + bias);
                    short h = f2bf(tv);
                    Hhi[HSW(tl, col)] = h;
                    Hlo[HSW(tl, col)] = f2bf(tv - bf2f(h));
                }
        }
    }

    // ---- GEMM2: double-buffered B; k0=0 preload overlaps the barrier ----
    f32x4 acc[4][2];
#pragma unroll
    for (int mt = 0; mt < 4; ++mt)
#pragma unroll
        for (int nt = 0; nt < 2; ++nt) acc[mt][nt] = (f32x4){0.f, 0.f, 0.f, 0.f};

    bf16x8 Bh[2][2], Bl[2][2];
#pragma unroll
    for (int nt = 0; nt < 2; ++nt) {
        size_t o = (size_t)(n0 + nt * 16 + l15) * 256 + quad * 8;
        Bh[0][nt] = *(const bf16x8*)&W2Thi[o];
        Bl[0][nt] = *(const bf16x8*)&W2Tlo[o];
    }
    __syncthreads();

#pragma unroll
    for (int ki = 0; ki < 8; ++ki) {
        const int cur = ki & 1, nxt = cur ^ 1;
        if (ki < 7) {
            int k0n = (ki + 1) * 32;
#pragma unroll
            for (int nt = 0; nt < 2; ++nt) {
                size_t o = (size_t)(n0 + nt * 16 + l15) * 256 + k0n + quad * 8;
                Bh[nxt][nt] = *(const bf16x8*)&W2Thi[o];
                Bl[nxt][nt] = *(const bf16x8*)&W2Tlo[o];
            }
        }
        const int k0 = ki * 32;
#pragma unroll
        for (int mt = 0; mt < 4; ++mt) {
            bf16x8 Ah = *(bf16x8*)&Hhi[HSW(mt * 16 + l15, k0 + quad * 8)];
            bf16x8 Al = *(bf16x8*)&Hlo[HSW(mt * 16 + l15, k0 + quad * 8)];
#pragma unroll
            for (int nt = 0; nt < 2; ++nt) {
                acc[mt][nt] = __builtin_amdgcn_mfma_f32_16x16x32_bf16(Ah, Bh[cur][nt], acc[mt][nt], 0, 0, 0);
                acc[mt][nt] = __builtin_amdgcn_mfma_f32_16x16x32_bf16(Ah, Bl[cur][nt], acc[mt][nt], 0, 0, 0);
                acc[mt][nt] = __builtin_amdgcn_mfma_f32_16x16x32_bf16(Al, Bh[cur][nt], acc[mt][nt], 0, 0, 0);
            }
        }
    }

    // all waves finished READING Hhi/Hlo before we overwrite with Xbf
    __syncthreads();
    short* Xbf = Hhi;   // reuse: bf16 xa strip, swizzled [64][256]
    float colsum[2] = {0.f, 0.f};
#pragma unroll
    for (int nt = 0; nt < 2; ++nt) {
        int col = n0 + nt * 16 + l15;
        float bias = (col < DMA) ? b2[col] : 0.f;
#pragma unroll
        for (int mt = 0; mt < 4; ++mt)
#pragma unroll
            for (int r = 0; r < 4; ++r) {
                int tl = mt * 16 + quad * 4 + r;
                int token = m0 + tl;
                float v;
                if (col < DMA) v = acc[mt][nt][r] + bias;
                else           v = a_prev[(size_t)token * ACT_ + (col - DMA)];
                xa[(size_t)token * 256 + col] = v;
                Xbf[HSW(tl, col)] = f2bf(v);
                colsum[nt] += v;
            }
    }
    // xasum partial: reduce across the 4 quads (rows); quad==0 lane stores
    // this block's 64-row column sum to its OWN slot (no atomics, no RMW).
#pragma unroll
    for (int nt = 0; nt < 2; ++nt) {
        float s = colsum[nt];
        s += __shfl_xor(s, 16);
        s += __shfl_xor(s, 32);
        if (quad == 0)
            xasum_p[((size_t)half * BB + b) * 256 + n0 + nt * 16 + l15] = s;
    }

    // prefetch ntile0's FIRST half B panel (k=0..127) before the barrier
    bf16x8 bfv[4][2];
#pragma unroll
    for (int k8 = 0; k8 < 4; ++k8)
#pragma unroll
        for (int nf = 0; nf < 2; ++nf)
            bfv[k8][nf] = *(const bf16x8*)&WkvT[(size_t)(n0 + nf * 16 + l15) * 256
                                                + k8 * 32 + quad * 8];
    __syncthreads();

    // ---- GEMM3: K/V = Xbf @ WkvT + bkv. 8 waves x 2 ntiles x 32 cols.
    // B panel in 4-deep halves. Per-element k8 order 0..7 -> bit-identical.
    for (int ntile = 0; ntile < 2; ++ntile) {
        const int nbase = ntile * 256 + n0;
        f32x4 acc3[4][2];
#pragma unroll
        for (int nf = 0; nf < 2; ++nf) {
            float bias = bqkv[256 + nbase + nf * 16 + l15];
#pragma unroll
            for (int mt = 0; mt < 4; ++mt)
                acc3[mt][nf] = (f32x4){bias, bias, bias, bias};
        }
        // first half: k8 = 0..3 (bfv already loaded)
#pragma unroll
        for (int k8 = 0; k8 < 4; ++k8) {
            const int k0 = k8 * 32;
            bf16x8 af[4];
#pragma unroll
            for (int mt = 0; mt < 4; ++mt)
                af[mt] = *(bf16x8*)&Xbf[HSW(mt * 16 + l15, k0 + quad * 8)];
#pragma unroll
            for (int mt = 0; mt < 4; ++mt)
#pragma unroll
                for (int nf = 0; nf < 2; ++nf)
                    acc3[mt][nf] = __builtin_amdgcn_mfma_f32_16x16x32_bf16(
                        af[mt], bfv[k8][nf], acc3[mt][nf], 0, 0, 0);
        }
        // second half: load k=128..255 then k8 = 4..7
#pragma unroll
        for (int k8 = 0; k8 < 4; ++k8)
#pragma unroll
            for (int nf = 0; nf < 2; ++nf)
                bfv[k8][nf] = *(const bf16x8*)&WkvT[(size_t)(nbase + nf * 16 + l15) * 256
                                                    + 128 + k8 * 32 + quad * 8];
#pragma unroll
        for (int k8 = 0; k8 < 4; ++k8) {
            const int k0 = 128 + k8 * 32;
            bf16x8 af[4];
#pragma unroll
            for (int mt = 0; mt < 4; ++mt)
                af[mt] = *(bf16x8*)&Xbf[HSW(mt * 16 + l15, k0 + quad * 8)];
#pragma unroll
            for (int mt = 0; mt < 4; ++mt)
#pragma unroll
                for (int nf = 0; nf < 2; ++nf)
                    acc3[mt][nf] = __builtin_amdgcn_mfma_f32_16x16x32_bf16(
                        af[mt], bfv[k8][nf], acc3[mt][nf], 0, 0, 0);
        }
        // prefetch next ntile's first half before the store tail
        if (ntile < 1) {
            const int nb2 = 256 + n0;
#pragma unroll
            for (int k8 = 0; k8 < 4; ++k8)
#pragma unroll
                for (int nf = 0; nf < 2; ++nf)
                    bfv[k8][nf] = *(const bf16x8*)&WkvT[(size_t)(nb2 + nf * 16 + l15) * 256
                                                        + k8 * 32 + quad * 8];
        }
#pragma unroll
        for (int nf = 0; nf < 2; ++nf) {
            int n_g = nbase + nf * 16 + l15;
            if (n_g < 256) {
#pragma unroll
                for (int mt = 0; mt < 4; ++mt)
#pragma unroll
                    for (int r = 0; r < 4; ++r) {
                        int token = tb0 + mt * 16 + quad * 4 + r;
                        kbf[((size_t)b * SS + token) * 256 + n_g] = __float2bfloat16(acc3[mt][nf][r]);
                    }
            } else {
                // transposed V: 4 consecutive tokens -> one aligned 8B store
#pragma unroll
                for (int mt = 0; mt < 4; ++mt) {
                    short4v pv;
#pragma unroll
                    for (int r = 0; r < 4; ++r) pv[r] = f2bf(acc3[mt][nf][r]);
                    *(short4v*)((short*)vbfT + ((size_t)b * 256 + (n_g - 256)) * SS
                                + tb0 + mt * 16 + quad * 4) = pv;
                }
            }
        }
    }
}

// ---------------------------------------------------------------------------
// K_score (R7): xasum = p0 + p1 from the two per-half slots (fixed order,
// deterministic). bqdot and the 0.125 scale remain dropped: scores feed ONLY
// top-k index selection; per-batch constant shift / positive scale is a
// monotone transform -> identical indices.
// ---------------------------------------------------------------------------
__global__ void __launch_bounds__(256) k_score(const float* __restrict__ xa,
        const float* __restrict__ xasum_p,
        const float* __restrict__ Wqkv, const float* __restrict__ WqT,
        const float* __restrict__ bqkv, int* __restrict__ idxb) {
    __shared__ float xasum_sh[256];
    __shared__ float ksum_sh[256];
    __shared__ float wqk_sh[256];
    __shared__ double ssd[128];
    const int b = blockIdx.x;
    const int tid = threadIdx.x;
    const float* xab = xa + (size_t)b * SS * DD;

    xasum_sh[tid] = xasum_p[(size_t)b * 256 + tid]
                  + xasum_p[((size_t)BB + b) * 256 + tid];
    __syncthreads();

    float ks = 128.f * bqkv[256 + tid];
    for (int d = 0; d < 256; ++d)
        ks = fmaf(xasum_sh[d], Wqkv[(size_t)d * D3 + 256 + tid], ks);
    ksum_sh[tid] = ks;
    __syncthreads();

    float wq = 0.f;
    for (int c = 0; c < 256; ++c)
        wq = fmaf(WqT[(size_t)c * 256 + tid], ksum_sh[c], wq);
    wqk_sh[tid] = wq;
    __syncthreads();

    // row dots: wave w rows [w*32, w*32+32); lane l covers cols 4l..4l+3.
    {
        const int wv = tid >> 6, lane = tid & 63;
#pragma unroll 4
        for (int rr = 0; rr < 32; ++rr) {
            int r = wv * 32 + rr;
            float4 x4 = *(const float4*)&xab[(size_t)r * 256 + lane * 4];
            const float* w4 = wqk_sh + lane * 4;
            double p = (double)x4.x * (double)w4[0];
            p += (double)x4.y * (double)w4[1];
            p += (double)x4.z * (double)w4[2];
            p += (double)x4.w * (double)w4[3];
#pragma unroll
            for (int off = 1; off < 64; off <<= 1) p += __shfl_xor(p, off);
            if (lane == 0) ssd[r] = p;
        }
    }
    __syncthreads();
    if (tid < 64) {
        double v0 = ssd[tid], v1 = ssd[tid + 64];
        int i0 = tid, i1 = tid + 64;
        bool t0 = false, t1 = false;
        for (int t = 0; t < TOPK; ++t) {
            double c0 = t0 ? -1e300 : v0;
            double c1 = t1 ? -1e300 : v1;
            double bvv; int bi;
            if (c1 > c0) { bvv = c1; bi = i1; } else { bvv = c0; bi = i0; }
#pragma unroll
            for (int off = 1; off < 64; off <<= 1) {
                double ov = __shfl_xor(bvv, off);
                int oi = __shfl_xor(bi, off);
                if (ov > bvv || (ov == bvv && oi < bi)) { bvv = ov; bi = oi; }
            }
            if (tid == 0) idxb[b * TOPK + t] = bi;
            if (bi == i0) t0 = true;
            if (bi == i1) t1 = true;
        }
    }
}

// ---------------------------------------------------------------------------
// K_attn2: gather + q-projection + attention fused, per batch. Wave = head.
// ---------------------------------------------------------------------------
__global__ void __launch_bounds__(256) k_attn2(const float* __restrict__ xa,
        const int* __restrict__ idxb, const short* __restrict__ WqTbf,
        const float* __restrict__ bqkv,
        const short* __restrict__ kbf, const short* __restrict__ vbfT,
        short* __restrict__ Ctx) {
    __shared__ __attribute__((aligned(16))) short Xsh[16 * 264];
    __shared__ __attribute__((aligned(16))) short Qsh[16 * 264];
    __shared__ short Pbuf[4][16 * 136];
    __shared__ int sidx[8];
    const int b = blockIdx.x;
    const int tid = threadIdx.x;
    const int h = tid >> 6, lane = tid & 63;
    const int quad = lane >> 4, l15 = lane & 15;

    if (tid < 8) sidx[tid] = idxb[b * TOPK + tid];
    __syncthreads();
#pragma unroll
    for (int t = 0; t < 16; ++t) {
        short v = 0;
        if (t < 8) v = f2bf(xa[((size_t)b * SS + sidx[t]) * 256 + tid]);
        Xsh[t * 264 + tid] = v;
    }
    __syncthreads();

    {
        f32x4 qacc[4];
#pragma unroll
        for (int nt = 0; nt < 4; ++nt) qacc[nt] = (f32x4){0.f, 0.f, 0.f, 0.f};
#pragma unroll
        for (int ki = 0; ki < 8; ++ki) {
            int k0 = ki * 32;
            bf16x8 Ax = *(bf16x8*)&Xsh[l15 * 264 + k0 + quad * 8];
#pragma unroll
            for (int nt = 0; nt < 4; ++nt) {
                int col = h * 64 + nt * 16 + l15;
                bf16x8 Bq = *(const bf16x8*)&WqTbf[(size_t)col * 256 + k0 + quad * 8];
                qacc[nt] = __builtin_amdgcn_mfma_f32_16x16x32_bf16(Ax, Bq, qacc[nt], 0, 0, 0);
            }
        }
#pragma unroll
        for (int nt = 0; nt < 4; ++nt) {
            int col = h * 64 + nt * 16 + l15;
            float bq = bqkv[col];
#pragma unroll
            for (int r = 0; r < 4; ++r)
                Qsh[(quad * 4 + r) * 264 + col] = f2bf(qacc[nt][r] + bq);
        }
    }
    // Qsh strip is wave-local — no barrier needed.

    const short* kb = kbf + (size_t)b * SS * 256 + h * 64;
    const short* vb = vbfT + ((size_t)b * 256 + h * 64) * SS;

    bf16x8 aq[2];
#pragma unroll
    for (int ks = 0; ks < 2; ++ks)
        aq[ks] = *(bf16x8*)&Qsh[l15 * 264 + h * 64 + ks * 32 + quad * 8];
    f32x4 sc[8];
#pragma unroll
    for (int nt = 0; nt < 8; ++nt) sc[nt] = (f32x4){0.f, 0.f, 0.f, 0.f};
#pragma unroll
    for (int nt = 0; nt < 8; ++nt)
#pragma unroll
        for (int ks = 0; ks < 2; ++ks) {
            bf16x8 bk = *(const bf16x8*)&kb[(size_t)(nt * 16 + l15) * 256 + ks * 32 + quad * 8];
            sc[nt] = __builtin_amdgcn_mfma_f32_16x16x32_bf16(aq[ks], bk, sc[nt], 0, 0, 0);
        }
#pragma unroll
    for (int r = 0; r < 4; ++r) {
        float m = -3.4e38f;
#pragma unroll
        for (int nt = 0; nt < 8; ++nt) m = fmaxf(m, sc[nt][r]);
        m = fmaxf(m, __shfl_xor(m, 1));
        m = fmaxf(m, __shfl_xor(m, 2));
        m = fmaxf(m, __shfl_xor(m, 4));
        m = fmaxf(m, __shfl_xor(m, 8));
        float s = 0.f;
#pragma unroll
        for (int nt = 0; nt < 8; ++nt) {
            float e = __expf((sc[nt][r] - m) * 0.125f);
            sc[nt][r] = e;
            s += e;
        }
        s += __shfl_xor(s, 1);
        s += __shfl_xor(s, 2);
        s += __shfl_xor(s, 4);
        s += __shfl_xor(s, 8);
        float inv = 1.f / s;
        int row = quad * 4 + r;
#pragma unroll
        for (int nt = 0; nt < 8; ++nt)
            Pbuf[h][row * 136 + nt * 16 + l15] = f2bf(sc[nt][r] * inv);
    }
    __syncthreads();
    bf16x8 ap[4];
#pragma unroll
    for (int ks = 0; ks < 4; ++ks)
        ap[ks] = *(bf16x8*)&Pbuf[h][l15 * 136 + ks * 32 + quad * 8];
    f32x4 ct[4];
#pragma unroll
    for (int nt = 0; nt < 4; ++nt) ct[nt] = (f32x4){0.f, 0.f, 0.f, 0.f};
#pragma unroll
    for (int nt = 0; nt < 4; ++nt)
#pragma unroll
        for (int ks = 0; ks < 4; ++ks) {
            bf16x8 bv = *(const bf16x8*)&vb[(size_t)(nt * 16 + l15) * SS + ks * 32 + quad * 8];
            ct[nt] = __builtin_amdgcn_mfma_f32_16x16x32_bf16(ap[ks], bv, ct[nt], 0, 0, 0);
        }
#pragma unroll
    for (int nt = 0; nt < 4; ++nt)
#pragma unroll
        for (int r = 0; r < 4; ++r)
            Ctx[((size_t)b * 16 + quad * 4 + r) * 256 + h * 64 + nt * 16 + l15] =
                f2bf(ct[nt][r]);
}

// ---------------------------------------------------------------------------
// K_omm: resh = Ctx @ WoT^T + bo. Writes fp32 resh (d_out) + bf16 resh_bf.
// ---------------------------------------------------------------------------
__global__ void __launch_bounds__(256) k_omm(const short* __restrict__ A,
        const short* __restrict__ BT, const float* __restrict__ bias,
        float* __restrict__ resh_out, __hip_bfloat16* __restrict__ resh_bf) {
    __shared__ __attribute__((aligned(16))) short Ash[128 * 72];
    __shared__ __attribute__((aligned(16))) short Bsh[128 * 72];
    const int mt = blockIdx.x >> 1, nt2 = blockIdx.x & 1;
    const int m0 = mt * 128, n0 = nt2 * 128;
    const int tid = threadIdx.x;
    const int wave = tid >> 6, lane = tid & 63;
    const int wm = wave >> 1, wn = wave & 1;
    const int quad = lane >> 4, l15 = lane & 15;

    f32x4 acc[4][4];
#pragma unroll
    for (int tm = 0; tm < 4; ++tm)
#pragma unroll
        for (int tn = 0; tn < 4; ++tn) acc[tm][tn] = (f32x4){0.f, 0.f, 0.f, 0.f};

    for (int k0 = 0; k0 < 256; k0 += 64) {
        __syncthreads();
#pragma unroll
        for (int it = 0; it < 4; ++it) {
            int idx = it * 256 + tid;
            int row = idx >> 3, c8 = idx & 7;
            *(uint4*)&Ash[row * 72 + c8 * 8] =
                *(const uint4*)&A[(size_t)(m0 + row) * 256 + k0 + c8 * 8];
            *(uint4*)&Bsh[row * 72 + c8 * 8] =
                *(const uint4*)&BT[(size_t)(n0 + row) * 256 + k0 + c8 * 8];
        }
        __syncthreads();
#pragma unroll
        for (int ks = 0; ks < 2; ++ks) {
            bf16x8 af[4], bfr[4];
#pragma unroll
            for (int t = 0; t < 4; ++t) {
                af[t]  = *(bf16x8*)&Ash[(wm * 64 + t * 16 + l15) * 72 + ks * 32 + quad * 8];
                bfr[t] = *(bf16x8*)&Bsh[(wn * 64 + t * 16 + l15) * 72 + ks * 32 + quad * 8];
            }
#pragma unroll
            for (int tm = 0; tm < 4; ++tm)
#pragma unroll
                for (int tn = 0; tn < 4; ++tn)
                    acc[tm][tn] = __builtin_amdgcn_mfma_f32_16x16x32_bf16(
                        af[tm], bfr[tn], acc[tm][tn], 0, 0, 0);
        }
    }
#pragma unroll
    for (int tm = 0; tm < 4; ++tm)
#pragma unroll
        for (int tn = 0; tn < 4; ++tn) {
            int col = n0 + wn * 64 + tn * 16 + l15;
            float bv = bias[col];
#pragma unroll
            for (int r = 0; r < 4; ++r) {
                int row = m0 + wm * 64 + tm * 16 + quad * 4 + r;
                int bidx = row >> 4, r16 = row & 15;
                if (r16 < 8) {
                    float v = acc[tm][tn][r] + bv;
                    size_t o = (size_t)bidx * 2048 + r16 * 256 + col;
                    resh_out[o] = v;
                    resh_bf[o] = __float2bfloat16(v);
                }
            }
        }
}

// ---------------------------------------------------------------------------
// K_gru2: GRU GEMMs with split-K on the K=2048 input GEMM.
// blocks [0,96): gi partials; blocks [96,120): gh (K=256).
// ---------------------------------------------------------------------------
__global__ void __launch_bounds__(256) k_gru2(const __hip_bfloat16* __restrict__ resh_bf,
        const __hip_bfloat16* __restrict__ WihT, const __hip_bfloat16* __restrict__ pdbf,
        const __hip_bfloat16* __restrict__ WhhT, float* __restrict__ gip,
        float* __restrict__ gh) {
    __shared__ __attribute__((aligned(16))) short Ash[128 * 72];
    __shared__ __attribute__((aligned(16))) short Bsh[128 * 72];
    int blk = blockIdx.x;
    const __hip_bfloat16 *A, *BT;
    float* C;
    int K, kbeg, kend;
    if (blk < 96) {
        int chunk = blk / 24; blk %= 24;
        A = resh_bf; BT = WihT; C = gip + (size_t)chunk * 512 * 768;
        K = 2048; kbeg = chunk * 512; kend = kbeg + 512;
    } else {
        blk -= 96; A = pdbf; BT = WhhT; C = gh; K = 256; kbeg = 0; kend = 256;
    }
    const int mt = blk / 6, nt = blk % 6;
    const int m0 = mt * 128, n0 = nt * 128;
    const int tid = threadIdx.x;
    const int wave = tid >> 6, lane = tid & 63;
    const int wm = wave >> 1, wn = wave & 1;
    const int quad = lane >> 4, l15 = lane & 15;

    f32x4 acc[4][4];
#pragma unroll
    for (int tm = 0; tm < 4; ++tm)
#pragma unroll
        for (int tn = 0; tn < 4; ++tn)
            acc[tm][tn] = (f32x4){0.f, 0.f, 0.f, 0.f};

    for (int k0 = kbeg; k0 < kend; k0 += 64) {
        __syncthreads();
#pragma unroll
        for (int it = 0; it < 4; ++it) {
            int idx = it * 256 + tid;
            int row = idx >> 3, c8 = idx & 7;
            *(uint4*)&Ash[row * 72 + c8 * 8] =
                *(const uint4*)&A[(size_t)(m0 + row) * K + k0 + c8 * 8];
            *(uint4*)&Bsh[row * 72 + c8 * 8] =
                *(const uint4*)&BT[(size_t)(n0 + row) * K + k0 + c8 * 8];
        }
        __syncthreads();
#pragma unroll
        for (int ks = 0; ks < 2; ++ks) {
            bf16x8 af[4], bfr[4];
#pragma unroll
            for (int t = 0; t < 4; ++t) {
                af[t]  = *(bf16x8*)&Ash[(wm * 64 + t * 16 + l15) * 72 + ks * 32 + quad * 8];
                bfr[t] = *(bf16x8*)&Bsh[(wn * 64 + t * 16 + l15) * 72 + ks * 32 + quad * 8];
            }
#pragma unroll
            for (int tm = 0; tm < 4; ++tm)
#pragma unroll
                for (int tn = 0; tn < 4; ++tn)
                    acc[tm][tn] = __builtin_amdgcn_mfma_f32_16x16x32_bf16(
                        af[tm], bfr[tn], acc[tm][tn], 0, 0, 0);
        }
    }
#pragma unroll
    for (int tm = 0; tm < 4; ++tm)
#pragma unroll
        for (int tn = 0; tn < 4; ++tn) {
            int col = n0 + wn * 64 + tn * 16 + l15;
#pragma unroll
            for (int r = 0; r < 4; ++r) {
                int row = m0 + wm * 64 + tm * 16 + quad * 4 + r;
                C[(size_t)row * 768 + col] = acc[tm][tn][r];
            }
        }
}

// ---------------------------------------------------------------------------
// K_gruact: gates elementwise. newd = (1-z)*n + z*prev_d. Sums the 4 split-K
// gi partials in fixed order (deterministic).
// ---------------------------------------------------------------------------
__global__ void k_gruact(const float* __restrict__ gip, const float* __restrict__ gh,
                         const float* __restrict__ b_ih, const float* __restrict__ b_hh,
                         const float* __restrict__ prev_d, float* __restrict__ newd) {
    const int b = blockIdx.x, tid = threadIdx.x;
    const size_t SZ = (size_t)512 * 768;
    const float* g0 = gip + (size_t)b * D3;
    const float* ghb = gh + (size_t)b * D3;
    float ir = ((g0[tid] + g0[SZ + tid]) + g0[2 * SZ + tid]) + g0[3 * SZ + tid] + b_ih[tid];
    float iz = ((g0[256 + tid] + g0[SZ + 256 + tid]) + g0[2 * SZ + 256 + tid]) + g0[3 * SZ + 256 + tid] + b_ih[256 + tid];
    float in = ((g0[512 + tid] + g0[SZ + 512 + tid]) + g0[2 * SZ + 512 + tid]) + g0[3 * SZ + 512 + tid] + b_ih[512 + tid];
    float hr = ghb[tid] + b_hh[tid];
    float hz = ghb[256 + tid] + b_hh[256 + tid];
    float hn = ghb[512 + tid] + b_hh[512 + tid];
    float pd = prev_d[(size_t)b * 256 + tid];
    float r = 1.f / (1.f + __expf(-(ir + hr)));
    float z = 1.f / (1.f + __expf(-(iz + hz)));
    float n = tanhf(in + r * hn);
    newd[(size_t)b * 256 + tid] = (1.f - z) * n + z * pd;
}

// ---------------------------------------------------------------------------
extern "C" void kernel_launch(void* const* d_in, const int* in_sizes, int n_in,
                              void* d_out, int out_size, void* d_ws, size_t ws_size,
                              hipStream_t stream) {
    const float* prev_d = (const float*)d_in[0];
    const float* x_obs  = (const float*)d_in[1];
    const float* a_prev = (const float*)d_in[2];
    const float* W1     = (const float*)d_in[3];
    const float* b1     = (const float*)d_in[4];
    const float* W2     = (const float*)d_in[5];
    const float* b2     = (const float*)d_in[6];
    const float* Wqkv   = (const float*)d_in[7];
    const float* bqkv   = (const float*)d_in[8];
    const float* Wo     = (const float*)d_in[9];
    const float* bo     = (const float*)d_in[10];
    const float* W_ih   = (const float*)d_in[11];
    const float* b_ih   = (const float*)d_in[12];
    const float* W_hh   = (const float*)d_in[13];
    const float* b_hh   = (const float*)d_in[14];
    float* out = (float*)d_out;

    const size_t NT = (size_t)BB * SS * DD;   // 16,777,216
    // region 1: xa fp32 (67 MB)
    float* xa = (float*)d_ws;
    // region 2 (67 MB): [kbf|vbfT]; late GRU bufs alias kbf AFTER k_attn2
    short* hkv = (short*)(xa + NT);
    __hip_bfloat16* kbf = (__hip_bfloat16*)hkv;
    __hip_bfloat16* vbfT = (__hip_bfloat16*)(hkv + NT);
    char* r2late = (char*)hkv;
    __hip_bfloat16* resh_bf = (__hip_bfloat16*)r2late;                // 2,097,152
    float* gip = (float*)(r2late + 2359296);                          // 4x 512x768 fp32 = 6,291,456
    float* gh  = (float*)(r2late + 2359296 + 6291456);                // 1,572,864
    // region 3 (16.8 MB): attn-phase buffers
    short* xsp = hkv + 2 * NT;
    char* late = (char*)xsp;
    __hip_bfloat16* WihT = (__hip_bfloat16*)late;                     // 3,145,728
    __hip_bfloat16* WhhT = (__hip_bfloat16*)(late + 3145728);         //   393,216
    __hip_bfloat16* WoT  = (__hip_bfloat16*)(late + 3538944);         //   131,072
    short* WqTbf = (short*)(late + 3670016);                          //   131,072
    short* Ctx   = (short*)(late + 3801088);                          // 4,194,304
    // region 4: persistent small (never aliased)
    short* fixed = xsp + 2 * (size_t)NTOK * 64;
    short* W1Thi = fixed;                    // 16384
    short* W1Tlo = W1Thi + 16384;
    short* W2Thi = W1Tlo + 16384;            // 65536
    short* W2Tlo = W2Thi + 65536;
    float* WqT = (float*)(W2Tlo + 65536);    // 65536 floats
    __hip_bfloat16* WkvT = (__hip_bfloat16*)(WqT + 65536);  // 131072
    int* idxb = (int*)(WkvT + 131072);                      // 4096 ints
    __hip_bfloat16* pdbf = (__hip_bfloat16*)(idxb + 4096);  // 131072 bf16
    float* xasum_p = (float*)(pdbf + 131072);               // 2*512*256 fp32 = 1 MB

    float* newd = out;                       // [B, D]
    float* resh = out + (size_t)BB * DD;     // [B, TOPK*D]

    k_prepall <<<2192, 256, 0, stream>>>(W1, W1Thi, W1Tlo, W2, W2Thi, W2Tlo,
                                         Wqkv, WqT, WqTbf, WkvT,
                                         W_ih, WihT, W_hh, WhhT, Wo, WoT,
                                         prev_d, pdbf);
    k_mlp     <<<NTOK / 64, 512, 0, stream>>>(x_obs, W1Thi, W1Tlo, b1,
                                              W2Thi, W2Tlo, b2, a_prev,
                                              (const short*)WkvT, bqkv,
                                              xa, xasum_p, kbf, vbfT);
    k_score   <<<BB, 256, 0, stream>>>(xa, xasum_p, Wqkv, WqT, bqkv, idxb);
    k_attn2   <<<BB, 256, 0, stream>>>(xa, idxb, WqTbf, bqkv,
                                       (const short*)kbf, (const short*)vbfT, Ctx);
    k_omm     <<<128, 256, 0, stream>>>(Ctx, (const short*)WoT, bo, resh, resh_bf);
    k_gru2    <<<120, 256, 0, stream>>>(resh_bf, WihT, pdbf, WhhT, gip, gh);
    k_gruact  <<<BB, 256, 0, stream>>>(gip, gh, b_ih, b_hh, prev_d, newd);
}

// Round 8
// 294.932 us; speedup vs baseline: 1.0723x; 1.0704x over previous
//
#include <hip/hip_runtime.h>
#include <hip/hip_bf16.h>
#include <math.h>

#define BB 512
#define SS 128
#define DD 256
#define HH 4
#define TOPK 8
#define D3 768
#define DMA 248
#define ACT_ 8
#define NTOK 65536            // B*S

typedef __attribute__((ext_vector_type(8))) short bf16x8;
typedef __attribute__((ext_vector_type(4))) short short4v;
typedef __attribute__((ext_vector_type(4))) float f32x4;

static __device__ __forceinline__ short f2bf(float x) {
    __hip_bfloat16 h = __float2bfloat16(x);
    return *reinterpret_cast<short*>(&h);
}
static __device__ __forceinline__ float bf2f(short s) {
    __hip_bfloat16 h = *reinterpret_cast<__hip_bfloat16*>(&s);
    return __bfloat162float(h);
}
static __device__ __forceinline__ float tanh_fast(float x) {
    float e = __expf(2.f * x);
    return 1.f - 2.f / (e + 1.f);
}

// Swizzled LDS index for the [64][256]-short H/X strips: XOR row bits into the
// 16B-unit bits of col. Keeps bf16x8 groups contiguous (XOR bits >= 3 only).
#define HSW(r, c) ((r) * 256 + ((c) ^ (((r) & 7) << 3)))

// ---------------------------------------------------------------------------
// device helpers for the merged prep kernel
// ---------------------------------------------------------------------------
__device__ __forceinline__ void dev_wsplit(float (*t)[33], const float* src,
        short* dhi, short* dlo, int R, int C, int Cpad, int blk, int tid) {
    const int ctiles = Cpad >> 5;
    const int rt = blk / ctiles, ct = blk % ctiles;
    const int r0 = rt * 32, c0 = ct * 32;
#pragma unroll
    for (int i = 0; i < 4; ++i) {
        int idx = i * 256 + tid;
        int lr = idx >> 5, lc = idx & 31;
        t[lr][lc] = (c0 + lc < C) ? src[(size_t)(r0 + lr) * C + c0 + lc] : 0.f;
    }
    __syncthreads();
#pragma unroll
    for (int i = 0; i < 4; ++i) {
        int idx = i * 256 + tid;
        int lc = idx >> 5, lr = idx & 31;
        float v = t[lr][lc];
        short h = f2bf(v);
        size_t o = (size_t)(c0 + lc) * R + r0 + lr;
        dhi[o] = h;
        dlo[o] = f2bf(v - bf2f(h));
    }
}

__device__ __forceinline__ void dev_trbf(float (*t)[33], const float* src,
        __hip_bfloat16* dst, int R, int C, int blk, int tid) {
    const int ctiles = C >> 5;
    const int rt = blk / ctiles, ct = blk % ctiles;
    const int r0 = rt * 32, c0 = ct * 32;
#pragma unroll
    for (int i = 0; i < 4; ++i) {
        int idx = i * 256 + tid;
        int lr = idx >> 5, lc = idx & 31;
        t[lr][lc] = src[(size_t)(r0 + lr) * C + c0 + lc];
    }
    __syncthreads();
#pragma unroll
    for (int i = 0; i < 4; ++i) {
        int idx = i * 256 + tid;
        int lc = idx >> 5, lr = idx & 31;
        dst[(size_t)(c0 + lc) * R + r0 + lr] = __float2bfloat16(t[lr][lc]);
    }
}

__device__ __forceinline__ void dev_prep(float (*t)[33], const float* Wqkv,
        float* WqT, short* WqTbf, __hip_bfloat16* WkvT, int blk, int tid) {
    const int rt = blk / 24, ct = blk % 24;
    const int r0 = rt * 32, c0 = ct * 32;
#pragma unroll
    for (int i = 0; i < 4; ++i) {
        int idx = i * 256 + tid;
        int lr = idx >> 5, lc = idx & 31;
        t[lr][lc] = Wqkv[(size_t)(r0 + lr) * D3 + c0 + lc];
    }
    __syncthreads();
#pragma unroll
    for (int i = 0; i < 4; ++i) {
        int idx = i * 256 + tid;
        int lc = idx >> 5, lr = idx & 31;
        float v = t[lr][lc];
        int c = c0 + lc, r = r0 + lr;
        if (c < 256) {
            WqT[(size_t)c * 256 + r] = v;
            WqTbf[(size_t)c * 256 + r] = f2bf(v);
        } else {
            WkvT[(size_t)(c - 256) * 256 + r] = __float2bfloat16(v);
        }
    }
}

// ---------------------------------------------------------------------------
// K_prepall: all weight transposes/splits + pdcast in ONE launch.
// ---------------------------------------------------------------------------
__global__ void __launch_bounds__(256) k_prepall(
        const float* __restrict__ W1, short* __restrict__ W1Thi, short* __restrict__ W1Tlo,
        const float* __restrict__ W2, short* __restrict__ W2Thi, short* __restrict__ W2Tlo,
        const float* __restrict__ Wqkv, float* __restrict__ WqT, short* __restrict__ WqTbf,
        __hip_bfloat16* __restrict__ WkvT,
        const float* __restrict__ W_ih, __hip_bfloat16* __restrict__ WihT,
        const float* __restrict__ W_hh, __hip_bfloat16* __restrict__ WhhT,
        const float* __restrict__ Wo, __hip_bfloat16* __restrict__ WoT,
        const float* __restrict__ prev_d, __hip_bfloat16* __restrict__ pdbf) {
    __shared__ float t[32][33];
    const int blk = blockIdx.x, tid = threadIdx.x;
    if (blk < 16)        dev_wsplit(t, W1, W1Thi, W1Tlo, 64, 256, 256, blk, tid);
    else if (blk < 80)   dev_wsplit(t, W2, W2Thi, W2Tlo, 256, DMA, 256, blk - 16, tid);
    else if (blk < 272)  dev_prep(t, Wqkv, WqT, WqTbf, WkvT, blk - 80, tid);
    else if (blk < 1808) dev_trbf(t, W_ih, WihT, 2048, 768, blk - 272, tid);
    else if (blk < 2000) dev_trbf(t, W_hh, WhhT, 256, 768, blk - 1808, tid);
    else if (blk < 2064) dev_trbf(t, Wo, WoT, 256, 256, blk - 2000, tid);
    else {
        int i = (blk - 2064) * 1024 + tid * 4;
        float4 v = *(const float4*)&prev_d[i];
        pdbf[i]     = __float2bfloat16(v.x);
        pdbf[i + 1] = __float2bfloat16(v.y);
        pdbf[i + 2] = __float2bfloat16(v.z);
        pdbf[i + 3] = __float2bfloat16(v.w);
    }
}

// ---------------------------------------------------------------------------
// K_mlp: FUSED MLP + K/V emit. R8 = EXACT R5 version (proven 126us,
// FETCH ~18GB-KB). R6/R7's colsum/xasum epilogue fusion added ~24MB
// symmetric FETCH+WRITE (epilogue register pressure -> scratch) for zero
// net gain and is reverted. 64 tok/block, 512 thr / 8 waves, nt=2.
// ---------------------------------------------------------------------------
__global__ void __launch_bounds__(512, 4) k_mlp(const float* __restrict__ x_obs,
        const short* __restrict__ W1Thi, const short* __restrict__ W1Tlo,
        const float* __restrict__ b1,
        const short* __restrict__ W2Thi, const short* __restrict__ W2Tlo,
        const float* __restrict__ b2, const float* __restrict__ a_prev,
        const short* __restrict__ WkvT, const float* __restrict__ bqkv,
        float* __restrict__ xa,
        __hip_bfloat16* __restrict__ kbf, __hip_bfloat16* __restrict__ vbfT) {
    __shared__ __attribute__((aligned(16))) short Hhi[64 * 256];
    __shared__ __attribute__((aligned(16))) short Hlo[64 * 256];
    const int m0 = blockIdx.x * 64;
    const int b = blockIdx.x >> 1;                 // batch
    const int tb0 = (blockIdx.x & 1) * 64;          // token base within batch
    const int tid = threadIdx.x;
    const int wave = tid >> 6, lane = tid & 63;     // wave in [0,8)
    const int quad = lane >> 4, l15 = lane & 15;
    const int n0 = wave * 32;                       // 32-col slice per wave

    // ---- GEMM1: h strip [64 tokens x 32 cols per wave] ----
    {
        bf16x8 Bh[2][2], Bl[2][2];
#pragma unroll
        for (int nt = 0; nt < 2; ++nt)
#pragma unroll
            for (int ks = 0; ks < 2; ++ks) {
                size_t o = (size_t)(n0 + nt * 16 + l15) * 64 + ks * 32 + quad * 8;
                Bh[nt][ks] = *(const bf16x8*)&W1Thi[o];
                Bl[nt][ks] = *(const bf16x8*)&W1Tlo[o];
            }
        f32x4 acc[4][2];
#pragma unroll
        for (int mt = 0; mt < 4; ++mt)
#pragma unroll
            for (int nt = 0; nt < 2; ++nt) acc[mt][nt] = (f32x4){0.f, 0.f, 0.f, 0.f};
#pragma unroll
        for (int mt = 0; mt < 4; ++mt) {
            bf16x8 Ah[2], Al[2];
#pragma unroll
            for (int ks = 0; ks < 2; ++ks) {
                const float* xp = &x_obs[(size_t)(m0 + mt * 16 + l15) * 64 + ks * 32 + quad * 8];
                float4 a0 = *(const float4*)xp;
                float4 a1 = *(const float4*)(xp + 4);
                bf16x8 h, l;
                h[0]=f2bf(a0.x); l[0]=f2bf(a0.x - bf2f(h[0]));
                h[1]=f2bf(a0.y); l[1]=f2bf(a0.y - bf2f(h[1]));
                h[2]=f2bf(a0.z); l[2]=f2bf(a0.z - bf2f(h[2]));
                h[3]=f2bf(a0.w); l[3]=f2bf(a0.w - bf2f(h[3]));
                h[4]=f2bf(a1.x); l[4]=f2bf(a1.x - bf2f(h[4]));
                h[5]=f2bf(a1.y); l[5]=f2bf(a1.y - bf2f(h[5]));
                h[6]=f2bf(a1.z); l[6]=f2bf(a1.z - bf2f(h[6]));
                h[7]=f2bf(a1.w); l[7]=f2bf(a1.w - bf2f(h[7]));
                Ah[ks] = h; Al[ks] = l;
            }
#pragma unroll
            for (int nt = 0; nt < 2; ++nt)
#pragma unroll
                for (int ks = 0; ks < 2; ++ks) {
                    acc[mt][nt] = __builtin_amdgcn_mfma_f32_16x16x32_bf16(Ah[ks], Bh[nt][ks], acc[mt][nt], 0, 0, 0);
                    acc[mt][nt] = __builtin_amdgcn_mfma_f32_16x16x32_bf16(Ah[ks], Bl[nt][ks], acc[mt][nt], 0, 0, 0);
                    acc[mt][nt] = __builtin_amdgcn_mfma_f32_16x16x32_bf16(Al[ks], Bh[nt][ks], acc[mt][nt], 0, 0, 0);
                }
        }
#pragma unroll
        for (int nt = 0; nt < 2; ++nt) {
            int col = n0 + nt * 16 + l15;
            float bias = b1[col];
#pragma unroll
            for (int mt = 0; mt < 4; ++mt)
#pragma unroll
                for (int r = 0; r < 4; ++r) {
                    int tl = mt * 16 + quad * 4 + r;       // local token
                    float tv = tanh_fast(acc[mt][nt][r] + bias);
                    short h = f2bf(tv);
                    Hhi[HSW(tl, col)] = h;
                    Hlo[HSW(tl, col)] = f2bf(tv - bf2f(h));
                }
        }
    }

    // ---- GEMM2: double-buffered B; k0=0 preload overlaps the barrier ----
    f32x4 acc[4][2];
#pragma unroll
    for (int mt = 0; mt < 4; ++mt)
#pragma unroll
        for (int nt = 0; nt < 2; ++nt) acc[mt][nt] = (f32x4){0.f, 0.f, 0.f, 0.f};

    bf16x8 Bh[2][2], Bl[2][2];
#pragma unroll
    for (int nt = 0; nt < 2; ++nt) {
        size_t o = (size_t)(n0 + nt * 16 + l15) * 256 + quad * 8;
        Bh[0][nt] = *(const bf16x8*)&W2Thi[o];
        Bl[0][nt] = *(const bf16x8*)&W2Tlo[o];
    }
    __syncthreads();

#pragma unroll
    for (int ki = 0; ki < 8; ++ki) {
        const int cur = ki & 1, nxt = cur ^ 1;
        if (ki < 7) {
            int k0n = (ki + 1) * 32;
#pragma unroll
            for (int nt = 0; nt < 2; ++nt) {
                size_t o = (size_t)(n0 + nt * 16 + l15) * 256 + k0n + quad * 8;
                Bh[nxt][nt] = *(const bf16x8*)&W2Thi[o];
                Bl[nxt][nt] = *(const bf16x8*)&W2Tlo[o];
            }
        }
        const int k0 = ki * 32;
#pragma unroll
        for (int mt = 0; mt < 4; ++mt) {
            bf16x8 Ah = *(bf16x8*)&Hhi[HSW(mt * 16 + l15, k0 + quad * 8)];
            bf16x8 Al = *(bf16x8*)&Hlo[HSW(mt * 16 + l15, k0 + quad * 8)];
#pragma unroll
            for (int nt = 0; nt < 2; ++nt) {
                acc[mt][nt] = __builtin_amdgcn_mfma_f32_16x16x32_bf16(Ah, Bh[cur][nt], acc[mt][nt], 0, 0, 0);
                acc[mt][nt] = __builtin_amdgcn_mfma_f32_16x16x32_bf16(Ah, Bl[cur][nt], acc[mt][nt], 0, 0, 0);
                acc[mt][nt] = __builtin_amdgcn_mfma_f32_16x16x32_bf16(Al, Bh[cur][nt], acc[mt][nt], 0, 0, 0);
            }
        }
    }

    // all waves finished READING Hhi/Hlo before we overwrite with Xbf
    __syncthreads();
    short* Xbf = Hhi;   // reuse: bf16 xa strip, swizzled [64][256]
#pragma unroll
    for (int nt = 0; nt < 2; ++nt) {
        int col = n0 + nt * 16 + l15;
        float bias = (col < DMA) ? b2[col] : 0.f;
#pragma unroll
        for (int mt = 0; mt < 4; ++mt)
#pragma unroll
            for (int r = 0; r < 4; ++r) {
                int tl = mt * 16 + quad * 4 + r;
                int token = m0 + tl;
                float v;
                if (col < DMA) v = acc[mt][nt][r] + bias;
                else           v = a_prev[(size_t)token * ACT_ + (col - DMA)];
                xa[(size_t)token * 256 + col] = v;
                Xbf[HSW(tl, col)] = f2bf(v);
            }
    }

    // prefetch ntile0's FIRST half B panel (k=0..127) before the barrier
    bf16x8 bfv[4][2];
#pragma unroll
    for (int k8 = 0; k8 < 4; ++k8)
#pragma unroll
        for (int nf = 0; nf < 2; ++nf)
            bfv[k8][nf] = *(const bf16x8*)&WkvT[(size_t)(n0 + nf * 16 + l15) * 256
                                                + k8 * 32 + quad * 8];
    __syncthreads();

    // ---- GEMM3: K/V = Xbf @ WkvT + bkv. 8 waves x 2 ntiles x 32 cols.
    // B panel in 4-deep halves. Per-element k8 order 0..7 -> bit-identical.
    for (int ntile = 0; ntile < 2; ++ntile) {
        const int nbase = ntile * 256 + n0;
        f32x4 acc3[4][2];
#pragma unroll
        for (int nf = 0; nf < 2; ++nf) {
            float bias = bqkv[256 + nbase + nf * 16 + l15];
#pragma unroll
            for (int mt = 0; mt < 4; ++mt)
                acc3[mt][nf] = (f32x4){bias, bias, bias, bias};
        }
        // first half: k8 = 0..3 (bfv already loaded)
#pragma unroll
        for (int k8 = 0; k8 < 4; ++k8) {
            const int k0 = k8 * 32;
            bf16x8 af[4];
#pragma unroll
            for (int mt = 0; mt < 4; ++mt)
                af[mt] = *(bf16x8*)&Xbf[HSW(mt * 16 + l15, k0 + quad * 8)];
#pragma unroll
            for (int mt = 0; mt < 4; ++mt)
#pragma unroll
                for (int nf = 0; nf < 2; ++nf)
                    acc3[mt][nf] = __builtin_amdgcn_mfma_f32_16x16x32_bf16(
                        af[mt], bfv[k8][nf], acc3[mt][nf], 0, 0, 0);
        }
        // second half: load k=128..255 then k8 = 4..7
#pragma unroll
        for (int k8 = 0; k8 < 4; ++k8)
#pragma unroll
            for (int nf = 0; nf < 2; ++nf)
                bfv[k8][nf] = *(const bf16x8*)&WkvT[(size_t)(nbase + nf * 16 + l15) * 256
                                                    + 128 + k8 * 32 + quad * 8];
#pragma unroll
        for (int k8 = 0; k8 < 4; ++k8) {
            const int k0 = 128 + k8 * 32;
            bf16x8 af[4];
#pragma unroll
            for (int mt = 0; mt < 4; ++mt)
                af[mt] = *(bf16x8*)&Xbf[HSW(mt * 16 + l15, k0 + quad * 8)];
#pragma unroll
            for (int mt = 0; mt < 4; ++mt)
#pragma unroll
                for (int nf = 0; nf < 2; ++nf)
                    acc3[mt][nf] = __builtin_amdgcn_mfma_f32_16x16x32_bf16(
                        af[mt], bfv[k8][nf], acc3[mt][nf], 0, 0, 0);
        }
        // prefetch next ntile's first half before the store tail
        if (ntile < 1) {
            const int nb2 = 256 + n0;
#pragma unroll
            for (int k8 = 0; k8 < 4; ++k8)
#pragma unroll
                for (int nf = 0; nf < 2; ++nf)
                    bfv[k8][nf] = *(const bf16x8*)&WkvT[(size_t)(nb2 + nf * 16 + l15) * 256
                                                        + k8 * 32 + quad * 8];
        }
#pragma unroll
        for (int nf = 0; nf < 2; ++nf) {
            int n_g = nbase + nf * 16 + l15;
            if (n_g < 256) {
#pragma unroll
                for (int mt = 0; mt < 4; ++mt)
#pragma unroll
                    for (int r = 0; r < 4; ++r) {
                        int token = tb0 + mt * 16 + quad * 4 + r;
                        kbf[((size_t)b * SS + token) * 256 + n_g] = __float2bfloat16(acc3[mt][nf][r]);
                    }
            } else {
                // transposed V: 4 consecutive tokens -> one aligned 8B store
#pragma unroll
                for (int mt = 0; mt < 4; ++mt) {
                    short4v pv;
#pragma unroll
                    for (int r = 0; r < 4; ++r) pv[r] = f2bf(acc3[mt][nf][r]);
                    *(short4v*)((short*)vbfT + ((size_t)b * 256 + (n_g - 256)) * SS
                                + tb0 + mt * 16 + quad * 4) = pv;
                }
            }
        }
    }
}

// ---------------------------------------------------------------------------
// K_sattn (R8): k_score + k_attn2 + k_omm merged, one block per batch.
// Phase 1 (score): R5's exact loops, minus bqdot/0.125 (validated monotone
// drop in R6/R7 — feeds only top-k index selection). top-8 stays in LDS.
// Phase 2 (attention): unchanged k_attn2 code; ctx written f2bf to LDS
// (identical bits to the old Ctx global store).
// Phase 3 (out-proj): resh = ctx @ WoT^T + bo with k_omm's exact ascending
// 32-chunk K order -> bit-identical resh. Kills k_omm + Ctx round-trip.
// ---------------------------------------------------------------------------
__global__ void __launch_bounds__(256) k_sattn(const float* __restrict__ xa,
        const float* __restrict__ Wqkv, const float* __restrict__ WqT,
        const float* __restrict__ bqkv, const short* __restrict__ WqTbf,
        const short* __restrict__ kbf, const short* __restrict__ vbfT,
        const short* __restrict__ WoT, const float* __restrict__ bo,
        float* __restrict__ resh_out, __hip_bfloat16* __restrict__ resh_bf) {
    __shared__ float xasum_sh[256];
    __shared__ float ksum_sh[256];
    __shared__ float wqk_sh[256];
    __shared__ double ssd[128];
    __shared__ int sidx[8];
    __shared__ __attribute__((aligned(16))) short Xsh[16 * 264];
    __shared__ __attribute__((aligned(16))) short Qsh[16 * 264];
    __shared__ short Pbuf[4][16 * 136];
    __shared__ __attribute__((aligned(16))) short Csh[16 * 264];
    const int b = blockIdx.x;
    const int tid = threadIdx.x;
    const int h = tid >> 6, lane = tid & 63;
    const int quad = lane >> 4, l15 = lane & 15;
    const float* xab = xa + (size_t)b * SS * DD;

    // ---- phase 1: score + top-8 ----
    {
        float s = 0.f;
        for (int r = 0; r < 128; ++r) s += xab[r * 256 + tid];
        xasum_sh[tid] = s;
        __syncthreads();

        float ks = 128.f * bqkv[256 + tid];
        for (int d = 0; d < 256; ++d)
            ks = fmaf(xasum_sh[d], Wqkv[(size_t)d * D3 + 256 + tid], ks);
        ksum_sh[tid] = ks;
        __syncthreads();

        float wq = 0.f;
        for (int c = 0; c < 256; ++c)
            wq = fmaf(WqT[(size_t)c * 256 + tid], ksum_sh[c], wq);
        wqk_sh[tid] = wq;
        __syncthreads();

        // row dots: wave w rows [w*32, w*32+32); lane l covers cols 4l..4l+3.
#pragma unroll 4
        for (int rr = 0; rr < 32; ++rr) {
            int r = h * 32 + rr;
            float4 x4 = *(const float4*)&xab[(size_t)r * 256 + lane * 4];
            const float* w4 = wqk_sh + lane * 4;
            double p = (double)x4.x * (double)w4[0];
            p += (double)x4.y * (double)w4[1];
            p += (double)x4.z * (double)w4[2];
            p += (double)x4.w * (double)w4[3];
#pragma unroll
            for (int off = 1; off < 64; off <<= 1) p += __shfl_xor(p, off);
            if (lane == 0) ssd[r] = p;
        }
        __syncthreads();
        if (tid < 64) {
            double v0 = ssd[tid], v1 = ssd[tid + 64];
            int i0 = tid, i1 = tid + 64;
            bool t0 = false, t1 = false;
            for (int t = 0; t < TOPK; ++t) {
                double c0 = t0 ? -1e300 : v0;
                double c1 = t1 ? -1e300 : v1;
                double bvv; int bi;
                if (c1 > c0) { bvv = c1; bi = i1; } else { bvv = c0; bi = i0; }
#pragma unroll
                for (int off = 1; off < 64; off <<= 1) {
                    double ov = __shfl_xor(bvv, off);
                    int oi = __shfl_xor(bi, off);
                    if (ov > bvv || (ov == bvv && oi < bi)) { bvv = ov; bi = oi; }
                }
                if (tid == 0) sidx[t] = bi;
                if (bi == i0) t0 = true;
                if (bi == i1) t1 = true;
            }
        }
        __syncthreads();
    }

    // ---- phase 2: gather + q-projection + attention (wave = head) ----
#pragma unroll
    for (int t = 0; t < 16; ++t) {
        short v = 0;
        if (t < 8) v = f2bf(xa[((size_t)b * SS + sidx[t]) * 256 + tid]);
        Xsh[t * 264 + tid] = v;
    }
    __syncthreads();

    {
        f32x4 qacc[4];
#pragma unroll
        for (int nt = 0; nt < 4; ++nt) qacc[nt] = (f32x4){0.f, 0.f, 0.f, 0.f};
#pragma unroll
        for (int ki = 0; ki < 8; ++ki) {
            int k0 = ki * 32;
            bf16x8 Ax = *(bf16x8*)&Xsh[l15 * 264 + k0 + quad * 8];
#pragma unroll
            for (int nt = 0; nt < 4; ++nt) {
                int col = h * 64 + nt * 16 + l15;
                bf16x8 Bq = *(const bf16x8*)&WqTbf[(size_t)col * 256 + k0 + quad * 8];
                qacc[nt] = __builtin_amdgcn_mfma_f32_16x16x32_bf16(Ax, Bq, qacc[nt], 0, 0, 0);
            }
        }
#pragma unroll
        for (int nt = 0; nt < 4; ++nt) {
            int col = h * 64 + nt * 16 + l15;
            float bq = bqkv[col];
#pragma unroll
            for (int r = 0; r < 4; ++r)
                Qsh[(quad * 4 + r) * 264 + col] = f2bf(qacc[nt][r] + bq);
        }
    }
    // Qsh strip is wave-local — no barrier needed.

    const short* kb = kbf + (size_t)b * SS * 256 + h * 64;
    const short* vb = vbfT + ((size_t)b * 256 + h * 64) * SS;

    bf16x8 aq[2];
#pragma unroll
    for (int ks = 0; ks < 2; ++ks)
        aq[ks] = *(bf16x8*)&Qsh[l15 * 264 + h * 64 + ks * 32 + quad * 8];
    f32x4 sc[8];
#pragma unroll
    for (int nt = 0; nt < 8; ++nt) sc[nt] = (f32x4){0.f, 0.f, 0.f, 0.f};
#pragma unroll
    for (int nt = 0; nt < 8; ++nt)
#pragma unroll
        for (int ks = 0; ks < 2; ++ks) {
            bf16x8 bk = *(const bf16x8*)&kb[(size_t)(nt * 16 + l15) * 256 + ks * 32 + quad * 8];
            sc[nt] = __builtin_amdgcn_mfma_f32_16x16x32_bf16(aq[ks], bk, sc[nt], 0, 0, 0);
        }
#pragma unroll
    for (int r = 0; r < 4; ++r) {
        float m = -3.4e38f;
#pragma unroll
        for (int nt = 0; nt < 8; ++nt) m = fmaxf(m, sc[nt][r]);
        m = fmaxf(m, __shfl_xor(m, 1));
        m = fmaxf(m, __shfl_xor(m, 2));
        m = fmaxf(m, __shfl_xor(m, 4));
        m = fmaxf(m, __shfl_xor(m, 8));
        float s = 0.f;
#pragma unroll
        for (int nt = 0; nt < 8; ++nt) {
            float e = __expf((sc[nt][r] - m) * 0.125f);
            sc[nt][r] = e;
            s += e;
        }
        s += __shfl_xor(s, 1);
        s += __shfl_xor(s, 2);
        s += __shfl_xor(s, 4);
        s += __shfl_xor(s, 8);
        float inv = 1.f / s;
        int row = quad * 4 + r;
#pragma unroll
        for (int nt = 0; nt < 8; ++nt)
            Pbuf[h][row * 136 + nt * 16 + l15] = f2bf(sc[nt][r] * inv);
    }
    __syncthreads();
    bf16x8 ap[4];
#pragma unroll
    for (int ks = 0; ks < 4; ++ks)
        ap[ks] = *(bf16x8*)&Pbuf[h][l15 * 136 + ks * 32 + quad * 8];
    f32x4 ct[4];
#pragma unroll
    for (int nt = 0; nt < 4; ++nt) ct[nt] = (f32x4){0.f, 0.f, 0.f, 0.f};
#pragma unroll
    for (int nt = 0; nt < 4; ++nt)
#pragma unroll
        for (int ks = 0; ks < 4; ++ks) {
            bf16x8 bv = *(const bf16x8*)&vb[(size_t)(nt * 16 + l15) * SS + ks * 32 + quad * 8];
            ct[nt] = __builtin_amdgcn_mfma_f32_16x16x32_bf16(ap[ks], bv, ct[nt], 0, 0, 0);
        }
    // ctx -> LDS with the same f2bf rounding the old Ctx global store used
#pragma unroll
    for (int nt = 0; nt < 4; ++nt)
#pragma unroll
        for (int r = 0; r < 4; ++r)
            Csh[(quad * 4 + r) * 264 + h * 64 + nt * 16 + l15] = f2bf(ct[nt][r]);
    __syncthreads();

    // ---- phase 3: resh = ctx @ WoT^T + bo (k_omm's exact K order) ----
    {
        f32x4 oacc[4];
#pragma unroll
        for (int nt = 0; nt < 4; ++nt) oacc[nt] = (f32x4){0.f, 0.f, 0.f, 0.f};
#pragma unroll
        for (int ki = 0; ki < 8; ++ki) {
            bf16x8 af = *(bf16x8*)&Csh[l15 * 264 + ki * 32 + quad * 8];
#pragma unroll
            for (int nt = 0; nt < 4; ++nt) {
                int col = h * 64 + nt * 16 + l15;
                bf16x8 bw = *(const bf16x8*)&WoT[(size_t)col * 256 + ki * 32 + quad * 8];
                oacc[nt] = __builtin_amdgcn_mfma_f32_16x16x32_bf16(af, bw, oacc[nt], 0, 0, 0);
            }
        }
#pragma unroll
        for (int nt = 0; nt < 4; ++nt) {
            int col = h * 64 + nt * 16 + l15;
            float bv = bo[col];
#pragma unroll
            for (int r = 0; r < 4; ++r) {
                int row = quad * 4 + r;
                if (row < 8) {
                    float v = oacc[nt][r] + bv;
                    size_t o = (size_t)b * 2048 + row * 256 + col;
                    resh_out[o] = v;
                    resh_bf[o] = __float2bfloat16(v);
                }
            }
        }
    }
}

// ---------------------------------------------------------------------------
// K_gru2: GRU GEMMs with split-K on the K=2048 input GEMM.
// blocks [0,96): gi partials; blocks [96,120): gh (K=256).
// ---------------------------------------------------------------------------
__global__ void __launch_bounds__(256) k_gru2(const __hip_bfloat16* __restrict__ resh_bf,
        const __hip_bfloat16* __restrict__ WihT, const __hip_bfloat16* __restrict__ pdbf,
        const __hip_bfloat16* __restrict__ WhhT, float* __restrict__ gip,
        float* __restrict__ gh) {
    __shared__ __attribute__((aligned(16))) short Ash[128 * 72];
    __shared__ __attribute__((aligned(16))) short Bsh[128 * 72];
    int blk = blockIdx.x;
    const __hip_bfloat16 *A, *BT;
    float* C;
    int K, kbeg, kend;
    if (blk < 96) {
        int chunk = blk / 24; blk %= 24;
        A = resh_bf; BT = WihT; C = gip + (size_t)chunk * 512 * 768;
        K = 2048; kbeg = chunk * 512; kend = kbeg + 512;
    } else {
        blk -= 96; A = pdbf; BT = WhhT; C = gh; K = 256; kbeg = 0; kend = 256;
    }
    const int mt = blk / 6, nt = blk % 6;
    const int m0 = mt * 128, n0 = nt * 128;
    const int tid = threadIdx.x;
    const int wave = tid >> 6, lane = tid & 63;
    const int wm = wave >> 1, wn = wave & 1;
    const int quad = lane >> 4, l15 = lane & 15;

    f32x4 acc[4][4];
#pragma unroll
    for (int tm = 0; tm < 4; ++tm)
#pragma unroll
        for (int tn = 0; tn < 4; ++tn)
            acc[tm][tn] = (f32x4){0.f, 0.f, 0.f, 0.f};

    for (int k0 = kbeg; k0 < kend; k0 += 64) {
        __syncthreads();
#pragma unroll
        for (int it = 0; it < 4; ++it) {
            int idx = it * 256 + tid;
            int row = idx >> 3, c8 = idx & 7;
            *(uint4*)&Ash[row * 72 + c8 * 8] =
                *(const uint4*)&A[(size_t)(m0 + row) * K + k0 + c8 * 8];
            *(uint4*)&Bsh[row * 72 + c8 * 8] =
                *(const uint4*)&BT[(size_t)(n0 + row) * K + k0 + c8 * 8];
        }
        __syncthreads();
#pragma unroll
        for (int ks = 0; ks < 2; ++ks) {
            bf16x8 af[4], bfr[4];
#pragma unroll
            for (int t = 0; t < 4; ++t) {
                af[t]  = *(bf16x8*)&Ash[(wm * 64 + t * 16 + l15) * 72 + ks * 32 + quad * 8];
                bfr[t] = *(bf16x8*)&Bsh[(wn * 64 + t * 16 + l15) * 72 + ks * 32 + quad * 8];
            }
#pragma unroll
            for (int tm = 0; tm < 4; ++tm)
#pragma unroll
                for (int tn = 0; tn < 4; ++tn)
                    acc[tm][tn] = __builtin_amdgcn_mfma_f32_16x16x32_bf16(
                        af[tm], bfr[tn], acc[tm][tn], 0, 0, 0);
        }
    }
#pragma unroll
    for (int tm = 0; tm < 4; ++tm)
#pragma unroll
        for (int tn = 0; tn < 4; ++tn) {
            int col = n0 + wn * 64 + tn * 16 + l15;
#pragma unroll
            for (int r = 0; r < 4; ++r) {
                int row = m0 + wm * 64 + tm * 16 + quad * 4 + r;
                C[(size_t)row * 768 + col] = acc[tm][tn][r];
            }
        }
}

// ---------------------------------------------------------------------------
// K_gruact: gates elementwise. newd = (1-z)*n + z*prev_d. Sums the 4 split-K
// gi partials in fixed order (deterministic).
// ---------------------------------------------------------------------------
__global__ void k_gruact(const float* __restrict__ gip, const float* __restrict__ gh,
                         const float* __restrict__ b_ih, const float* __restrict__ b_hh,
                         const float* __restrict__ prev_d, float* __restrict__ newd) {
    const int b = blockIdx.x, tid = threadIdx.x;
    const size_t SZ = (size_t)512 * 768;
    const float* g0 = gip + (size_t)b * D3;
    const float* ghb = gh + (size_t)b * D3;
    float ir = ((g0[tid] + g0[SZ + tid]) + g0[2 * SZ + tid]) + g0[3 * SZ + tid] + b_ih[tid];
    float iz = ((g0[256 + tid] + g0[SZ + 256 + tid]) + g0[2 * SZ + 256 + tid]) + g0[3 * SZ + 256 + tid] + b_ih[256 + tid];
    float in = ((g0[512 + tid] + g0[SZ + 512 + tid]) + g0[2 * SZ + 512 + tid]) + g0[3 * SZ + 512 + tid] + b_ih[512 + tid];
    float hr = ghb[tid] + b_hh[tid];
    float hz = ghb[256 + tid] + b_hh[256 + tid];
    float hn = ghb[512 + tid] + b_hh[512 + tid];
    float pd = prev_d[(size_t)b * 256 + tid];
    float r = 1.f / (1.f + __expf(-(ir + hr)));
    float z = 1.f / (1.f + __expf(-(iz + hz)));
    float n = tanhf(in + r * hn);
    newd[(size_t)b * 256 + tid] = (1.f - z) * n + z * pd;
}

// ---------------------------------------------------------------------------
extern "C" void kernel_launch(void* const* d_in, const int* in_sizes, int n_in,
                              void* d_out, int out_size, void* d_ws, size_t ws_size,
                              hipStream_t stream) {
    const float* prev_d = (const float*)d_in[0];
    const float* x_obs  = (const float*)d_in[1];
    const float* a_prev = (const float*)d_in[2];
    const float* W1     = (const float*)d_in[3];
    const float* b1     = (const float*)d_in[4];
    const float* W2     = (const float*)d_in[5];
    const float* b2     = (const float*)d_in[6];
    const float* Wqkv   = (const float*)d_in[7];
    const float* bqkv   = (const float*)d_in[8];
    const float* Wo     = (const float*)d_in[9];
    const float* bo     = (const float*)d_in[10];
    const float* W_ih   = (const float*)d_in[11];
    const float* b_ih   = (const float*)d_in[12];
    const float* W_hh   = (const float*)d_in[13];
    const float* b_hh   = (const float*)d_in[14];
    float* out = (float*)d_out;

    const size_t NT = (size_t)BB * SS * DD;   // 16,777,216
    // region 1: xa fp32 (67 MB)
    float* xa = (float*)d_ws;
    // region 2 (67 MB): [kbf|vbfT]; gip/gh alias kbf AFTER k_sattn is done
    // reading it (k_gru2 runs strictly later).
    short* hkv = (short*)(xa + NT);
    __hip_bfloat16* kbf = (__hip_bfloat16*)hkv;
    __hip_bfloat16* vbfT = (__hip_bfloat16*)(hkv + NT);
    char* r2late = (char*)hkv;
    float* gip = (float*)(r2late + 2359296);                          // 4x 512x768 fp32 = 6,291,456
    float* gh  = (float*)(r2late + 2359296 + 6291456);                // 1,572,864
    // region 3 (16.8 MB): attn-phase buffers. resh_bf lives in the old Ctx
    // slot — k_sattn reads kbf (region 2) while writing resh_bf, so resh_bf
    // must NOT alias region 2 anymore.
    short* xsp = hkv + 2 * NT;
    char* late = (char*)xsp;
    __hip_bfloat16* WihT = (__hip_bfloat16*)late;                     // 3,145,728
    __hip_bfloat16* WhhT = (__hip_bfloat16*)(late + 3145728);         //   393,216
    __hip_bfloat16* WoT  = (__hip_bfloat16*)(late + 3538944);         //   131,072
    short* WqTbf = (short*)(late + 3670016);                          //   131,072
    __hip_bfloat16* resh_bf = (__hip_bfloat16*)(late + 3801088);      // 2,097,152 (old Ctx slot)
    // region 4: persistent small (never aliased)
    short* fixed = xsp + 2 * (size_t)NTOK * 64;
    short* W1Thi = fixed;                    // 16384
    short* W1Tlo = W1Thi + 16384;
    short* W2Thi = W1Tlo + 16384;            // 65536
    short* W2Tlo = W2Thi + 65536;
    float* WqT = (float*)(W2Tlo + 65536);    // 65536 floats
    __hip_bfloat16* WkvT = (__hip_bfloat16*)(WqT + 65536);  // 131072
    int* idxb = (int*)(WkvT + 131072);                      // 4096 ints (unused, layout keep)
    __hip_bfloat16* pdbf = (__hip_bfloat16*)(idxb + 4096);  // 131072 bf16

    float* newd = out;                       // [B, D]
    float* resh = out + (size_t)BB * DD;     // [B, TOPK*D]

    k_prepall <<<2192, 256, 0, stream>>>(W1, W1Thi, W1Tlo, W2, W2Thi, W2Tlo,
                                         Wqkv, WqT, WqTbf, WkvT,
                                         W_ih, WihT, W_hh, WhhT, Wo, WoT,
                                         prev_d, pdbf);
    k_mlp     <<<NTOK / 64, 512, 0, stream>>>(x_obs, W1Thi, W1Tlo, b1,
                                              W2Thi, W2Tlo, b2, a_prev,
                                              (const short*)WkvT, bqkv,
                                              xa, kbf, vbfT);
    k_sattn   <<<BB, 256, 0, stream>>>(xa, Wqkv, WqT, bqkv, WqTbf,
                                       (const short*)kbf, (const short*)vbfT,
                                       (const short*)WoT, bo, resh, resh_bf);
    k_gru2    <<<120, 256, 0, stream>>>(resh_bf, WihT, pdbf, WhhT, gip, gh);
    k_gruact  <<<BB, 256, 0, stream>>>(gip, gh, b_ih, b_hh, prev_d, newd);
}

// Round 9
// 275.807 us; speedup vs baseline: 1.1467x; 1.0693x over previous
//
#include <hip/hip_runtime.h>
#include <hip/hip_bf16.h>
#include <math.h>

#define BB 512
#define SS 128
#define DD 256
#define HH 4
#define TOPK 8
#define D3 768
#define DMA 248
#define ACT_ 8
#define NTOK 65536            // B*S

typedef __attribute__((ext_vector_type(8))) short bf16x8;
typedef __attribute__((ext_vector_type(4))) short short4v;
typedef __attribute__((ext_vector_type(4))) float f32x4;

static __device__ __forceinline__ short f2bf(float x) {
    __hip_bfloat16 h = __float2bfloat16(x);
    return *reinterpret_cast<short*>(&h);
}
static __device__ __forceinline__ float bf2f(short s) {
    __hip_bfloat16 h = *reinterpret_cast<__hip_bfloat16*>(&s);
    return __bfloat162float(h);
}
static __device__ __forceinline__ float tanh_fast(float x) {
    float e = __expf(2.f * x);
    return 1.f - 2.f / (e + 1.f);
}

// Swizzled LDS index for the [64][256]-short H/X strips: XOR row bits into the
// 16B-unit bits of col. Keeps bf16x8 groups contiguous (XOR bits >= 3 only).
#define HSW(r, c) ((r) * 256 + ((c) ^ (((r) & 7) << 3)))

// ---------------------------------------------------------------------------
// device helpers for the merged prep kernel
// ---------------------------------------------------------------------------
__device__ __forceinline__ void dev_wsplit(float (*t)[33], const float* src,
        short* dhi, short* dlo, int R, int C, int Cpad, int blk, int tid) {
    const int ctiles = Cpad >> 5;
    const int rt = blk / ctiles, ct = blk % ctiles;
    const int r0 = rt * 32, c0 = ct * 32;
#pragma unroll
    for (int i = 0; i < 4; ++i) {
        int idx = i * 256 + tid;
        int lr = idx >> 5, lc = idx & 31;
        t[lr][lc] = (c0 + lc < C) ? src[(size_t)(r0 + lr) * C + c0 + lc] : 0.f;
    }
    __syncthreads();
#pragma unroll
    for (int i = 0; i < 4; ++i) {
        int idx = i * 256 + tid;
        int lc = idx >> 5, lr = idx & 31;
        float v = t[lr][lc];
        short h = f2bf(v);
        size_t o = (size_t)(c0 + lc) * R + r0 + lr;
        dhi[o] = h;
        dlo[o] = f2bf(v - bf2f(h));
    }
}

__device__ __forceinline__ void dev_trbf(float (*t)[33], const float* src,
        __hip_bfloat16* dst, int R, int C, int blk, int tid) {
    const int ctiles = C >> 5;
    const int rt = blk / ctiles, ct = blk % ctiles;
    const int r0 = rt * 32, c0 = ct * 32;
#pragma unroll
    for (int i = 0; i < 4; ++i) {
        int idx = i * 256 + tid;
        int lr = idx >> 5, lc = idx & 31;
        t[lr][lc] = src[(size_t)(r0 + lr) * C + c0 + lc];
    }
    __syncthreads();
#pragma unroll
    for (int i = 0; i < 4; ++i) {
        int idx = i * 256 + tid;
        int lc = idx >> 5, lr = idx & 31;
        dst[(size_t)(c0 + lc) * R + r0 + lr] = __float2bfloat16(t[lr][lc]);
    }
}

__device__ __forceinline__ void dev_prep(float (*t)[33], const float* Wqkv,
        float* WqT, short* WqTbf, __hip_bfloat16* WkvT, int blk, int tid) {
    const int rt = blk / 24, ct = blk % 24;
    const int r0 = rt * 32, c0 = ct * 32;
#pragma unroll
    for (int i = 0; i < 4; ++i) {
        int idx = i * 256 + tid;
        int lr = idx >> 5, lc = idx & 31;
        t[lr][lc] = Wqkv[(size_t)(r0 + lr) * D3 + c0 + lc];
    }
    __syncthreads();
#pragma unroll
    for (int i = 0; i < 4; ++i) {
        int idx = i * 256 + tid;
        int lc = idx >> 5, lr = idx & 31;
        float v = t[lr][lc];
        int c = c0 + lc, r = r0 + lr;
        if (c < 256) {
            WqT[(size_t)c * 256 + r] = v;
            WqTbf[(size_t)c * 256 + r] = f2bf(v);
        } else {
            WkvT[(size_t)(c - 256) * 256 + r] = __float2bfloat16(v);
        }
    }
}

// ---------------------------------------------------------------------------
// K_prepall: all weight transposes/splits + pdcast in ONE launch.
// ---------------------------------------------------------------------------
__global__ void __launch_bounds__(256) k_prepall(
        const float* __restrict__ W1, short* __restrict__ W1Thi, short* __restrict__ W1Tlo,
        const float* __restrict__ W2, short* __restrict__ W2Thi, short* __restrict__ W2Tlo,
        const float* __restrict__ Wqkv, float* __restrict__ WqT, short* __restrict__ WqTbf,
        __hip_bfloat16* __restrict__ WkvT,
        const float* __restrict__ W_ih, __hip_bfloat16* __restrict__ WihT,
        const float* __restrict__ W_hh, __hip_bfloat16* __restrict__ WhhT,
        const float* __restrict__ Wo, __hip_bfloat16* __restrict__ WoT,
        const float* __restrict__ prev_d, __hip_bfloat16* __restrict__ pdbf) {
    __shared__ float t[32][33];
    const int blk = blockIdx.x, tid = threadIdx.x;
    if (blk < 16)        dev_wsplit(t, W1, W1Thi, W1Tlo, 64, 256, 256, blk, tid);
    else if (blk < 80)   dev_wsplit(t, W2, W2Thi, W2Tlo, 256, DMA, 256, blk - 16, tid);
    else if (blk < 272)  dev_prep(t, Wqkv, WqT, WqTbf, WkvT, blk - 80, tid);
    else if (blk < 1808) dev_trbf(t, W_ih, WihT, 2048, 768, blk - 272, tid);
    else if (blk < 2000) dev_trbf(t, W_hh, WhhT, 256, 768, blk - 1808, tid);
    else if (blk < 2064) dev_trbf(t, Wo, WoT, 256, 256, blk - 2000, tid);
    else {
        int i = (blk - 2064) * 1024 + tid * 4;
        float4 v = *(const float4*)&prev_d[i];
        pdbf[i]     = __float2bfloat16(v.x);
        pdbf[i + 1] = __float2bfloat16(v.y);
        pdbf[i + 2] = __float2bfloat16(v.z);
        pdbf[i + 3] = __float2bfloat16(v.w);
    }
}

// ---------------------------------------------------------------------------
// K_mlp: FUSED MLP + K/V emit. EXACT R5/R8 version (proven 125us,
// FETCH ~18GB-KB). 64 tok/block, 512 thr / 8 waves, nt=2.
// ---------------------------------------------------------------------------
__global__ void __launch_bounds__(512, 4) k_mlp(const float* __restrict__ x_obs,
        const short* __restrict__ W1Thi, const short* __restrict__ W1Tlo,
        const float* __restrict__ b1,
        const short* __restrict__ W2Thi, const short* __restrict__ W2Tlo,
        const float* __restrict__ b2, const float* __restrict__ a_prev,
        const short* __restrict__ WkvT, const float* __restrict__ bqkv,
        float* __restrict__ xa,
        __hip_bfloat16* __restrict__ kbf, __hip_bfloat16* __restrict__ vbfT) {
    __shared__ __attribute__((aligned(16))) short Hhi[64 * 256];
    __shared__ __attribute__((aligned(16))) short Hlo[64 * 256];
    const int m0 = blockIdx.x * 64;
    const int b = blockIdx.x >> 1;                 // batch
    const int tb0 = (blockIdx.x & 1) * 64;          // token base within batch
    const int tid = threadIdx.x;
    const int wave = tid >> 6, lane = tid & 63;     // wave in [0,8)
    const int quad = lane >> 4, l15 = lane & 15;
    const int n0 = wave * 32;                       // 32-col slice per wave

    // ---- GEMM1: h strip [64 tokens x 32 cols per wave] ----
    {
        bf16x8 Bh[2][2], Bl[2][2];
#pragma unroll
        for (int nt = 0; nt < 2; ++nt)
#pragma unroll
            for (int ks = 0; ks < 2; ++ks) {
                size_t o = (size_t)(n0 + nt * 16 + l15) * 64 + ks * 32 + quad * 8;
                Bh[nt][ks] = *(const bf16x8*)&W1Thi[o];
                Bl[nt][ks] = *(const bf16x8*)&W1Tlo[o];
            }
        f32x4 acc[4][2];
#pragma unroll
        for (int mt = 0; mt < 4; ++mt)
#pragma unroll
            for (int nt = 0; nt < 2; ++nt) acc[mt][nt] = (f32x4){0.f, 0.f, 0.f, 0.f};
#pragma unroll
        for (int mt = 0; mt < 4; ++mt) {
            bf16x8 Ah[2], Al[2];
#pragma unroll
            for (int ks = 0; ks < 2; ++ks) {
                const float* xp = &x_obs[(size_t)(m0 + mt * 16 + l15) * 64 + ks * 32 + quad * 8];
                float4 a0 = *(const float4*)xp;
                float4 a1 = *(const float4*)(xp + 4);
                bf16x8 h, l;
                h[0]=f2bf(a0.x); l[0]=f2bf(a0.x - bf2f(h[0]));
                h[1]=f2bf(a0.y); l[1]=f2bf(a0.y - bf2f(h[1]));
                h[2]=f2bf(a0.z); l[2]=f2bf(a0.z - bf2f(h[2]));
                h[3]=f2bf(a0.w); l[3]=f2bf(a0.w - bf2f(h[3]));
                h[4]=f2bf(a1.x); l[4]=f2bf(a1.x - bf2f(h[4]));
                h[5]=f2bf(a1.y); l[5]=f2bf(a1.y - bf2f(h[5]));
                h[6]=f2bf(a1.z); l[6]=f2bf(a1.z - bf2f(h[6]));
                h[7]=f2bf(a1.w); l[7]=f2bf(a1.w - bf2f(h[7]));
                Ah[ks] = h; Al[ks] = l;
            }
#pragma unroll
            for (int nt = 0; nt < 2; ++nt)
#pragma unroll
                for (int ks = 0; ks < 2; ++ks) {
                    acc[mt][nt] = __builtin_amdgcn_mfma_f32_16x16x32_bf16(Ah[ks], Bh[nt][ks], acc[mt][nt], 0, 0, 0);
                    acc[mt][nt] = __builtin_amdgcn_mfma_f32_16x16x32_bf16(Ah[ks], Bl[nt][ks], acc[mt][nt], 0, 0, 0);
                    acc[mt][nt] = __builtin_amdgcn_mfma_f32_16x16x32_bf16(Al[ks], Bh[nt][ks], acc[mt][nt], 0, 0, 0);
                }
        }
#pragma unroll
        for (int nt = 0; nt < 2; ++nt) {
            int col = n0 + nt * 16 + l15;
            float bias = b1[col];
#pragma unroll
            for (int mt = 0; mt < 4; ++mt)
#pragma unroll
                for (int r = 0; r < 4; ++r) {
                    int tl = mt * 16 + quad * 4 + r;       // local token
                    float tv = tanh_fast(acc[mt][nt][r] + bias);
                    short h = f2bf(tv);
                    Hhi[HSW(tl, col)] = h;
                    Hlo[HSW(tl, col)] = f2bf(tv - bf2f(h));
                }
        }
    }

    // ---- GEMM2: double-buffered B; k0=0 preload overlaps the barrier ----
    f32x4 acc[4][2];
#pragma unroll
    for (int mt = 0; mt < 4; ++mt)
#pragma unroll
        for (int nt = 0; nt < 2; ++nt) acc[mt][nt] = (f32x4){0.f, 0.f, 0.f, 0.f};

    bf16x8 Bh[2][2], Bl[2][2];
#pragma unroll
    for (int nt = 0; nt < 2; ++nt) {
        size_t o = (size_t)(n0 + nt * 16 + l15) * 256 + quad * 8;
        Bh[0][nt] = *(const bf16x8*)&W2Thi[o];
        Bl[0][nt] = *(const bf16x8*)&W2Tlo[o];
    }
    __syncthreads();

#pragma unroll
    for (int ki = 0; ki < 8; ++ki) {
        const int cur = ki & 1, nxt = cur ^ 1;
        if (ki < 7) {
            int k0n = (ki + 1) * 32;
#pragma unroll
            for (int nt = 0; nt < 2; ++nt) {
                size_t o = (size_t)(n0 + nt * 16 + l15) * 256 + k0n + quad * 8;
                Bh[nxt][nt] = *(const bf16x8*)&W2Thi[o];
                Bl[nxt][nt] = *(const bf16x8*)&W2Tlo[o];
            }
        }
        const int k0 = ki * 32;
#pragma unroll
        for (int mt = 0; mt < 4; ++mt) {
            bf16x8 Ah = *(bf16x8*)&Hhi[HSW(mt * 16 + l15, k0 + quad * 8)];
            bf16x8 Al = *(bf16x8*)&Hlo[HSW(mt * 16 + l15, k0 + quad * 8)];
#pragma unroll
            for (int nt = 0; nt < 2; ++nt) {
                acc[mt][nt] = __builtin_amdgcn_mfma_f32_16x16x32_bf16(Ah, Bh[cur][nt], acc[mt][nt], 0, 0, 0);
                acc[mt][nt] = __builtin_amdgcn_mfma_f32_16x16x32_bf16(Ah, Bl[cur][nt], acc[mt][nt], 0, 0, 0);
                acc[mt][nt] = __builtin_amdgcn_mfma_f32_16x16x32_bf16(Al, Bh[cur][nt], acc[mt][nt], 0, 0, 0);
            }
        }
    }

    // all waves finished READING Hhi/Hlo before we overwrite with Xbf
    __syncthreads();
    short* Xbf = Hhi;   // reuse: bf16 xa strip, swizzled [64][256]
#pragma unroll
    for (int nt = 0; nt < 2; ++nt) {
        int col = n0 + nt * 16 + l15;
        float bias = (col < DMA) ? b2[col] : 0.f;
#pragma unroll
        for (int mt = 0; mt < 4; ++mt)
#pragma unroll
            for (int r = 0; r < 4; ++r) {
                int tl = mt * 16 + quad * 4 + r;
                int token = m0 + tl;
                float v;
                if (col < DMA) v = acc[mt][nt][r] + bias;
                else           v = a_prev[(size_t)token * ACT_ + (col - DMA)];
                xa[(size_t)token * 256 + col] = v;
                Xbf[HSW(tl, col)] = f2bf(v);
            }
    }

    // prefetch ntile0's FIRST half B panel (k=0..127) before the barrier
    bf16x8 bfv[4][2];
#pragma unroll
    for (int k8 = 0; k8 < 4; ++k8)
#pragma unroll
        for (int nf = 0; nf < 2; ++nf)
            bfv[k8][nf] = *(const bf16x8*)&WkvT[(size_t)(n0 + nf * 16 + l15) * 256
                                                + k8 * 32 + quad * 8];
    __syncthreads();

    // ---- GEMM3: K/V = Xbf @ WkvT + bkv. 8 waves x 2 ntiles x 32 cols.
    // B panel in 4-deep halves. Per-element k8 order 0..7 -> bit-identical.
    for (int ntile = 0; ntile < 2; ++ntile) {
        const int nbase = ntile * 256 + n0;
        f32x4 acc3[4][2];
#pragma unroll
        for (int nf = 0; nf < 2; ++nf) {
            float bias = bqkv[256 + nbase + nf * 16 + l15];
#pragma unroll
            for (int mt = 0; mt < 4; ++mt)
                acc3[mt][nf] = (f32x4){bias, bias, bias, bias};
        }
        // first half: k8 = 0..3 (bfv already loaded)
#pragma unroll
        for (int k8 = 0; k8 < 4; ++k8) {
            const int k0 = k8 * 32;
            bf16x8 af[4];
#pragma unroll
            for (int mt = 0; mt < 4; ++mt)
                af[mt] = *(bf16x8*)&Xbf[HSW(mt * 16 + l15, k0 + quad * 8)];
#pragma unroll
            for (int mt = 0; mt < 4; ++mt)
#pragma unroll
                for (int nf = 0; nf < 2; ++nf)
                    acc3[mt][nf] = __builtin_amdgcn_mfma_f32_16x16x32_bf16(
                        af[mt], bfv[k8][nf], acc3[mt][nf], 0, 0, 0);
        }
        // second half: load k=128..255 then k8 = 4..7
#pragma unroll
        for (int k8 = 0; k8 < 4; ++k8)
#pragma unroll
            for (int nf = 0; nf < 2; ++nf)
                bfv[k8][nf] = *(const bf16x8*)&WkvT[(size_t)(nbase + nf * 16 + l15) * 256
                                                    + 128 + k8 * 32 + quad * 8];
#pragma unroll
        for (int k8 = 0; k8 < 4; ++k8) {
            const int k0 = 128 + k8 * 32;
            bf16x8 af[4];
#pragma unroll
            for (int mt = 0; mt < 4; ++mt)
                af[mt] = *(bf16x8*)&Xbf[HSW(mt * 16 + l15, k0 + quad * 8)];
#pragma unroll
            for (int mt = 0; mt < 4; ++mt)
#pragma unroll
                for (int nf = 0; nf < 2; ++nf)
                    acc3[mt][nf] = __builtin_amdgcn_mfma_f32_16x16x32_bf16(
                        af[mt], bfv[k8][nf], acc3[mt][nf], 0, 0, 0);
        }
        // prefetch next ntile's first half before the store tail
        if (ntile < 1) {
            const int nb2 = 256 + n0;
#pragma unroll
            for (int k8 = 0; k8 < 4; ++k8)
#pragma unroll
                for (int nf = 0; nf < 2; ++nf)
                    bfv[k8][nf] = *(const bf16x8*)&WkvT[(size_t)(nb2 + nf * 16 + l15) * 256
                                                        + k8 * 32 + quad * 8];
        }
#pragma unroll
        for (int nf = 0; nf < 2; ++nf) {
            int n_g = nbase + nf * 16 + l15;
            if (n_g < 256) {
#pragma unroll
                for (int mt = 0; mt < 4; ++mt)
#pragma unroll
                    for (int r = 0; r < 4; ++r) {
                        int token = tb0 + mt * 16 + quad * 4 + r;
                        kbf[((size_t)b * SS + token) * 256 + n_g] = __float2bfloat16(acc3[mt][nf][r]);
                    }
            } else {
                // transposed V: 4 consecutive tokens -> one aligned 8B store
#pragma unroll
                for (int mt = 0; mt < 4; ++mt) {
                    short4v pv;
#pragma unroll
                    for (int r = 0; r < 4; ++r) pv[r] = f2bf(acc3[mt][nf][r]);
                    *(short4v*)((short*)vbfT + ((size_t)b * 256 + (n_g - 256)) * SS
                                + tb0 + mt * 16 + quad * 4) = pv;
                }
            }
        }
    }
}

// ---------------------------------------------------------------------------
// K_sattn (R9): merged score + attention + out-proj. Phase-1 serial chains
// shortened: xasum/ksum/wqk use 4 independent accumulators (reorder class
// validated bit-stable in R6/R7); row-dots restructured to 16-lane groups —
// 4 rows in flight, 4-step fp64 butterfly (64 shuffles/wave vs 384), wqk
// cached in registers. fp64 reassociation: ties are measure-zero; existing
// tie-break handles exact equality. Phases 2-3 unchanged from R8.
// ---------------------------------------------------------------------------
__global__ void __launch_bounds__(256) k_sattn(const float* __restrict__ xa,
        const float* __restrict__ Wqkv, const float* __restrict__ WqT,
        const float* __restrict__ bqkv, const short* __restrict__ WqTbf,
        const short* __restrict__ kbf, const short* __restrict__ vbfT,
        const short* __restrict__ WoT, const float* __restrict__ bo,
        float* __restrict__ resh_out, __hip_bfloat16* __restrict__ resh_bf) {
    __shared__ float xasum_sh[256];
    __shared__ float ksum_sh[256];
    __shared__ float wqk_sh[256];
    __shared__ double ssd[128];
    __shared__ int sidx[8];
    __shared__ __attribute__((aligned(16))) short Xsh[16 * 264];
    __shared__ __attribute__((aligned(16))) short Qsh[16 * 264];
    __shared__ short Pbuf[4][16 * 136];
    __shared__ __attribute__((aligned(16))) short Csh[16 * 264];
    const int b = blockIdx.x;
    const int tid = threadIdx.x;
    const int h = tid >> 6, lane = tid & 63;
    const int quad = lane >> 4, l15 = lane & 15;
    const float* xab = xa + (size_t)b * SS * DD;

    // ---- phase 1: score + top-8 ----
    {
        // xasum: 4 independent chains (reorder validated in R6/R7)
        float s0 = 0.f, s1 = 0.f, s2 = 0.f, s3 = 0.f;
        for (int r = 0; r < 128; r += 4) {
            s0 += xab[(r + 0) * 256 + tid];
            s1 += xab[(r + 1) * 256 + tid];
            s2 += xab[(r + 2) * 256 + tid];
            s3 += xab[(r + 3) * 256 + tid];
        }
        xasum_sh[tid] = (s0 + s1) + (s2 + s3);
        __syncthreads();

        float k0 = 0.f, k1 = 0.f, k2 = 0.f, k3 = 0.f;
        for (int d = 0; d < 256; d += 4) {
            k0 = fmaf(xasum_sh[d + 0], Wqkv[(size_t)(d + 0) * D3 + 256 + tid], k0);
            k1 = fmaf(xasum_sh[d + 1], Wqkv[(size_t)(d + 1) * D3 + 256 + tid], k1);
            k2 = fmaf(xasum_sh[d + 2], Wqkv[(size_t)(d + 2) * D3 + 256 + tid], k2);
            k3 = fmaf(xasum_sh[d + 3], Wqkv[(size_t)(d + 3) * D3 + 256 + tid], k3);
        }
        ksum_sh[tid] = 128.f * bqkv[256 + tid] + ((k0 + k1) + (k2 + k3));
        __syncthreads();

        float w0 = 0.f, w1 = 0.f, w2 = 0.f, w3 = 0.f;
        for (int c = 0; c < 256; c += 4) {
            w0 = fmaf(WqT[(size_t)(c + 0) * 256 + tid], ksum_sh[c + 0], w0);
            w1 = fmaf(WqT[(size_t)(c + 1) * 256 + tid], ksum_sh[c + 1], w1);
            w2 = fmaf(WqT[(size_t)(c + 2) * 256 + tid], ksum_sh[c + 2], w2);
            w3 = fmaf(WqT[(size_t)(c + 3) * 256 + tid], ksum_sh[c + 3], w3);
        }
        wqk_sh[tid] = (w0 + w1) + (w2 + w3);
        __syncthreads();

        // row dots: wave h covers rows [h*32, h*32+32); 16-lane groups, 4
        // rows in flight. Each lane owns 16 cols; wqk cached in registers.
        {
            const int g = lane >> 4;             // row subgroup 0..3
            const int c16 = (lane & 15) * 16;    // column base for this lane
            float4 w4[4];
#pragma unroll
            for (int j = 0; j < 4; ++j)
                w4[j] = *(const float4*)(wqk_sh + c16 + j * 4);
            for (int rb = 0; rb < 32; rb += 4) {
                int r = h * 32 + rb + g;
                const float* xp = &xab[(size_t)r * 256 + c16];
                double p = 0.0;
#pragma unroll
                for (int j = 0; j < 4; ++j) {
                    float4 x4 = *(const float4*)(xp + j * 4);
                    p += (double)x4.x * (double)w4[j].x;
                    p += (double)x4.y * (double)w4[j].y;
                    p += (double)x4.z * (double)w4[j].z;
                    p += (double)x4.w * (double)w4[j].w;
                }
#pragma unroll
                for (int off = 1; off < 16; off <<= 1) p += __shfl_xor(p, off);
                if ((lane & 15) == 0) ssd[r] = p;
            }
        }
        __syncthreads();
        if (tid < 64) {
            double v0 = ssd[tid], v1 = ssd[tid + 64];
            int i0 = tid, i1 = tid + 64;
            bool t0 = false, t1 = false;
            for (int t = 0; t < TOPK; ++t) {
                double c0 = t0 ? -1e300 : v0;
                double c1 = t1 ? -1e300 : v1;
                double bvv; int bi;
                if (c1 > c0) { bvv = c1; bi = i1; } else { bvv = c0; bi = i0; }
#pragma unroll
                for (int off = 1; off < 64; off <<= 1) {
                    double ov = __shfl_xor(bvv, off);
                    int oi = __shfl_xor(bi, off);
                    if (ov > bvv || (ov == bvv && oi < bi)) { bvv = ov; bi = oi; }
                }
                if (tid == 0) sidx[t] = bi;
                if (bi == i0) t0 = true;
                if (bi == i1) t1 = true;
            }
        }
        __syncthreads();
    }

    // ---- phase 2: gather + q-projection + attention (wave = head) ----
#pragma unroll
    for (int t = 0; t < 16; ++t) {
        short v = 0;
        if (t < 8) v = f2bf(xa[((size_t)b * SS + sidx[t]) * 256 + tid]);
        Xsh[t * 264 + tid] = v;
    }
    __syncthreads();

    {
        f32x4 qacc[4];
#pragma unroll
        for (int nt = 0; nt < 4; ++nt) qacc[nt] = (f32x4){0.f, 0.f, 0.f, 0.f};
#pragma unroll
        for (int ki = 0; ki < 8; ++ki) {
            int k0 = ki * 32;
            bf16x8 Ax = *(bf16x8*)&Xsh[l15 * 264 + k0 + quad * 8];
#pragma unroll
            for (int nt = 0; nt < 4; ++nt) {
                int col = h * 64 + nt * 16 + l15;
                bf16x8 Bq = *(const bf16x8*)&WqTbf[(size_t)col * 256 + k0 + quad * 8];
                qacc[nt] = __builtin_amdgcn_mfma_f32_16x16x32_bf16(Ax, Bq, qacc[nt], 0, 0, 0);
            }
        }
#pragma unroll
        for (int nt = 0; nt < 4; ++nt) {
            int col = h * 64 + nt * 16 + l15;
            float bq = bqkv[col];
#pragma unroll
            for (int r = 0; r < 4; ++r)
                Qsh[(quad * 4 + r) * 264 + col] = f2bf(qacc[nt][r] + bq);
        }
    }
    // Qsh strip is wave-local — no barrier needed.

    const short* kb = kbf + (size_t)b * SS * 256 + h * 64;
    const short* vb = vbfT + ((size_t)b * 256 + h * 64) * SS;

    bf16x8 aq[2];
#pragma unroll
    for (int ks = 0; ks < 2; ++ks)
        aq[ks] = *(bf16x8*)&Qsh[l15 * 264 + h * 64 + ks * 32 + quad * 8];
    f32x4 sc[8];
#pragma unroll
    for (int nt = 0; nt < 8; ++nt) sc[nt] = (f32x4){0.f, 0.f, 0.f, 0.f};
#pragma unroll
    for (int nt = 0; nt < 8; ++nt)
#pragma unroll
        for (int ks = 0; ks < 2; ++ks) {
            bf16x8 bk = *(const bf16x8*)&kb[(size_t)(nt * 16 + l15) * 256 + ks * 32 + quad * 8];
            sc[nt] = __builtin_amdgcn_mfma_f32_16x16x32_bf16(aq[ks], bk, sc[nt], 0, 0, 0);
        }
#pragma unroll
    for (int r = 0; r < 4; ++r) {
        float m = -3.4e38f;
#pragma unroll
        for (int nt = 0; nt < 8; ++nt) m = fmaxf(m, sc[nt][r]);
        m = fmaxf(m, __shfl_xor(m, 1));
        m = fmaxf(m, __shfl_xor(m, 2));
        m = fmaxf(m, __shfl_xor(m, 4));
        m = fmaxf(m, __shfl_xor(m, 8));
        float s = 0.f;
#pragma unroll
        for (int nt = 0; nt < 8; ++nt) {
            float e = __expf((sc[nt][r] - m) * 0.125f);
            sc[nt][r] = e;
            s += e;
        }
        s += __shfl_xor(s, 1);
        s += __shfl_xor(s, 2);
        s += __shfl_xor(s, 4);
        s += __shfl_xor(s, 8);
        float inv = 1.f / s;
        int row = quad * 4 + r;
#pragma unroll
        for (int nt = 0; nt < 8; ++nt)
            Pbuf[h][row * 136 + nt * 16 + l15] = f2bf(sc[nt][r] * inv);
    }
    __syncthreads();
    bf16x8 ap[4];
#pragma unroll
    for (int ks = 0; ks < 4; ++ks)
        ap[ks] = *(bf16x8*)&Pbuf[h][l15 * 136 + ks * 32 + quad * 8];
    f32x4 ct[4];
#pragma unroll
    for (int nt = 0; nt < 4; ++nt) ct[nt] = (f32x4){0.f, 0.f, 0.f, 0.f};
#pragma unroll
    for (int nt = 0; nt < 4; ++nt)
#pragma unroll
        for (int ks = 0; ks < 4; ++ks) {
            bf16x8 bv = *(const bf16x8*)&vb[(size_t)(nt * 16 + l15) * SS + ks * 32 + quad * 8];
            ct[nt] = __builtin_amdgcn_mfma_f32_16x16x32_bf16(ap[ks], bv, ct[nt], 0, 0, 0);
        }
    // ctx -> LDS with the same f2bf rounding the old Ctx global store used
#pragma unroll
    for (int nt = 0; nt < 4; ++nt)
#pragma unroll
        for (int r = 0; r < 4; ++r)
            Csh[(quad * 4 + r) * 264 + h * 64 + nt * 16 + l15] = f2bf(ct[nt][r]);
    __syncthreads();

    // ---- phase 3: resh = ctx @ WoT^T + bo (k_omm's exact K order) ----
    {
        f32x4 oacc[4];
#pragma unroll
        for (int nt = 0; nt < 4; ++nt) oacc[nt] = (f32x4){0.f, 0.f, 0.f, 0.f};
#pragma unroll
        for (int ki = 0; ki < 8; ++ki) {
            bf16x8 af = *(bf16x8*)&Csh[l15 * 264 + ki * 32 + quad * 8];
#pragma unroll
            for (int nt = 0; nt < 4; ++nt) {
                int col = h * 64 + nt * 16 + l15;
                bf16x8 bw = *(const bf16x8*)&WoT[(size_t)col * 256 + ki * 32 + quad * 8];
                oacc[nt] = __builtin_amdgcn_mfma_f32_16x16x32_bf16(af, bw, oacc[nt], 0, 0, 0);
            }
        }
#pragma unroll
        for (int nt = 0; nt < 4; ++nt) {
            int col = h * 64 + nt * 16 + l15;
            float bv = bo[col];
#pragma unroll
            for (int r = 0; r < 4; ++r) {
                int row = quad * 4 + r;
                if (row < 8) {
                    float v = oacc[nt][r] + bv;
                    size_t o = (size_t)b * 2048 + row * 256 + col;
                    resh_out[o] = v;
                    resh_bf[o] = __float2bfloat16(v);
                }
            }
        }
    }
}

// ---------------------------------------------------------------------------
// K_gru2 (R9): split-K widened — gi in 8 chunks of K=256 (192 blocks) +
// gh (24 blocks) = 216 blocks (84% CU coverage vs 47%). k_gruact sums the
// 8 gi partials in fixed ascending order (deterministic).
// ---------------------------------------------------------------------------
__global__ void __launch_bounds__(256) k_gru2(const __hip_bfloat16* __restrict__ resh_bf,
        const __hip_bfloat16* __restrict__ WihT, const __hip_bfloat16* __restrict__ pdbf,
        const __hip_bfloat16* __restrict__ WhhT, float* __restrict__ gip,
        float* __restrict__ gh) {
    __shared__ __attribute__((aligned(16))) short Ash[128 * 72];
    __shared__ __attribute__((aligned(16))) short Bsh[128 * 72];
    int blk = blockIdx.x;
    const __hip_bfloat16 *A, *BT;
    float* C;
    int K, kbeg, kend;
    if (blk < 192) {
        int chunk = blk / 24; blk %= 24;
        A = resh_bf; BT = WihT; C = gip + (size_t)chunk * 512 * 768;
        K = 2048; kbeg = chunk * 256; kend = kbeg + 256;
    } else {
        blk -= 192; A = pdbf; BT = WhhT; C = gh; K = 256; kbeg = 0; kend = 256;
    }
    const int mt = blk / 6, nt = blk % 6;
    const int m0 = mt * 128, n0 = nt * 128;
    const int tid = threadIdx.x;
    const int wave = tid >> 6, lane = tid & 63;
    const int wm = wave >> 1, wn = wave & 1;
    const int quad = lane >> 4, l15 = lane & 15;

    f32x4 acc[4][4];
#pragma unroll
    for (int tm = 0; tm < 4; ++tm)
#pragma unroll
        for (int tn = 0; tn < 4; ++tn)
            acc[tm][tn] = (f32x4){0.f, 0.f, 0.f, 0.f};

    for (int k0 = kbeg; k0 < kend; k0 += 64) {
        __syncthreads();
#pragma unroll
        for (int it = 0; it < 4; ++it) {
            int idx = it * 256 + tid;
            int row = idx >> 3, c8 = idx & 7;
            *(uint4*)&Ash[row * 72 + c8 * 8] =
                *(const uint4*)&A[(size_t)(m0 + row) * K + k0 + c8 * 8];
            *(uint4*)&Bsh[row * 72 + c8 * 8] =
                *(const uint4*)&BT[(size_t)(n0 + row) * K + k0 + c8 * 8];
        }
        __syncthreads();
#pragma unroll
        for (int ks = 0; ks < 2; ++ks) {
            bf16x8 af[4], bfr[4];
#pragma unroll
            for (int t = 0; t < 4; ++t) {
                af[t]  = *(bf16x8*)&Ash[(wm * 64 + t * 16 + l15) * 72 + ks * 32 + quad * 8];
                bfr[t] = *(bf16x8*)&Bsh[(wn * 64 + t * 16 + l15) * 72 + ks * 32 + quad * 8];
            }
#pragma unroll
            for (int tm = 0; tm < 4; ++tm)
#pragma unroll
                for (int tn = 0; tn < 4; ++tn)
                    acc[tm][tn] = __builtin_amdgcn_mfma_f32_16x16x32_bf16(
                        af[tm], bfr[tn], acc[tm][tn], 0, 0, 0);
        }
    }
#pragma unroll
    for (int tm = 0; tm < 4; ++tm)
#pragma unroll
        for (int tn = 0; tn < 4; ++tn) {
            int col = n0 + wn * 64 + tn * 16 + l15;
#pragma unroll
            for (int r = 0; r < 4; ++r) {
                int row = m0 + wm * 64 + tm * 16 + quad * 4 + r;
                C[(size_t)row * 768 + col] = acc[tm][tn][r];
            }
        }
}

// ---------------------------------------------------------------------------
// K_gruact: gates elementwise. newd = (1-z)*n + z*prev_d. Sums the 8 split-K
// gi partials in fixed ascending order (deterministic).
// ---------------------------------------------------------------------------
__global__ void k_gruact(const float* __restrict__ gip, const float* __restrict__ gh,
                         const float* __restrict__ b_ih, const float* __restrict__ b_hh,
                         const float* __restrict__ prev_d, float* __restrict__ newd) {
    const int b = blockIdx.x, tid = threadIdx.x;
    const size_t SZ = (size_t)512 * 768;
    const float* g0 = gip + (size_t)b * D3;
    const float* ghb = gh + (size_t)b * D3;
    float ir = 0.f, iz = 0.f, in = 0.f;
#pragma unroll
    for (int c = 0; c < 8; ++c) {
        ir += g0[c * SZ + tid];
        iz += g0[c * SZ + 256 + tid];
        in += g0[c * SZ + 512 + tid];
    }
    ir += b_ih[tid];
    iz += b_ih[256 + tid];
    in += b_ih[512 + tid];
    float hr = ghb[tid] + b_hh[tid];
    float hz = ghb[256 + tid] + b_hh[256 + tid];
    float hn = ghb[512 + tid] + b_hh[512 + tid];
    float pd = prev_d[(size_t)b * 256 + tid];
    float r = 1.f / (1.f + __expf(-(ir + hr)));
    float z = 1.f / (1.f + __expf(-(iz + hz)));
    float n = tanhf(in + r * hn);
    newd[(size_t)b * 256 + tid] = (1.f - z) * n + z * pd;
}

// ---------------------------------------------------------------------------
extern "C" void kernel_launch(void* const* d_in, const int* in_sizes, int n_in,
                              void* d_out, int out_size, void* d_ws, size_t ws_size,
                              hipStream_t stream) {
    const float* prev_d = (const float*)d_in[0];
    const float* x_obs  = (const float*)d_in[1];
    const float* a_prev = (const float*)d_in[2];
    const float* W1     = (const float*)d_in[3];
    const float* b1     = (const float*)d_in[4];
    const float* W2     = (const float*)d_in[5];
    const float* b2     = (const float*)d_in[6];
    const float* Wqkv   = (const float*)d_in[7];
    const float* bqkv   = (const float*)d_in[8];
    const float* Wo     = (const float*)d_in[9];
    const float* bo     = (const float*)d_in[10];
    const float* W_ih   = (const float*)d_in[11];
    const float* b_ih   = (const float*)d_in[12];
    const float* W_hh   = (const float*)d_in[13];
    const float* b_hh   = (const float*)d_in[14];
    float* out = (float*)d_out;

    const size_t NT = (size_t)BB * SS * DD;   // 16,777,216
    // region 1: xa fp32 (67 MB)
    float* xa = (float*)d_ws;
    // region 2 (67 MB): [kbf|vbfT]; gip/gh alias kbf AFTER k_sattn is done
    // reading it (k_gru2 runs strictly later). gip = 8 x 1.5MB = 12.6MB.
    short* hkv = (short*)(xa + NT);
    __hip_bfloat16* kbf = (__hip_bfloat16*)hkv;
    __hip_bfloat16* vbfT = (__hip_bfloat16*)(hkv + NT);
    char* r2late = (char*)hkv;
    float* gip = (float*)(r2late + 2359296);                          // 8x 512x768 fp32 = 12,582,912
    float* gh  = (float*)(r2late + 2359296 + 12582912);               // 1,572,864
    // region 3 (16.8 MB): attn-phase buffers. resh_bf in the old Ctx slot.
    short* xsp = hkv + 2 * NT;
    char* late = (char*)xsp;
    __hip_bfloat16* WihT = (__hip_bfloat16*)late;                     // 3,145,728
    __hip_bfloat16* WhhT = (__hip_bfloat16*)(late + 3145728);         //   393,216
    __hip_bfloat16* WoT  = (__hip_bfloat16*)(late + 3538944);         //   131,072
    short* WqTbf = (short*)(late + 3670016);                          //   131,072
    __hip_bfloat16* resh_bf = (__hip_bfloat16*)(late + 3801088);      // 2,097,152
    // region 4: persistent small (never aliased)
    short* fixed = xsp + 2 * (size_t)NTOK * 64;
    short* W1Thi = fixed;                    // 16384
    short* W1Tlo = W1Thi + 16384;
    short* W2Thi = W1Tlo + 16384;            // 65536
    short* W2Tlo = W2Thi + 65536;
    float* WqT = (float*)(W2Tlo + 65536);    // 65536 floats
    __hip_bfloat16* WkvT = (__hip_bfloat16*)(WqT + 65536);  // 131072
    int* idxb = (int*)(WkvT + 131072);                      // 4096 ints (unused, layout keep)
    __hip_bfloat16* pdbf = (__hip_bfloat16*)(idxb + 4096);  // 131072 bf16

    float* newd = out;                       // [B, D]
    float* resh = out + (size_t)BB * DD;     // [B, TOPK*D]

    k_prepall <<<2192, 256, 0, stream>>>(W1, W1Thi, W1Tlo, W2, W2Thi, W2Tlo,
                                         Wqkv, WqT, WqTbf, WkvT,
                                         W_ih, WihT, W_hh, WhhT, Wo, WoT,
                                         prev_d, pdbf);
    k_mlp     <<<NTOK / 64, 512, 0, stream>>>(x_obs, W1Thi, W1Tlo, b1,
                                              W2Thi, W2Tlo, b2, a_prev,
                                              (const short*)WkvT, bqkv,
                                              xa, kbf, vbfT);
    k_sattn   <<<BB, 256, 0, stream>>>(xa, Wqkv, WqT, bqkv, WqTbf,
                                       (const short*)kbf, (const short*)vbfT,
                                       (const short*)WoT, bo, resh, resh_bf);
    k_gru2    <<<216, 256, 0, stream>>>(resh_bf, WihT, pdbf, WhhT, gip, gh);
    k_gruact  <<<BB, 256, 0, stream>>>(gip, gh, b_ih, b_hh, prev_d, newd);
}

// Round 10
// 274.294 us; speedup vs baseline: 1.1530x; 1.0055x over previous
//
#include <hip/hip_runtime.h>
#include <hip/hip_bf16.h>
#include <math.h>

#define BB 512
#define SS 128
#define DD 256
#define HH 4
#define TOPK 8
#define D3 768
#define DMA 248
#define ACT_ 8
#define NTOK 65536            // B*S

typedef __attribute__((ext_vector_type(8))) short bf16x8;
typedef __attribute__((ext_vector_type(4))) short short4v;
typedef __attribute__((ext_vector_type(4))) float f32x4;

static __device__ __forceinline__ short f2bf(float x) {
    __hip_bfloat16 h = __float2bfloat16(x);
    return *reinterpret_cast<short*>(&h);
}
static __device__ __forceinline__ float bf2f(short s) {
    __hip_bfloat16 h = *reinterpret_cast<__hip_bfloat16*>(&s);
    return __bfloat162float(h);
}
static __device__ __forceinline__ float tanh_fast(float x) {
    float e = __expf(2.f * x);
    return 1.f - 2.f / (e + 1.f);
}

// Swizzled LDS index for the [64][256]-short H/X strips: XOR row bits into the
// 16B-unit bits of col. Keeps bf16x8 groups contiguous (XOR bits >= 3 only).
#define HSW(r, c) ((r) * 256 + ((c) ^ (((r) & 7) << 3)))

// ---------------------------------------------------------------------------
// device helpers for the prep work
// ---------------------------------------------------------------------------
__device__ __forceinline__ void dev_wsplit(float (*t)[33], const float* src,
        short* dhi, short* dlo, int R, int C, int Cpad, int blk, int tid) {
    const int ctiles = Cpad >> 5;
    const int rt = blk / ctiles, ct = blk % ctiles;
    const int r0 = rt * 32, c0 = ct * 32;
#pragma unroll
    for (int i = 0; i < 4; ++i) {
        int idx = i * 256 + tid;
        int lr = idx >> 5, lc = idx & 31;
        t[lr][lc] = (c0 + lc < C) ? src[(size_t)(r0 + lr) * C + c0 + lc] : 0.f;
    }
    __syncthreads();
#pragma unroll
    for (int i = 0; i < 4; ++i) {
        int idx = i * 256 + tid;
        int lc = idx >> 5, lr = idx & 31;
        float v = t[lr][lc];
        short h = f2bf(v);
        size_t o = (size_t)(c0 + lc) * R + r0 + lr;
        dhi[o] = h;
        dlo[o] = f2bf(v - bf2f(h));
    }
}

__device__ __forceinline__ void dev_trbf(float (*t)[33], const float* src,
        __hip_bfloat16* dst, int R, int C, int blk, int tid) {
    const int ctiles = C >> 5;
    const int rt = blk / ctiles, ct = blk % ctiles;
    const int r0 = rt * 32, c0 = ct * 32;
#pragma unroll
    for (int i = 0; i < 4; ++i) {
        int idx = i * 256 + tid;
        int lr = idx >> 5, lc = idx & 31;
        t[lr][lc] = src[(size_t)(r0 + lr) * C + c0 + lc];
    }
    __syncthreads();
#pragma unroll
    for (int i = 0; i < 4; ++i) {
        int idx = i * 256 + tid;
        int lc = idx >> 5, lr = idx & 31;
        dst[(size_t)(c0 + lc) * R + r0 + lr] = __float2bfloat16(t[lr][lc]);
    }
}

__device__ __forceinline__ void dev_prep(float (*t)[33], const float* Wqkv,
        float* WqT, short* WqTbf, __hip_bfloat16* WkvT, int blk, int tid) {
    const int rt = blk / 24, ct = blk % 24;
    const int r0 = rt * 32, c0 = ct * 32;
#pragma unroll
    for (int i = 0; i < 4; ++i) {
        int idx = i * 256 + tid;
        int lr = idx >> 5, lc = idx & 31;
        t[lr][lc] = Wqkv[(size_t)(r0 + lr) * D3 + c0 + lc];
    }
    __syncthreads();
#pragma unroll
    for (int i = 0; i < 4; ++i) {
        int idx = i * 256 + tid;
        int lc = idx >> 5, lr = idx & 31;
        float v = t[lr][lc];
        int c = c0 + lc, r = r0 + lr;
        if (c < 256) {
            WqT[(size_t)c * 256 + r] = v;
            WqTbf[(size_t)c * 256 + r] = f2bf(v);
        } else {
            WkvT[(size_t)(c - 256) * 256 + r] = __float2bfloat16(v);
        }
    }
}

// ---------------------------------------------------------------------------
// K_prepA (R10): ONLY what k_mlp / k_sattn need upstream: W1/W2 splits,
// Wqkv prep, Wo transpose. The GRU-only prep (W_ih/W_hh/pdbf, 1856 blocks)
// moved into k_sattn's grid — it rides in k_sattn's latency shadow and is
// ready before k_gru2 (same-stream ordering).
// ---------------------------------------------------------------------------
__global__ void __launch_bounds__(256) k_prepA(
        const float* __restrict__ W1, short* __restrict__ W1Thi, short* __restrict__ W1Tlo,
        const float* __restrict__ W2, short* __restrict__ W2Thi, short* __restrict__ W2Tlo,
        const float* __restrict__ Wqkv, float* __restrict__ WqT, short* __restrict__ WqTbf,
        __hip_bfloat16* __restrict__ WkvT,
        const float* __restrict__ Wo, __hip_bfloat16* __restrict__ WoT) {
    __shared__ float t[32][33];
    const int blk = blockIdx.x, tid = threadIdx.x;
    if (blk < 16)        dev_wsplit(t, W1, W1Thi, W1Tlo, 64, 256, 256, blk, tid);
    else if (blk < 80)   dev_wsplit(t, W2, W2Thi, W2Tlo, 256, DMA, 256, blk - 16, tid);
    else if (blk < 272)  dev_prep(t, Wqkv, WqT, WqTbf, WkvT, blk - 80, tid);
    else                 dev_trbf(t, Wo, WoT, 256, 256, blk - 272, tid);
}

// ---------------------------------------------------------------------------
// K_mlp: FUSED MLP + K/V emit. EXACT R5/R8/R9 version (proven ~123us,
// FETCH ~18GB-KB). 64 tok/block, 512 thr / 8 waves, nt=2.
// ---------------------------------------------------------------------------
__global__ void __launch_bounds__(512, 4) k_mlp(const float* __restrict__ x_obs,
        const short* __restrict__ W1Thi, const short* __restrict__ W1Tlo,
        const float* __restrict__ b1,
        const short* __restrict__ W2Thi, const short* __restrict__ W2Tlo,
        const float* __restrict__ b2, const float* __restrict__ a_prev,
        const short* __restrict__ WkvT, const float* __restrict__ bqkv,
        float* __restrict__ xa,
        __hip_bfloat16* __restrict__ kbf, __hip_bfloat16* __restrict__ vbfT) {
    __shared__ __attribute__((aligned(16))) short Hhi[64 * 256];
    __shared__ __attribute__((aligned(16))) short Hlo[64 * 256];
    const int m0 = blockIdx.x * 64;
    const int b = blockIdx.x >> 1;                 // batch
    const int tb0 = (blockIdx.x & 1) * 64;          // token base within batch
    const int tid = threadIdx.x;
    const int wave = tid >> 6, lane = tid & 63;     // wave in [0,8)
    const int quad = lane >> 4, l15 = lane & 15;
    const int n0 = wave * 32;                       // 32-col slice per wave

    // ---- GEMM1: h strip [64 tokens x 32 cols per wave] ----
    {
        bf16x8 Bh[2][2], Bl[2][2];
#pragma unroll
        for (int nt = 0; nt < 2; ++nt)
#pragma unroll
            for (int ks = 0; ks < 2; ++ks) {
                size_t o = (size_t)(n0 + nt * 16 + l15) * 64 + ks * 32 + quad * 8;
                Bh[nt][ks] = *(const bf16x8*)&W1Thi[o];
                Bl[nt][ks] = *(const bf16x8*)&W1Tlo[o];
            }
        f32x4 acc[4][2];
#pragma unroll
        for (int mt = 0; mt < 4; ++mt)
#pragma unroll
            for (int nt = 0; nt < 2; ++nt) acc[mt][nt] = (f32x4){0.f, 0.f, 0.f, 0.f};
#pragma unroll
        for (int mt = 0; mt < 4; ++mt) {
            bf16x8 Ah[2], Al[2];
#pragma unroll
            for (int ks = 0; ks < 2; ++ks) {
                const float* xp = &x_obs[(size_t)(m0 + mt * 16 + l15) * 64 + ks * 32 + quad * 8];
                float4 a0 = *(const float4*)xp;
                float4 a1 = *(const float4*)(xp + 4);
                bf16x8 h, l;
                h[0]=f2bf(a0.x); l[0]=f2bf(a0.x - bf2f(h[0]));
                h[1]=f2bf(a0.y); l[1]=f2bf(a0.y - bf2f(h[1]));
                h[2]=f2bf(a0.z); l[2]=f2bf(a0.z - bf2f(h[2]));
                h[3]=f2bf(a0.w); l[3]=f2bf(a0.w - bf2f(h[3]));
                h[4]=f2bf(a1.x); l[4]=f2bf(a1.x - bf2f(h[4]));
                h[5]=f2bf(a1.y); l[5]=f2bf(a1.y - bf2f(h[5]));
                h[6]=f2bf(a1.z); l[6]=f2bf(a1.z - bf2f(h[6]));
                h[7]=f2bf(a1.w); l[7]=f2bf(a1.w - bf2f(h[7]));
                Ah[ks] = h; Al[ks] = l;
            }
#pragma unroll
            for (int nt = 0; nt < 2; ++nt)
#pragma unroll
                for (int ks = 0; ks < 2; ++ks) {
                    acc[mt][nt] = __builtin_amdgcn_mfma_f32_16x16x32_bf16(Ah[ks], Bh[nt][ks], acc[mt][nt], 0, 0, 0);
                    acc[mt][nt] = __builtin_amdgcn_mfma_f32_16x16x32_bf16(Ah[ks], Bl[nt][ks], acc[mt][nt], 0, 0, 0);
                    acc[mt][nt] = __builtin_amdgcn_mfma_f32_16x16x32_bf16(Al[ks], Bh[nt][ks], acc[mt][nt], 0, 0, 0);
                }
        }
#pragma unroll
        for (int nt = 0; nt < 2; ++nt) {
            int col = n0 + nt * 16 + l15;
            float bias = b1[col];
#pragma unroll
            for (int mt = 0; mt < 4; ++mt)
#pragma unroll
                for (int r = 0; r < 4; ++r) {
                    int tl = mt * 16 + quad * 4 + r;       // local token
                    float tv = tanh_fast(acc[mt][nt][r] + bias);
                    short h = f2bf(tv);
                    Hhi[HSW(tl, col)] = h;
                    Hlo[HSW(tl, col)] = f2bf(tv - bf2f(h));
                }
        }
    }

    // ---- GEMM2: double-buffered B; k0=0 preload overlaps the barrier ----
    f32x4 acc[4][2];
#pragma unroll
    for (int mt = 0; mt < 4; ++mt)
#pragma unroll
        for (int nt = 0; nt < 2; ++nt) acc[mt][nt] = (f32x4){0.f, 0.f, 0.f, 0.f};

    bf16x8 Bh[2][2], Bl[2][2];
#pragma unroll
    for (int nt = 0; nt < 2; ++nt) {
        size_t o = (size_t)(n0 + nt * 16 + l15) * 256 + quad * 8;
        Bh[0][nt] = *(const bf16x8*)&W2Thi[o];
        Bl[0][nt] = *(const bf16x8*)&W2Tlo[o];
    }
    __syncthreads();

#pragma unroll
    for (int ki = 0; ki < 8; ++ki) {
        const int cur = ki & 1, nxt = cur ^ 1;
        if (ki < 7) {
            int k0n = (ki + 1) * 32;
#pragma unroll
            for (int nt = 0; nt < 2; ++nt) {
                size_t o = (size_t)(n0 + nt * 16 + l15) * 256 + k0n + quad * 8;
                Bh[nxt][nt] = *(const bf16x8*)&W2Thi[o];
                Bl[nxt][nt] = *(const bf16x8*)&W2Tlo[o];
            }
        }
        const int k0 = ki * 32;
#pragma unroll
        for (int mt = 0; mt < 4; ++mt) {
            bf16x8 Ah = *(bf16x8*)&Hhi[HSW(mt * 16 + l15, k0 + quad * 8)];
            bf16x8 Al = *(bf16x8*)&Hlo[HSW(mt * 16 + l15, k0 + quad * 8)];
#pragma unroll
            for (int nt = 0; nt < 2; ++nt) {
                acc[mt][nt] = __builtin_amdgcn_mfma_f32_16x16x32_bf16(Ah, Bh[cur][nt], acc[mt][nt], 0, 0, 0);
                acc[mt][nt] = __builtin_amdgcn_mfma_f32_16x16x32_bf16(Ah, Bl[cur][nt], acc[mt][nt], 0, 0, 0);
                acc[mt][nt] = __builtin_amdgcn_mfma_f32_16x16x32_bf16(Al, Bh[cur][nt], acc[mt][nt], 0, 0, 0);
            }
        }
    }

    // all waves finished READING Hhi/Hlo before we overwrite with Xbf
    __syncthreads();
    short* Xbf = Hhi;   // reuse: bf16 xa strip, swizzled [64][256]
#pragma unroll
    for (int nt = 0; nt < 2; ++nt) {
        int col = n0 + nt * 16 + l15;
        float bias = (col < DMA) ? b2[col] : 0.f;
#pragma unroll
        for (int mt = 0; mt < 4; ++mt)
#pragma unroll
            for (int r = 0; r < 4; ++r) {
                int tl = mt * 16 + quad * 4 + r;
                int token = m0 + tl;
                float v;
                if (col < DMA) v = acc[mt][nt][r] + bias;
                else           v = a_prev[(size_t)token * ACT_ + (col - DMA)];
                xa[(size_t)token * 256 + col] = v;
                Xbf[HSW(tl, col)] = f2bf(v);
            }
    }

    // prefetch ntile0's FIRST half B panel (k=0..127) before the barrier
    bf16x8 bfv[4][2];
#pragma unroll
    for (int k8 = 0; k8 < 4; ++k8)
#pragma unroll
        for (int nf = 0; nf < 2; ++nf)
            bfv[k8][nf] = *(const bf16x8*)&WkvT[(size_t)(n0 + nf * 16 + l15) * 256
                                                + k8 * 32 + quad * 8];
    __syncthreads();

    // ---- GEMM3: K/V = Xbf @ WkvT + bkv. 8 waves x 2 ntiles x 32 cols.
    // B panel in 4-deep halves. Per-element k8 order 0..7 -> bit-identical.
    for (int ntile = 0; ntile < 2; ++ntile) {
        const int nbase = ntile * 256 + n0;
        f32x4 acc3[4][2];
#pragma unroll
        for (int nf = 0; nf < 2; ++nf) {
            float bias = bqkv[256 + nbase + nf * 16 + l15];
#pragma unroll
            for (int mt = 0; mt < 4; ++mt)
                acc3[mt][nf] = (f32x4){bias, bias, bias, bias};
        }
        // first half: k8 = 0..3 (bfv already loaded)
#pragma unroll
        for (int k8 = 0; k8 < 4; ++k8) {
            const int k0 = k8 * 32;
            bf16x8 af[4];
#pragma unroll
            for (int mt = 0; mt < 4; ++mt)
                af[mt] = *(bf16x8*)&Xbf[HSW(mt * 16 + l15, k0 + quad * 8)];
#pragma unroll
            for (int mt = 0; mt < 4; ++mt)
#pragma unroll
                for (int nf = 0; nf < 2; ++nf)
                    acc3[mt][nf] = __builtin_amdgcn_mfma_f32_16x16x32_bf16(
                        af[mt], bfv[k8][nf], acc3[mt][nf], 0, 0, 0);
        }
        // second half: load k=128..255 then k8 = 4..7
#pragma unroll
        for (int k8 = 0; k8 < 4; ++k8)
#pragma unroll
            for (int nf = 0; nf < 2; ++nf)
                bfv[k8][nf] = *(const bf16x8*)&WkvT[(size_t)(nbase + nf * 16 + l15) * 256
                                                    + 128 + k8 * 32 + quad * 8];
#pragma unroll
        for (int k8 = 0; k8 < 4; ++k8) {
            const int k0 = 128 + k8 * 32;
            bf16x8 af[4];
#pragma unroll
            for (int mt = 0; mt < 4; ++mt)
                af[mt] = *(bf16x8*)&Xbf[HSW(mt * 16 + l15, k0 + quad * 8)];
#pragma unroll
            for (int mt = 0; mt < 4; ++mt)
#pragma unroll
                for (int nf = 0; nf < 2; ++nf)
                    acc3[mt][nf] = __builtin_amdgcn_mfma_f32_16x16x32_bf16(
                        af[mt], bfv[k8][nf], acc3[mt][nf], 0, 0, 0);
        }
        // prefetch next ntile's first half before the store tail
        if (ntile < 1) {
            const int nb2 = 256 + n0;
#pragma unroll
            for (int k8 = 0; k8 < 4; ++k8)
#pragma unroll
                for (int nf = 0; nf < 2; ++nf)
                    bfv[k8][nf] = *(const bf16x8*)&WkvT[(size_t)(nb2 + nf * 16 + l15) * 256
                                                        + k8 * 32 + quad * 8];
        }
#pragma unroll
        for (int nf = 0; nf < 2; ++nf) {
            int n_g = nbase + nf * 16 + l15;
            if (n_g < 256) {
#pragma unroll
                for (int mt = 0; mt < 4; ++mt)
#pragma unroll
                    for (int r = 0; r < 4; ++r) {
                        int token = tb0 + mt * 16 + quad * 4 + r;
                        kbf[((size_t)b * SS + token) * 256 + n_g] = __float2bfloat16(acc3[mt][nf][r]);
                    }
            } else {
                // transposed V: 4 consecutive tokens -> one aligned 8B store
#pragma unroll
                for (int mt = 0; mt < 4; ++mt) {
                    short4v pv;
#pragma unroll
                    for (int r = 0; r < 4; ++r) pv[r] = f2bf(acc3[mt][nf][r]);
                    *(short4v*)((short*)vbfT + ((size_t)b * 256 + (n_g - 256)) * SS
                                + tb0 + mt * 16 + quad * 4) = pv;
                }
            }
        }
    }
}

// ---------------------------------------------------------------------------
// K_sattn (R10): merged score + attention + out-proj (R9 code, unchanged)
// PLUS 1856 extra blocks (blk >= BB) doing the GRU-only prep (W_ih/W_hh
// transposes + pdbf cast) — fills idle CUs during the latency-bound attn
// phases; outputs consumed only by k_gru2 (next kernel, same stream).
// ---------------------------------------------------------------------------
__global__ void __launch_bounds__(256) k_sattn(const float* __restrict__ xa,
        const float* __restrict__ Wqkv, const float* __restrict__ WqT,
        const float* __restrict__ bqkv, const short* __restrict__ WqTbf,
        const short* __restrict__ kbf, const short* __restrict__ vbfT,
        const short* __restrict__ WoT, const float* __restrict__ bo,
        const float* __restrict__ W_ih, __hip_bfloat16* __restrict__ WihT,
        const float* __restrict__ W_hh, __hip_bfloat16* __restrict__ WhhT,
        const float* __restrict__ prev_d, __hip_bfloat16* __restrict__ pdbf,
        float* __restrict__ resh_out, __hip_bfloat16* __restrict__ resh_bf) {
    __shared__ float xasum_sh[256];
    __shared__ float ksum_sh[256];
    __shared__ float wqk_sh[256];
    __shared__ double ssd[128];
    __shared__ int sidx[8];
    __shared__ __attribute__((aligned(16))) short Xsh[16 * 264];
    __shared__ __attribute__((aligned(16))) short Qsh[16 * 264];
    __shared__ short Pbuf[4][16 * 136];
    __shared__ __attribute__((aligned(16))) short Csh[16 * 264];
    __shared__ float t[32][33];
    const int tid = threadIdx.x;

    // ---- extra blocks: GRU prep (consumed only by k_gru2) ----
    if (blockIdx.x >= BB) {
        int e = blockIdx.x - BB;
        if (e < 1536)      dev_trbf(t, W_ih, WihT, 2048, 768, e, tid);
        else if (e < 1728) dev_trbf(t, W_hh, WhhT, 256, 768, e - 1536, tid);
        else {
            int i = (e - 1728) * 1024 + tid * 4;
            float4 v = *(const float4*)&prev_d[i];
            pdbf[i]     = __float2bfloat16(v.x);
            pdbf[i + 1] = __float2bfloat16(v.y);
            pdbf[i + 2] = __float2bfloat16(v.z);
            pdbf[i + 3] = __float2bfloat16(v.w);
        }
        return;
    }

    const int b = blockIdx.x;
    const int h = tid >> 6, lane = tid & 63;
    const int quad = lane >> 4, l15 = lane & 15;
    const float* xab = xa + (size_t)b * SS * DD;

    // ---- phase 1: score + top-8 ----
    {
        // xasum: 4 independent chains (reorder validated in R6/R7)
        float s0 = 0.f, s1 = 0.f, s2 = 0.f, s3 = 0.f;
        for (int r = 0; r < 128; r += 4) {
            s0 += xab[(r + 0) * 256 + tid];
            s1 += xab[(r + 1) * 256 + tid];
            s2 += xab[(r + 2) * 256 + tid];
            s3 += xab[(r + 3) * 256 + tid];
        }
        xasum_sh[tid] = (s0 + s1) + (s2 + s3);
        __syncthreads();

        float k0 = 0.f, k1 = 0.f, k2 = 0.f, k3 = 0.f;
        for (int d = 0; d < 256; d += 4) {
            k0 = fmaf(xasum_sh[d + 0], Wqkv[(size_t)(d + 0) * D3 + 256 + tid], k0);
            k1 = fmaf(xasum_sh[d + 1], Wqkv[(size_t)(d + 1) * D3 + 256 + tid], k1);
            k2 = fmaf(xasum_sh[d + 2], Wqkv[(size_t)(d + 2) * D3 + 256 + tid], k2);
            k3 = fmaf(xasum_sh[d + 3], Wqkv[(size_t)(d + 3) * D3 + 256 + tid], k3);
        }
        ksum_sh[tid] = 128.f * bqkv[256 + tid] + ((k0 + k1) + (k2 + k3));
        __syncthreads();

        float w0 = 0.f, w1 = 0.f, w2 = 0.f, w3 = 0.f;
        for (int c = 0; c < 256; c += 4) {
            w0 = fmaf(WqT[(size_t)(c + 0) * 256 + tid], ksum_sh[c + 0], w0);
            w1 = fmaf(WqT[(size_t)(c + 1) * 256 + tid], ksum_sh[c + 1], w1);
            w2 = fmaf(WqT[(size_t)(c + 2) * 256 + tid], ksum_sh[c + 2], w2);
            w3 = fmaf(WqT[(size_t)(c + 3) * 256 + tid], ksum_sh[c + 3], w3);
        }
        wqk_sh[tid] = (w0 + w1) + (w2 + w3);
        __syncthreads();

        // row dots: wave h covers rows [h*32, h*32+32); 16-lane groups, 4
        // rows in flight. Each lane owns 16 cols; wqk cached in registers.
        {
            const int g = lane >> 4;             // row subgroup 0..3
            const int c16 = (lane & 15) * 16;    // column base for this lane
            float4 w4[4];
#pragma unroll
            for (int j = 0; j < 4; ++j)
                w4[j] = *(const float4*)(wqk_sh + c16 + j * 4);
            for (int rb = 0; rb < 32; rb += 4) {
                int r = h * 32 + rb + g;
                const float* xp = &xab[(size_t)r * 256 + c16];
                double p = 0.0;
#pragma unroll
                for (int j = 0; j < 4; ++j) {
                    float4 x4 = *(const float4*)(xp + j * 4);
                    p += (double)x4.x * (double)w4[j].x;
                    p += (double)x4.y * (double)w4[j].y;
                    p += (double)x4.z * (double)w4[j].z;
                    p += (double)x4.w * (double)w4[j].w;
                }
#pragma unroll
                for (int off = 1; off < 16; off <<= 1) p += __shfl_xor(p, off);
                if ((lane & 15) == 0) ssd[r] = p;
            }
        }
        __syncthreads();
        if (tid < 64) {
            double v0 = ssd[tid], v1 = ssd[tid + 64];
            int i0 = tid, i1 = tid + 64;
            bool t0 = false, t1 = false;
            for (int t_ = 0; t_ < TOPK; ++t_) {
                double c0 = t0 ? -1e300 : v0;
                double c1 = t1 ? -1e300 : v1;
                double bvv; int bi;
                if (c1 > c0) { bvv = c1; bi = i1; } else { bvv = c0; bi = i0; }
#pragma unroll
                for (int off = 1; off < 64; off <<= 1) {
                    double ov = __shfl_xor(bvv, off);
                    int oi = __shfl_xor(bi, off);
                    if (ov > bvv || (ov == bvv && oi < bi)) { bvv = ov; bi = oi; }
                }
                if (tid == 0) sidx[t_] = bi;
                if (bi == i0) t0 = true;
                if (bi == i1) t1 = true;
            }
        }
        __syncthreads();
    }

    // ---- phase 2: gather + q-projection + attention (wave = head) ----
#pragma unroll
    for (int t_ = 0; t_ < 16; ++t_) {
        short v = 0;
        if (t_ < 8) v = f2bf(xa[((size_t)b * SS + sidx[t_]) * 256 + tid]);
        Xsh[t_ * 264 + tid] = v;
    }
    __syncthreads();

    {
        f32x4 qacc[4];
#pragma unroll
        for (int nt = 0; nt < 4; ++nt) qacc[nt] = (f32x4){0.f, 0.f, 0.f, 0.f};
#pragma unroll
        for (int ki = 0; ki < 8; ++ki) {
            int k0 = ki * 32;
            bf16x8 Ax = *(bf16x8*)&Xsh[l15 * 264 + k0 + quad * 8];
#pragma unroll
            for (int nt = 0; nt < 4; ++nt) {
                int col = h * 64 + nt * 16 + l15;
                bf16x8 Bq = *(const bf16x8*)&WqTbf[(size_t)col * 256 + k0 + quad * 8];
                qacc[nt] = __builtin_amdgcn_mfma_f32_16x16x32_bf16(Ax, Bq, qacc[nt], 0, 0, 0);
            }
        }
#pragma unroll
        for (int nt = 0; nt < 4; ++nt) {
            int col = h * 64 + nt * 16 + l15;
            float bq = bqkv[col];
#pragma unroll
            for (int r = 0; r < 4; ++r)
                Qsh[(quad * 4 + r) * 264 + col] = f2bf(qacc[nt][r] + bq);
        }
    }
    // Qsh strip is wave-local — no barrier needed.

    const short* kb = kbf + (size_t)b * SS * 256 + h * 64;
    const short* vb = vbfT + ((size_t)b * 256 + h * 64) * SS;

    bf16x8 aq[2];
#pragma unroll
    for (int ks = 0; ks < 2; ++ks)
        aq[ks] = *(bf16x8*)&Qsh[l15 * 264 + h * 64 + ks * 32 + quad * 8];
    f32x4 sc[8];
#pragma unroll
    for (int nt = 0; nt < 8; ++nt) sc[nt] = (f32x4){0.f, 0.f, 0.f, 0.f};
#pragma unroll
    for (int nt = 0; nt < 8; ++nt)
#pragma unroll
        for (int ks = 0; ks < 2; ++ks) {
            bf16x8 bk = *(const bf16x8*)&kb[(size_t)(nt * 16 + l15) * 256 + ks * 32 + quad * 8];
            sc[nt] = __builtin_amdgcn_mfma_f32_16x16x32_bf16(aq[ks], bk, sc[nt], 0, 0, 0);
        }
#pragma unroll
    for (int r = 0; r < 4; ++r) {
        float m = -3.4e38f;
#pragma unroll
        for (int nt = 0; nt < 8; ++nt) m = fmaxf(m, sc[nt][r]);
        m = fmaxf(m, __shfl_xor(m, 1));
        m = fmaxf(m, __shfl_xor(m, 2));
        m = fmaxf(m, __shfl_xor(m, 4));
        m = fmaxf(m, __shfl_xor(m, 8));
        float s = 0.f;
#pragma unroll
        for (int nt = 0; nt < 8; ++nt) {
            float e = __expf((sc[nt][r] - m) * 0.125f);
            sc[nt][r] = e;
            s += e;
        }
        s += __shfl_xor(s, 1);
        s += __shfl_xor(s, 2);
        s += __shfl_xor(s, 4);
        s += __shfl_xor(s, 8);
        float inv = 1.f / s;
        int row = quad * 4 + r;
#pragma unroll
        for (int nt = 0; nt < 8; ++nt)
            Pbuf[h][row * 136 + nt * 16 + l15] = f2bf(sc[nt][r] * inv);
    }
    __syncthreads();
    bf16x8 ap[4];
#pragma unroll
    for (int ks = 0; ks < 4; ++ks)
        ap[ks] = *(bf16x8*)&Pbuf[h][l15 * 136 + ks * 32 + quad * 8];
    f32x4 ct[4];
#pragma unroll
    for (int nt = 0; nt < 4; ++nt) ct[nt] = (f32x4){0.f, 0.f, 0.f, 0.f};
#pragma unroll
    for (int nt = 0; nt < 4; ++nt)
#pragma unroll
        for (int ks = 0; ks < 4; ++ks) {
            bf16x8 bv = *(const bf16x8*)&vb[(size_t)(nt * 16 + l15) * SS + ks * 32 + quad * 8];
            ct[nt] = __builtin_amdgcn_mfma_f32_16x16x32_bf16(ap[ks], bv, ct[nt], 0, 0, 0);
        }
    // ctx -> LDS with the same f2bf rounding the old Ctx global store used
#pragma unroll
    for (int nt = 0; nt < 4; ++nt)
#pragma unroll
        for (int r = 0; r < 4; ++r)
            Csh[(quad * 4 + r) * 264 + h * 64 + nt * 16 + l15] = f2bf(ct[nt][r]);
    __syncthreads();

    // ---- phase 3: resh = ctx @ WoT^T + bo (k_omm's exact K order) ----
    {
        f32x4 oacc[4];
#pragma unroll
        for (int nt = 0; nt < 4; ++nt) oacc[nt] = (f32x4){0.f, 0.f, 0.f, 0.f};
#pragma unroll
        for (int ki = 0; ki < 8; ++ki) {
            bf16x8 af = *(bf16x8*)&Csh[l15 * 264 + ki * 32 + quad * 8];
#pragma unroll
            for (int nt = 0; nt < 4; ++nt) {
                int col = h * 64 + nt * 16 + l15;
                bf16x8 bw = *(const bf16x8*)&WoT[(size_t)col * 256 + ki * 32 + quad * 8];
                oacc[nt] = __builtin_amdgcn_mfma_f32_16x16x32_bf16(af, bw, oacc[nt], 0, 0, 0);
            }
        }
#pragma unroll
        for (int nt = 0; nt < 4; ++nt) {
            int col = h * 64 + nt * 16 + l15;
            float bv = bo[col];
#pragma unroll
            for (int r = 0; r < 4; ++r) {
                int row = quad * 4 + r;
                if (row < 8) {
                    float v = oacc[nt][r] + bv;
                    size_t o = (size_t)b * 2048 + row * 256 + col;
                    resh_out[o] = v;
                    resh_bf[o] = __float2bfloat16(v);
                }
            }
        }
    }
}

// ---------------------------------------------------------------------------
// K_gru2: split-K — gi in 8 chunks of K=256 (192 blocks) + gh (24 blocks)
// = 216 blocks. k_gruact sums the 8 gi partials in fixed ascending order.
// ---------------------------------------------------------------------------
__global__ void __launch_bounds__(256) k_gru2(const __hip_bfloat16* __restrict__ resh_bf,
        const __hip_bfloat16* __restrict__ WihT, const __hip_bfloat16* __restrict__ pdbf,
        const __hip_bfloat16* __restrict__ WhhT, float* __restrict__ gip,
        float* __restrict__ gh) {
    __shared__ __attribute__((aligned(16))) short Ash[128 * 72];
    __shared__ __attribute__((aligned(16))) short Bsh[128 * 72];
    int blk = blockIdx.x;
    const __hip_bfloat16 *A, *BT;
    float* C;
    int K, kbeg, kend;
    if (blk < 192) {
        int chunk = blk / 24; blk %= 24;
        A = resh_bf; BT = WihT; C = gip + (size_t)chunk * 512 * 768;
        K = 2048; kbeg = chunk * 256; kend = kbeg + 256;
    } else {
        blk -= 192; A = pdbf; BT = WhhT; C = gh; K = 256; kbeg = 0; kend = 256;
    }
    const int mt = blk / 6, nt = blk % 6;
    const int m0 = mt * 128, n0 = nt * 128;
    const int tid = threadIdx.x;
    const int wave = tid >> 6, lane = tid & 63;
    const int wm = wave >> 1, wn = wave & 1;
    const int quad = lane >> 4, l15 = lane & 15;

    f32x4 acc[4][4];
#pragma unroll
    for (int tm = 0; tm < 4; ++tm)
#pragma unroll
        for (int tn = 0; tn < 4; ++tn)
            acc[tm][tn] = (f32x4){0.f, 0.f, 0.f, 0.f};

    for (int k0 = kbeg; k0 < kend; k0 += 64) {
        __syncthreads();
#pragma unroll
        for (int it = 0; it < 4; ++it) {
            int idx = it * 256 + tid;
            int row = idx >> 3, c8 = idx & 7;
            *(uint4*)&Ash[row * 72 + c8 * 8] =
                *(const uint4*)&A[(size_t)(m0 + row) * K + k0 + c8 * 8];
            *(uint4*)&Bsh[row * 72 + c8 * 8] =
                *(const uint4*)&BT[(size_t)(n0 + row) * K + k0 + c8 * 8];
        }
        __syncthreads();
#pragma unroll
        for (int ks = 0; ks < 2; ++ks) {
            bf16x8 af[4], bfr[4];
#pragma unroll
            for (int t = 0; t < 4; ++t) {
                af[t]  = *(bf16x8*)&Ash[(wm * 64 + t * 16 + l15) * 72 + ks * 32 + quad * 8];
                bfr[t] = *(bf16x8*)&Bsh[(wn * 64 + t * 16 + l15) * 72 + ks * 32 + quad * 8];
            }
#pragma unroll
            for (int tm = 0; tm < 4; ++tm)
#pragma unroll
                for (int tn = 0; tn < 4; ++tn)
                    acc[tm][tn] = __builtin_amdgcn_mfma_f32_16x16x32_bf16(
                        af[tm], bfr[tn], acc[tm][tn], 0, 0, 0);
        }
    }
#pragma unroll
    for (int tm = 0; tm < 4; ++tm)
#pragma unroll
        for (int tn = 0; tn < 4; ++tn) {
            int col = n0 + wn * 64 + tn * 16 + l15;
#pragma unroll
            for (int r = 0; r < 4; ++r) {
                int row = m0 + wm * 64 + tm * 16 + quad * 4 + r;
                C[(size_t)row * 768 + col] = acc[tm][tn][r];
            }
        }
}

// ---------------------------------------------------------------------------
// K_gruact: gates elementwise. newd = (1-z)*n + z*prev_d. Sums the 8 split-K
// gi partials in fixed ascending order (deterministic).
// ---------------------------------------------------------------------------
__global__ void k_gruact(const float* __restrict__ gip, const float* __restrict__ gh,
                         const float* __restrict__ b_ih, const float* __restrict__ b_hh,
                         const float* __restrict__ prev_d, float* __restrict__ newd) {
    const int b = blockIdx.x, tid = threadIdx.x;
    const size_t SZ = (size_t)512 * 768;
    const float* g0 = gip + (size_t)b * D3;
    const float* ghb = gh + (size_t)b * D3;
    float ir = 0.f, iz = 0.f, in = 0.f;
#pragma unroll
    for (int c = 0; c < 8; ++c) {
        ir += g0[c * SZ + tid];
        iz += g0[c * SZ + 256 + tid];
        in += g0[c * SZ + 512 + tid];
    }
    ir += b_ih[tid];
    iz += b_ih[256 + tid];
    in += b_ih[512 + tid];
    float hr = ghb[tid] + b_hh[tid];
    float hz = ghb[256 + tid] + b_hh[256 + tid];
    float hn = ghb[512 + tid] + b_hh[512 + tid];
    float pd = prev_d[(size_t)b * 256 + tid];
    float r = 1.f / (1.f + __expf(-(ir + hr)));
    float z = 1.f / (1.f + __expf(-(iz + hz)));
    float n = tanhf(in + r * hn);
    newd[(size_t)b * 256 + tid] = (1.f - z) * n + z * pd;
}

// ---------------------------------------------------------------------------
extern "C" void kernel_launch(void* const* d_in, const int* in_sizes, int n_in,
                              void* d_out, int out_size, void* d_ws, size_t ws_size,
                              hipStream_t stream) {
    const float* prev_d = (const float*)d_in[0];
    const float* x_obs  = (const float*)d_in[1];
    const float* a_prev = (const float*)d_in[2];
    const float* W1     = (const float*)d_in[3];
    const float* b1     = (const float*)d_in[4];
    const float* W2     = (const float*)d_in[5];
    const float* b2     = (const float*)d_in[6];
    const float* Wqkv   = (const float*)d_in[7];
    const float* bqkv   = (const float*)d_in[8];
    const float* Wo     = (const float*)d_in[9];
    const float* bo     = (const float*)d_in[10];
    const float* W_ih   = (const float*)d_in[11];
    const float* b_ih   = (const float*)d_in[12];
    const float* W_hh   = (const float*)d_in[13];
    const float* b_hh   = (const float*)d_in[14];
    float* out = (float*)d_out;

    const size_t NT = (size_t)BB * SS * DD;   // 16,777,216
    // region 1: xa fp32 (67 MB)
    float* xa = (float*)d_ws;
    // region 2 (67 MB): [kbf|vbfT]; gip/gh alias kbf AFTER k_sattn is done
    // reading it (k_gru2 runs strictly later). gip = 8 x 1.5MB = 12.6MB.
    short* hkv = (short*)(xa + NT);
    __hip_bfloat16* kbf = (__hip_bfloat16*)hkv;
    __hip_bfloat16* vbfT = (__hip_bfloat16*)(hkv + NT);
    char* r2late = (char*)hkv;
    float* gip = (float*)(r2late + 2359296);                          // 8x 512x768 fp32 = 12,582,912
    float* gh  = (float*)(r2late + 2359296 + 12582912);               // 1,572,864
    // region 3 (16.8 MB): attn-phase buffers. resh_bf in the old Ctx slot.
    short* xsp = hkv + 2 * NT;
    char* late = (char*)xsp;
    __hip_bfloat16* WihT = (__hip_bfloat16*)late;                     // 3,145,728
    __hip_bfloat16* WhhT = (__hip_bfloat16*)(late + 3145728);         //   393,216
    __hip_bfloat16* WoT  = (__hip_bfloat16*)(late + 3538944);         //   131,072
    short* WqTbf = (short*)(late + 3670016);                          //   131,072
    __hip_bfloat16* resh_bf = (__hip_bfloat16*)(late + 3801088);      // 2,097,152
    // region 4: persistent small (never aliased)
    short* fixed = xsp + 2 * (size_t)NTOK * 64;
    short* W1Thi = fixed;                    // 16384
    short* W1Tlo = W1Thi + 16384;
    short* W2Thi = W1Tlo + 16384;            // 65536
    short* W2Tlo = W2Thi + 65536;
    float* WqT = (float*)(W2Tlo + 65536);    // 65536 floats
    __hip_bfloat16* WkvT = (__hip_bfloat16*)(WqT + 65536);  // 131072
    int* idxb = (int*)(WkvT + 131072);                      // 4096 ints (unused, layout keep)
    __hip_bfloat16* pdbf = (__hip_bfloat16*)(idxb + 4096);  // 131072 bf16

    float* newd = out;                       // [B, D]
    float* resh = out + (size_t)BB * DD;     // [B, TOPK*D]

    k_prepA   <<<336, 256, 0, stream>>>(W1, W1Thi, W1Tlo, W2, W2Thi, W2Tlo,
                                        Wqkv, WqT, WqTbf, WkvT, Wo, WoT);
    k_mlp     <<<NTOK / 64, 512, 0, stream>>>(x_obs, W1Thi, W1Tlo, b1,
                                              W2Thi, W2Tlo, b2, a_prev,
                                              (const short*)WkvT, bqkv,
                                              xa, kbf, vbfT);
    k_sattn   <<<BB + 1856, 256, 0, stream>>>(xa, Wqkv, WqT, bqkv, WqTbf,
                                       (const short*)kbf, (const short*)vbfT,
                                       (const short*)WoT, bo,
                                       W_ih, WihT, W_hh, WhhT, prev_d, pdbf,
                                       resh, resh_bf);
    k_gru2    <<<216, 256, 0, stream>>>(resh_bf, WihT, pdbf, WhhT, gip, gh);
    k_gruact  <<<BB, 256, 0, stream>>>(gip, gh, b_ih, b_hh, prev_d, newd);
}